// Round 3
// baseline (3068.726 us; speedup 1.0000x reference)
//
#include <hip/hip_runtime.h>

#define NTOK 8192
#define NB 4
#define TOT 32768       // NB*NTOK
#define DMODEL 512
#define NH 8
#define DHEAD 64
#define NM 256          // landmarks
#define LWIN 32         // NTOK / NM
#define BH 32           // NB*NH

__device__ __forceinline__ float wave_sum(float v) {
#pragma unroll
  for (int o = 32; o; o >>= 1) v += __shfl_xor(v, o, 64);
  return v;
}
__device__ __forceinline__ float wave_max(float v) {
#pragma unroll
  for (int o = 32; o; o >>= 1) v = fmaxf(v, __shfl_xor(v, o, 64));
  return v;
}

// ---------------- LayerNorm ----------------
__global__ __launch_bounds__(256) void ln_kernel(const float* __restrict__ x,
                                                 const float* __restrict__ g,
                                                 const float* __restrict__ b,
                                                 float* __restrict__ xn) {
  __shared__ float r1[4], r2[4];
  size_t row = blockIdx.x;
  int tid = threadIdx.x;
  float2 v = reinterpret_cast<const float2*>(x + row * DMODEL)[tid];
  float s = wave_sum(v.x + v.y);
  float ss = wave_sum(v.x * v.x + v.y * v.y);
  int lane = tid & 63, wid = tid >> 6;
  if (!lane) { r1[wid] = s; r2[wid] = ss; }
  __syncthreads();
  s = r1[0] + r1[1] + r1[2] + r1[3];
  ss = r2[0] + r2[1] + r2[2] + r2[3];
  float mu = s * (1.f / DMODEL);
  float var = ss * (1.f / DMODEL) - mu * mu;
  float rstd = rsqrtf(var + 1e-5f);
  float2 gg = reinterpret_cast<const float2*>(g)[tid];
  float2 bb = reinterpret_cast<const float2*>(b)[tid];
  float2 o;
  o.x = (v.x - mu) * rstd * gg.x + bb.x;
  o.y = (v.y - mu) * rstd * gg.y + bb.y;
  reinterpret_cast<float2*>(xn + row * DMODEL)[tid] = o;
}

// ---------------- GEMM C = A[M,K] @ B[K,N] (row-major), batched, epilogues ----
// epi 0: C = alpha*AB + diag*I
// epi 2: qkv scatter (C unused; writes qp/kp/vp in [b,h,n,dh], q scaled 0.125)
// epi 3: C[gr,gc] = AB + bias[gc] + resid[gr,gc]   (final out projection)
__global__ __launch_bounds__(256)
void gemm_ab(const float* __restrict__ A, const float* __restrict__ Bm,
             float* __restrict__ C, int Kdim,
             int lda, int ldb, int ldc,
             long long sA, long long sB, long long sC,
             float alpha, float diag, int epi,
             float* __restrict__ qp, float* __restrict__ kp, float* __restrict__ vp,
             const float* __restrict__ bias, const float* __restrict__ resid) {
  __shared__ float As[16][64], Bs[16][64];
  int bz = blockIdx.z;
  A += sA * bz; Bm += sB * bz; if (C) C += sC * bz;
  int n0 = blockIdx.x * 64, m0 = blockIdx.y * 64;
  int tid = threadIdx.x, tx = tid & 15, ty = tid >> 4;
  int am = tid >> 2, akg = tid & 3, bk = tid >> 4, bng = tid & 15;
  const float* Aload = A + (size_t)(m0 + am) * lda + akg * 4;
  const float* Bload = Bm + (size_t)bk * ldb + n0 + bng * 4;
  float acc[4][4] = {};
  for (int k0 = 0; k0 < Kdim; k0 += 16) {
    float4 av = *reinterpret_cast<const float4*>(Aload + k0);
    float4 bv = *reinterpret_cast<const float4*>(Bload + (size_t)k0 * ldb);
    __syncthreads();
    As[akg * 4 + 0][am] = av.x; As[akg * 4 + 1][am] = av.y;
    As[akg * 4 + 2][am] = av.z; As[akg * 4 + 3][am] = av.w;
    *reinterpret_cast<float4*>(&Bs[bk][bng * 4]) = bv;
    __syncthreads();
#pragma unroll
    for (int kk = 0; kk < 16; ++kk) {
      float4 bq = *reinterpret_cast<const float4*>(&Bs[kk][tx * 4]);
      float a0 = As[kk][ty * 4 + 0], a1 = As[kk][ty * 4 + 1];
      float a2 = As[kk][ty * 4 + 2], a3 = As[kk][ty * 4 + 3];
      acc[0][0] += a0 * bq.x; acc[0][1] += a0 * bq.y; acc[0][2] += a0 * bq.z; acc[0][3] += a0 * bq.w;
      acc[1][0] += a1 * bq.x; acc[1][1] += a1 * bq.y; acc[1][2] += a1 * bq.z; acc[1][3] += a1 * bq.w;
      acc[2][0] += a2 * bq.x; acc[2][1] += a2 * bq.y; acc[2][2] += a2 * bq.z; acc[2][3] += a2 * bq.w;
      acc[3][0] += a3 * bq.x; acc[3][1] += a3 * bq.y; acc[3][2] += a3 * bq.z; acc[3][3] += a3 * bq.w;
    }
  }
  if (epi == 0) {
#pragma unroll
    for (int i = 0; i < 4; ++i) {
      int gr = m0 + ty * 4 + i;
#pragma unroll
      for (int j = 0; j < 4; ++j) {
        int gc = n0 + tx * 4 + j;
        C[(size_t)gr * ldc + gc] = alpha * acc[i][j] + (gr == gc ? diag : 0.f);
      }
    }
  } else if (epi == 2) {
#pragma unroll
    for (int i = 0; i < 4; ++i) {
      int gr = m0 + ty * 4 + i;
      int bidx = gr >> 13, nn = gr & (NTOK - 1);
#pragma unroll
      for (int j = 0; j < 4; ++j) {
        int gc = n0 + tx * 4 + j;
        int which = gc >> 9, hh = (gc >> 6) & 7, dd = gc & 63;
        float val = acc[i][j];
        if (which == 0) val *= 0.125f;
        float* dst = which == 0 ? qp : (which == 1 ? kp : vp);
        dst[(((size_t)(bidx * NH + hh)) * NTOK + nn) * DHEAD + dd] = val;
      }
    }
  } else {  // epi 3
#pragma unroll
    for (int i = 0; i < 4; ++i) {
      int gr = m0 + ty * 4 + i;
#pragma unroll
      for (int j = 0; j < 4; ++j) {
        int gc = n0 + tx * 4 + j;
        C[(size_t)gr * 512 + gc] = acc[i][j] + bias[gc] + resid[(size_t)gr * 512 + gc];
      }
    }
  }
}

// ---------------- GEMM C = A[M,K] @ B[N,K]^T (K=64), for sim2 only ----------
__global__ __launch_bounds__(256)
void gemm_abt(const float* __restrict__ A, const float* __restrict__ Bm,
              float* __restrict__ C, int Kdim,
              int lda, int ldb, int ldc,
              long long sA, long long sB, long long sC) {
  __shared__ float As[16][64], Bs[16][64];
  int bz = blockIdx.z;
  A += sA * bz; Bm += sB * bz; C += sC * bz;
  int n0 = blockIdx.x * 64, m0 = blockIdx.y * 64;
  int tid = threadIdx.x, tx = tid & 15, ty = tid >> 4;
  int am = tid >> 2, akg = tid & 3;
  const float* Aload = A + (size_t)(m0 + am) * lda + akg * 4;
  const float* Bload = Bm + (size_t)(n0 + am) * ldb + akg * 4;
  float acc[4][4] = {};
  for (int k0 = 0; k0 < Kdim; k0 += 16) {
    float4 av = *reinterpret_cast<const float4*>(Aload + k0);
    float4 bv = *reinterpret_cast<const float4*>(Bload + k0);
    __syncthreads();
    As[akg * 4 + 0][am] = av.x; As[akg * 4 + 1][am] = av.y;
    As[akg * 4 + 2][am] = av.z; As[akg * 4 + 3][am] = av.w;
    Bs[akg * 4 + 0][am] = bv.x; Bs[akg * 4 + 1][am] = bv.y;
    Bs[akg * 4 + 2][am] = bv.z; Bs[akg * 4 + 3][am] = bv.w;
    __syncthreads();
#pragma unroll
    for (int kk = 0; kk < 16; ++kk) {
      float4 bq = *reinterpret_cast<const float4*>(&Bs[kk][tx * 4]);
      float a0 = As[kk][ty * 4 + 0], a1 = As[kk][ty * 4 + 1];
      float a2 = As[kk][ty * 4 + 2], a3 = As[kk][ty * 4 + 3];
      acc[0][0] += a0 * bq.x; acc[0][1] += a0 * bq.y; acc[0][2] += a0 * bq.z; acc[0][3] += a0 * bq.w;
      acc[1][0] += a1 * bq.x; acc[1][1] += a1 * bq.y; acc[1][2] += a1 * bq.z; acc[1][3] += a1 * bq.w;
      acc[2][0] += a2 * bq.x; acc[2][1] += a2 * bq.y; acc[2][2] += a2 * bq.z; acc[2][3] += a2 * bq.w;
      acc[3][0] += a3 * bq.x; acc[3][1] += a3 * bq.y; acc[3][2] += a3 * bq.z; acc[3][3] += a3 * bq.w;
    }
  }
#pragma unroll
  for (int i = 0; i < 4; ++i) {
    int gr = m0 + ty * 4 + i;
#pragma unroll
    for (int j = 0; j < 4; ++j) {
      int gc = n0 + tx * 4 + j;
      C[(size_t)gr * ldc + gc] = acc[i][j];
    }
  }
}

// ---------------- row softmax in place (256 cols) ----------------
__global__ __launch_bounds__(256) void softmax_rows256(float* __restrict__ buf) {
  __shared__ float red[4];
  size_t row = blockIdx.x;
  float* r = buf + row * 256;
  int tid = threadIdx.x;
  int lane = tid & 63, wid = tid >> 6;
  float v = r[tid];
  float mx = wave_max(v);
  if (!lane) red[wid] = mx;
  __syncthreads();
  mx = fmaxf(fmaxf(red[0], red[1]), fmaxf(red[2], red[3]));
  __syncthreads();
  float e = expf(v - mx);
  float s = wave_sum(e);
  if (!lane) red[wid] = s;
  __syncthreads();
  s = red[0] + red[1] + red[2] + red[3];
  r[tid] = e / s;
}

// ---------------- landmark mean pooling ----------------
__global__ __launch_bounds__(64) void pool_kernel(const float* __restrict__ q,
                                                  const float* __restrict__ k,
                                                  float* __restrict__ ql,
                                                  float* __restrict__ kl) {
  int z = blockIdx.x;  // bh*NM + mm
  int bh = z >> 8, mm = z & 255;
  int dd = threadIdx.x;
  size_t base = ((size_t)bh * NTOK + mm * LWIN) * DHEAD + dd;
  float sq = 0.f, sk = 0.f;
#pragma unroll 8
  for (int j = 0; j < LWIN; ++j) { sq += q[base + j * DHEAD]; sk += k[base + j * DHEAD]; }
  size_t o = ((size_t)bh * NM + mm) * DHEAD + dd;
  ql[o] = sq * (1.f / LWIN);
  kl[o] = sk * (1.f / LWIN);
}

// ---------------- pinv helpers ----------------
__global__ void init_scalars(float* sc) { if (threadIdx.x < 2) sc[threadIdx.x] = 0.f; }

__global__ __launch_bounds__(256) void rowsum_max(const float* __restrict__ a2, float* sc) {
  __shared__ float red[4];
  size_t row = blockIdx.x;
  float v = a2[row * 256 + threadIdx.x];
  v = wave_sum(v);
  int lane = threadIdx.x & 63, wid = threadIdx.x >> 6;
  if (!lane) red[wid] = v;
  __syncthreads();
  if (threadIdx.x == 0) {
    float s = red[0] + red[1] + red[2] + red[3];
    atomicMax(reinterpret_cast<int*>(sc), __float_as_int(s));
  }
}

__global__ __launch_bounds__(256) void colsum_max(const float* __restrict__ a2, float* sc) {
  __shared__ float red[4];
  int z = blockIdx.x;
  int bh = z >> 8, j = z & 255;
  float v = a2[((size_t)bh * 256 + threadIdx.x) * 256 + j];
  v = wave_sum(v);
  int lane = threadIdx.x & 63, wid = threadIdx.x >> 6;
  if (!lane) red[wid] = v;
  __syncthreads();
  if (threadIdx.x == 0) {
    float s = red[0] + red[1] + red[2] + red[3];
    atomicMax(reinterpret_cast<int*>(sc) + 1, __float_as_int(s));
  }
}

__global__ __launch_bounds__(256) void transpose_scale(const float* __restrict__ a2,
                                                       const float* __restrict__ sc,
                                                       float* __restrict__ z) {
  size_t zz = blockIdx.x;
  int bh = zz >> 8, i = zz & 255;
  int j = threadIdx.x;
  float inv = 1.f / (sc[0] * sc[1]);
  z[((size_t)bh * 256 + i) * 256 + j] = a2[((size_t)bh * 256 + j) * 256 + i] * inv;
}

__global__ __launch_bounds__(256) void neg7_kernel(const float* __restrict__ xz, float* __restrict__ ta) {
  size_t idx = (size_t)blockIdx.x * 256 + threadIdx.x;
  int i = (idx >> 8) & 255, j = idx & 255;
  ta[idx] = (i == j ? 7.f : 0.f) - xz[idx];
}

// ---------------- fused flash: O = softmax_rows(Q @ K^T) @ V ----------------
// 32 q-rows per block (256 threads, 16x16 outer-product tiles), 64-key tiles.
// LDS rows padded +1 -> all score/PV reads broadcast or 2-way (conflict-free).
__global__ __launch_bounds__(256)
void flash_kernel(const float* __restrict__ Q, const float* __restrict__ K,
                  const float* __restrict__ V, float* __restrict__ O,
                  int nkt, long long sQ, long long sK, long long sV,
                  long long sOb, long long sOh, int ldo) {
  __shared__ float qt[32][65];
  __shared__ float Kt[64][65];
  __shared__ float Vt[64][65];
  __shared__ float pb[32][65];
  int bh = blockIdx.y;
  int q0 = blockIdx.x * 32;
  const float* Qb = Q + sQ * bh;
  const float* Kb = K + sK * bh;
  const float* Vb = V + sV * bh;
  float* Ob = O + (long long)(bh >> 3) * sOb + (long long)(bh & 7) * sOh;
  int tid = threadIdx.x, tx = tid & 15, ty = tid >> 4;
  // stage q-tile (rows 0..31)
#pragma unroll
  for (int f = 0; f < 2; ++f) {
    int r = f * 16 + ty;
    float4 qv = *reinterpret_cast<const float4*>(Qb + (size_t)(q0 + r) * 64 + tx * 4);
    qt[r][tx * 4 + 0] = qv.x; qt[r][tx * 4 + 1] = qv.y;
    qt[r][tx * 4 + 2] = qv.z; qt[r][tx * 4 + 3] = qv.w;
  }
  int r0 = 2 * ty, r1 = 2 * ty + 1;
  float m0 = -1e30f, m1 = -1e30f, l0 = 0.f, l1 = 0.f;
  float o0[4] = {0.f, 0.f, 0.f, 0.f}, o1[4] = {0.f, 0.f, 0.f, 0.f};
  for (int kt = 0; kt < nkt; ++kt) {
    __syncthreads();
#pragma unroll
    for (int f = 0; f < 4; ++f) {
      int r = f * 16 + ty;
      float4 kv = *reinterpret_cast<const float4*>(Kb + ((size_t)kt * 64 + r) * 64 + tx * 4);
      Kt[r][tx * 4 + 0] = kv.x; Kt[r][tx * 4 + 1] = kv.y;
      Kt[r][tx * 4 + 2] = kv.z; Kt[r][tx * 4 + 3] = kv.w;
      float4 vv = *reinterpret_cast<const float4*>(Vb + ((size_t)kt * 64 + r) * 64 + tx * 4);
      Vt[r][tx * 4 + 0] = vv.x; Vt[r][tx * 4 + 1] = vv.y;
      Vt[r][tx * 4 + 2] = vv.z; Vt[r][tx * 4 + 3] = vv.w;
    }
    __syncthreads();
    // scores: S[r][4tx..4tx+3]
    float s0[4] = {0.f, 0.f, 0.f, 0.f}, s1[4] = {0.f, 0.f, 0.f, 0.f};
#pragma unroll 8
    for (int d = 0; d < 64; ++d) {
      float a0 = qt[r0][d], a1 = qt[r1][d];
      float k0v = Kt[tx * 4 + 0][d], k1v = Kt[tx * 4 + 1][d];
      float k2v = Kt[tx * 4 + 2][d], k3v = Kt[tx * 4 + 3][d];
      s0[0] += a0 * k0v; s0[1] += a0 * k1v; s0[2] += a0 * k2v; s0[3] += a0 * k3v;
      s1[0] += a1 * k0v; s1[1] += a1 * k1v; s1[2] += a1 * k2v; s1[3] += a1 * k3v;
    }
    // online softmax (row reduce over 16-lane groups)
    float mx0 = fmaxf(fmaxf(s0[0], s0[1]), fmaxf(s0[2], s0[3]));
    float mx1 = fmaxf(fmaxf(s1[0], s1[1]), fmaxf(s1[2], s1[3]));
#pragma unroll
    for (int off = 8; off; off >>= 1) {
      mx0 = fmaxf(mx0, __shfl_xor(mx0, off, 64));
      mx1 = fmaxf(mx1, __shfl_xor(mx1, off, 64));
    }
    float mn0 = fmaxf(m0, mx0), mn1 = fmaxf(m1, mx1);
    float sc0 = expf(m0 - mn0), sc1 = expf(m1 - mn1);
    float p0[4], p1[4];
    float ls0 = 0.f, ls1 = 0.f;
#pragma unroll
    for (int j = 0; j < 4; ++j) {
      p0[j] = expf(s0[j] - mn0); ls0 += p0[j];
      p1[j] = expf(s1[j] - mn1); ls1 += p1[j];
    }
#pragma unroll
    for (int off = 8; off; off >>= 1) {
      ls0 += __shfl_xor(ls0, off, 64);
      ls1 += __shfl_xor(ls1, off, 64);
    }
    l0 = l0 * sc0 + ls0; l1 = l1 * sc1 + ls1;
    m0 = mn0; m1 = mn1;
#pragma unroll
    for (int j = 0; j < 4; ++j) { o0[j] *= sc0; o1[j] *= sc1; }
#pragma unroll
    for (int j = 0; j < 4; ++j) { pb[r0][tx * 4 + j] = p0[j]; pb[r1][tx * 4 + j] = p1[j]; }
    // PV: O[r][4tx+i] += sum_j pb[r][j] * Vt[j][4tx+i]
#pragma unroll 8
    for (int j = 0; j < 64; ++j) {
      float pv0 = pb[r0][j], pv1 = pb[r1][j];
      float v0v = Vt[j][tx * 4 + 0], v1v = Vt[j][tx * 4 + 1];
      float v2v = Vt[j][tx * 4 + 2], v3v = Vt[j][tx * 4 + 3];
      o0[0] += pv0 * v0v; o0[1] += pv0 * v1v; o0[2] += pv0 * v2v; o0[3] += pv0 * v3v;
      o1[0] += pv1 * v0v; o1[1] += pv1 * v1v; o1[2] += pv1 * v2v; o1[3] += pv1 * v3v;
    }
  }
  float inv0 = 1.f / l0, inv1 = 1.f / l1;
#pragma unroll
  for (int j = 0; j < 4; ++j) {
    Ob[(size_t)(q0 + r0) * ldo + tx * 4 + j] = o0[j] * inv0;
    Ob[(size_t)(q0 + r1) * ldo + tx * 4 + j] = o1[j] * inv1;
  }
}

// ---------------- depthwise conv residual added into outh ----------------
__global__ __launch_bounds__(256) void conv_add(const float* __restrict__ v,
                                                const float* __restrict__ cw,
                                                float* __restrict__ outh) {
  __shared__ float vt[96][64];
  __shared__ float wt[33];
  int z = blockIdx.x;
  int bh = z >> 7, n0 = (z & 127) * 64;
  int tid = threadIdx.x;
  if (tid < 33) wt[tid] = cw[(bh & 7) * 33 + tid];
  const float4* v4 = reinterpret_cast<const float4*>(v + (size_t)bh * NTOK * DHEAD);
  for (int f = tid; f < 1536; f += 256) {
    int rowi = f >> 4, c4 = f & 15;
    int rn = n0 - 16 + rowi;
    float4 val = make_float4(0.f, 0.f, 0.f, 0.f);
    if (rn >= 0 && rn < NTOK) val = v4[(size_t)rn * 16 + c4];
    *reinterpret_cast<float4*>(&vt[rowi][c4 * 4]) = val;
  }
  __syncthreads();
  int dd = tid & 63, rg = tid >> 6;
  int bidx = bh >> 3, hh = bh & 7;
  for (int rr = 0; rr < 16; ++rr) {
    int rloc = rg * 16 + rr;
    float acc = 0.f;
#pragma unroll
    for (int kk = 0; kk < 33; ++kk) acc += wt[kk] * vt[rloc + kk][dd];
    size_t o = ((size_t)bidx * NTOK + n0 + rloc) * 512 + hh * 64 + dd;
    outh[o] += acc;
  }
}

extern "C" void kernel_launch(void* const* d_in, const int* in_sizes, int n_in,
                              void* d_out, int out_size, void* d_ws, size_t ws_size,
                              hipStream_t stream) {
  const float* x = (const float*)d_in[0];
  const float* gamma = (const float*)d_in[1];
  const float* beta = (const float*)d_in[2];
  const float* w_qkv = (const float*)d_in[3];
  const float* w_out = (const float*)d_in[4];
  const float* b_out = (const float*)d_in[5];
  const float* conv_w = (const float*)d_in[6];
  float* out = (float*)d_out;
  float* ws = (float*)d_ws;
  (void)ws_size; (void)in_sizes; (void)n_in; (void)out_size;

  // Workspace: exactly 4 x 16,777,216 floats = 256 MiB total.
  float* region0 = ws;
  float* q  = ws + 16777216;
  float* kb = ws + 33554432;   // k; reused as outh after flash A
  float* v  = ws + 50331648;

  float* xn = region0;
  float* X2 = region0 + 0;        // 2,097,152
  float* z0 = region0 + 2097152;
  float* z1 = region0 + 4194304;
  float* XZ = region0 + 6291456;
  float* TA = region0 + 8388608;
  float* TB = region0 + 10485760;
  float* ql = region0 + 12582912; // 524,288
  float* kl = region0 + 13107200;
  float* T3 = region0 + 13631488;
  float* W2 = region0 + 14155776;
  float* sc = region0 + 14680064; // 16 floats
  float* outh = kb;

  // 1. LayerNorm
  ln_kernel<<<TOT, 256, 0, stream>>>(x, gamma, beta, xn);

  // 2. qkv projection with head scatter (q scaled); xn dead afterwards
  gemm_ab<<<dim3(24, 512, 1), 256, 0, stream>>>(xn, w_qkv, nullptr, DMODEL,
                                                DMODEL, 1536, 0, 0, 0, 0,
                                                1.f, 0.f, 2, q, kb, v, nullptr, nullptr);

  // 3. landmark pooling
  pool_kernel<<<BH * NM, 64, 0, stream>>>(q, kb, ql, kl);

  // 4. sim2 = ql @ kl^T, softmax -> attn2 in X2
  gemm_abt<<<dim3(4, 4, BH), 256, 0, stream>>>(ql, kl, X2, DHEAD,
                                               DHEAD, DHEAD, NM, 16384, 16384, 65536);
  softmax_rows256<<<BH * NM, 256, 0, stream>>>(X2);

  // 5. pinv init: global scalars, z = attn2^T / (col*row)
  init_scalars<<<1, 64, 0, stream>>>(sc);
  rowsum_max<<<BH * NM, 256, 0, stream>>>(X2, sc);
  colsum_max<<<BH * NM, 256, 0, stream>>>(X2, sc);
  transpose_scale<<<BH * NM, 256, 0, stream>>>(X2, sc, z0);

  // 6. Newton-Schulz iterations (fp32); ends with zc == z0
  float* zc = z0;
  float* zn = z1;
  for (int it = 0; it < 6; ++it) {
    gemm_ab<<<dim3(4, 4, BH), 256, 0, stream>>>(X2, zc, XZ, NM, NM, NM, NM,
                                                65536, 65536, 65536, 1.f, 0.f, 0,
                                                nullptr, nullptr, nullptr, nullptr, nullptr);
    neg7_kernel<<<8192, 256, 0, stream>>>(XZ, TA);
    gemm_ab<<<dim3(4, 4, BH), 256, 0, stream>>>(XZ, TA, TB, NM, NM, NM, NM,
                                                65536, 65536, 65536, -1.f, 15.f, 0,
                                                nullptr, nullptr, nullptr, nullptr, nullptr);
    gemm_ab<<<dim3(4, 4, BH), 256, 0, stream>>>(XZ, TB, TA, NM, NM, NM, NM,
                                                65536, 65536, 65536, -1.f, 13.f, 0,
                                                nullptr, nullptr, nullptr, nullptr, nullptr);
    gemm_ab<<<dim3(4, 4, BH), 256, 0, stream>>>(zc, TA, zn, NM, NM, NM, NM,
                                                65536, 65536, 65536, 0.25f, 0.f, 0,
                                                nullptr, nullptr, nullptr, nullptr, nullptr);
    float* t = zc; zc = zn; zn = t;
  }

  // 7. T3 = softmax(ql @ k^T) @ v   (fused flash, per bh); k dead afterwards
  flash_kernel<<<dim3(8, BH), 256, 0, stream>>>(ql, kb, v, T3, NTOK / 64,
                                                16384, 524288, 524288,
                                                8LL * 16384, 16384, 64);

  // 8. W2 = pinv(attn2) @ T3  [256 x 64]
  gemm_ab<<<dim3(1, 4, BH), 256, 0, stream>>>(zc, T3, W2, NM,
                                              NM, DHEAD, DHEAD, 65536, 16384, 16384,
                                              1.f, 0.f, 0, nullptr, nullptr, nullptr, nullptr, nullptr);

  // 9. outh = softmax(q @ kl^T) @ W2, scattered into [b, n, h*64] (= kb region)
  flash_kernel<<<dim3(256, BH), 256, 0, stream>>>(q, kl, W2, outh, NM / 64,
                                                  524288, 16384, 16384,
                                                  4194304, 64, 512);

  // 10. depthwise conv residual added into outh
  conv_add<<<BH * (NTOK / 64), 256, 0, stream>>>(v, conv_w, outh);

  // 11. final: out = x + outh @ w_out + b_out
  gemm_ab<<<dim3(8, 512, 1), 256, 0, stream>>>(outh, w_out, out, DMODEL,
                                               DMODEL, DMODEL, DMODEL, 0, 0, 0,
                                               1.f, 0.f, 3, nullptr, nullptr, nullptr, b_out, x);
}

// Round 4
// 1192.655 us; speedup vs baseline: 2.5730x; 2.5730x over previous
//
#include <hip/hip_runtime.h>

#define NTOK 8192
#define TOT 32768
#define DMODEL 512
#define NM 256
#define BH 32

typedef __attribute__((ext_vector_type(8))) short bf16x8;
typedef __attribute__((ext_vector_type(8))) unsigned short u16x8;
typedef __attribute__((ext_vector_type(4))) float f32x4;

__device__ __forceinline__ unsigned short f2b(float f) {
  unsigned u = __float_as_uint(f);
  return (unsigned short)((u + 0x7fffu + ((u >> 16) & 1u)) >> 16);
}
__device__ __forceinline__ float b2f(unsigned short h) {
  return __uint_as_float((unsigned)h << 16);
}
__device__ __forceinline__ f32x4 mfma16(bf16x8 a, bf16x8 b, f32x4 c) {
  return __builtin_amdgcn_mfma_f32_16x16x32_bf16(a, b, c, 0, 0, 0);
}
__device__ __forceinline__ float wave_sum(float v) {
#pragma unroll
  for (int o = 32; o; o >>= 1) v += __shfl_xor(v, o, 64);
  return v;
}
__device__ __forceinline__ float wave_max(float v) {
#pragma unroll
  for (int o = 32; o; o >>= 1) v = fmaxf(v, __shfl_xor(v, o, 64));
  return v;
}

// ---------------- LayerNorm: fp32 out + bf16 out ----------------
__global__ __launch_bounds__(256) void ln_kernel(const float* __restrict__ x,
                                                 const float* __restrict__ g,
                                                 const float* __restrict__ b,
                                                 float* __restrict__ xn,
                                                 unsigned int* __restrict__ xnb) {
  __shared__ float r1[4], r2[4];
  size_t row = blockIdx.x;
  int tid = threadIdx.x;
  float2 v = reinterpret_cast<const float2*>(x + row * DMODEL)[tid];
  float s = wave_sum(v.x + v.y);
  float ss = wave_sum(v.x * v.x + v.y * v.y);
  int lane = tid & 63, wid = tid >> 6;
  if (!lane) { r1[wid] = s; r2[wid] = ss; }
  __syncthreads();
  s = r1[0] + r1[1] + r1[2] + r1[3];
  ss = r2[0] + r2[1] + r2[2] + r2[3];
  float mu = s * (1.f / DMODEL);
  float var = ss * (1.f / DMODEL) - mu * mu;
  float rstd = rsqrtf(var + 1e-5f);
  float2 gg = reinterpret_cast<const float2*>(g)[tid];
  float2 bb = reinterpret_cast<const float2*>(b)[tid];
  float2 o;
  o.x = (v.x - mu) * rstd * gg.x + bb.x;
  o.y = (v.y - mu) * rstd * gg.y + bb.y;
  reinterpret_cast<float2*>(xn + row * DMODEL)[tid] = o;
  xnb[row * 256 + tid] = (unsigned)f2b(o.x) | ((unsigned)f2b(o.y) << 16);
}

// ---------------- pool xn over 32-token windows -> xl ----------------
__global__ __launch_bounds__(256) void pool_x(const float* __restrict__ xn,
                                              float* __restrict__ xl) {
  int b = blockIdx.x >> 8, m = blockIdx.x & 255;
  int t = threadIdx.x;
  const float2* src = (const float2*)(xn + ((size_t)b * NTOK + m * 32) * DMODEL);
  float sx = 0.f, sy = 0.f;
#pragma unroll 8
  for (int j = 0; j < 32; ++j) { float2 v = src[j * 256 + t]; sx += v.x; sy += v.y; }
  float2 o; o.x = sx * (1.f / 32.f); o.y = sy * (1.f / 32.f);
  ((float2*)(xl + ((size_t)b * 256 + m) * DMODEL))[t] = o;
}

// ---------------- transpose + cvt fp32[K][N] -> bf16[N][K] ----------------
__global__ __launch_bounds__(256) void transpose_cvt(const float* __restrict__ in,
                                                     unsigned short* __restrict__ outp,
                                                     int K, int N) {
  __shared__ float t[32][33];
  int k0 = blockIdx.y * 32, n0 = blockIdx.x * 32;
  int tx = threadIdx.x & 31, ty = threadIdx.x >> 5;
#pragma unroll
  for (int i = 0; i < 32; i += 8)
    t[ty + i][tx] = in[(size_t)(k0 + ty + i) * N + n0 + tx];
  __syncthreads();
#pragma unroll
  for (int i = 0; i < 32; i += 8)
    outp[(size_t)(n0 + ty + i) * K + k0 + tx] = f2b(t[tx][ty + i]);
}

__global__ __launch_bounds__(256) void cvt_bf16(const float* __restrict__ in,
                                                unsigned short* __restrict__ out, int n) {
  int i = blockIdx.x * 256 + threadIdx.x;
  if (i < n) out[i] = f2b(in[i]);
}

// ---------------- MFMA GEMM NT: C = A[M,Kd] @ Bt[N,Kd]^T ----------------
// EPI 0: A bf16, scatter qkv (q*0.125) to bf16 [bh][n][64]
// EPI 1: A fp32 (cvt on stage), Cf = AB + bias + resid  (out projection)
template <int EPI>
__global__ __launch_bounds__(256) void gemm_mfma(const void* __restrict__ Ap,
                                                 const unsigned short* __restrict__ Bt,
                                                 int Kd,
                                                 unsigned short* __restrict__ qo,
                                                 unsigned short* __restrict__ ko,
                                                 unsigned short* __restrict__ vo,
                                                 float* __restrict__ Cf,
                                                 const float* __restrict__ bias,
                                                 const float* __restrict__ resid) {
  __shared__ __align__(16) unsigned short As[128][72];
  __shared__ __align__(16) unsigned short Bs[128][72];
  const int tid = threadIdx.x;
  const int l16 = tid & 15, h8 = (tid & 63) >> 4, w = tid >> 6;
  const int m0 = blockIdx.y * 128, n0 = blockIdx.x * 128;
  const int wr = (w >> 1) * 64, wc = (w & 1) * 64;
  const int srow = tid >> 1, sc0 = (tid & 1) * 32;
  f32x4 acc[4][4] = {};
  for (int k0 = 0; k0 < Kd; k0 += 64) {
    if (EPI == 0) {
      const unsigned short* Ab = (const unsigned short*)Ap + (size_t)(m0 + srow) * Kd + k0 + sc0;
#pragma unroll
      for (int i = 0; i < 4; ++i)
        *(u16x8*)&As[srow][sc0 + 8 * i] = *(const u16x8*)(Ab + 8 * i);
    } else {
      const float* Af = (const float*)Ap + (size_t)(m0 + srow) * Kd + k0 + sc0;
#pragma unroll
      for (int i = 0; i < 4; ++i) {
        float4 f0 = *(const float4*)(Af + 8 * i);
        float4 f1 = *(const float4*)(Af + 8 * i + 4);
        u16x8 u;
        u[0] = f2b(f0.x); u[1] = f2b(f0.y); u[2] = f2b(f0.z); u[3] = f2b(f0.w);
        u[4] = f2b(f1.x); u[5] = f2b(f1.y); u[6] = f2b(f1.z); u[7] = f2b(f1.w);
        *(u16x8*)&As[srow][sc0 + 8 * i] = u;
      }
    }
    const unsigned short* Bb = Bt + (size_t)(n0 + srow) * Kd + k0 + sc0;
#pragma unroll
    for (int i = 0; i < 4; ++i)
      *(u16x8*)&Bs[srow][sc0 + 8 * i] = *(const u16x8*)(Bb + 8 * i);
    __syncthreads();
#pragma unroll
    for (int ks = 0; ks < 2; ++ks) {
      bf16x8 a[4], b[4];
#pragma unroll
      for (int mi = 0; mi < 4; ++mi)
        a[mi] = *(const bf16x8*)&As[wr + mi * 16 + l16][ks * 32 + h8 * 8];
#pragma unroll
      for (int nj = 0; nj < 4; ++nj)
        b[nj] = *(const bf16x8*)&Bs[wc + nj * 16 + l16][ks * 32 + h8 * 8];
#pragma unroll
      for (int mi = 0; mi < 4; ++mi)
#pragma unroll
        for (int nj = 0; nj < 4; ++nj)
          acc[mi][nj] = mfma16(a[mi], b[nj], acc[mi][nj]);
    }
    __syncthreads();
  }
#pragma unroll
  for (int mi = 0; mi < 4; ++mi)
#pragma unroll
    for (int nj = 0; nj < 4; ++nj)
#pragma unroll
      for (int r = 0; r < 4; ++r) {
        int grow = m0 + wr + mi * 16 + 4 * h8 + r;
        int gcol = n0 + wc + nj * 16 + l16;
        float val = acc[mi][nj][r];
        if (EPI == 0) {
          int which = gcol >> 9, hh = (gcol >> 6) & 7, dd = gcol & 63;
          int bidx = grow >> 13, nn = grow & 8191;
          if (which == 0) val *= 0.125f;
          unsigned short* dst = which == 0 ? qo : (which == 1 ? ko : vo);
          dst[(((size_t)(bidx * 8 + hh)) * NTOK + nn) * 64 + dd] = f2b(val);
        } else {
          Cf[(size_t)grow * 512 + gcol] = val + bias[gcol] + resid[(size_t)grow * 512 + gcol];
        }
      }
}

// ---------------- fp32 GEMM (landmark path + pinv), epi 0 / 5 ----------------
__global__ __launch_bounds__(256)
void gemm_ab(const float* __restrict__ A, const float* __restrict__ Bm,
             float* __restrict__ C, int Kdim, int lda, int ldb, int ldc,
             long long sA, long long sB, long long sC,
             float alpha, float diag, int epi,
             float* __restrict__ qlp, float* __restrict__ klp) {
  __shared__ float As[16][64], Bs[16][64];
  int bz = blockIdx.z;
  A += sA * bz; Bm += sB * bz; if (C) C += sC * bz;
  int n0 = blockIdx.x * 64, m0 = blockIdx.y * 64;
  int tid = threadIdx.x, tx = tid & 15, ty = tid >> 4;
  int am = tid >> 2, akg = tid & 3, bk = tid >> 4, bng = tid & 15;
  const float* Aload = A + (size_t)(m0 + am) * lda + akg * 4;
  const float* Bload = Bm + (size_t)bk * ldb + n0 + bng * 4;
  float acc[4][4] = {};
  for (int k0 = 0; k0 < Kdim; k0 += 16) {
    float4 av = *reinterpret_cast<const float4*>(Aload + k0);
    float4 bv = *reinterpret_cast<const float4*>(Bload + (size_t)k0 * ldb);
    __syncthreads();
    As[akg * 4 + 0][am] = av.x; As[akg * 4 + 1][am] = av.y;
    As[akg * 4 + 2][am] = av.z; As[akg * 4 + 3][am] = av.w;
    *reinterpret_cast<float4*>(&Bs[bk][bng * 4]) = bv;
    __syncthreads();
#pragma unroll
    for (int kk = 0; kk < 16; ++kk) {
      float4 bq = *reinterpret_cast<const float4*>(&Bs[kk][tx * 4]);
      float a0 = As[kk][ty * 4 + 0], a1 = As[kk][ty * 4 + 1];
      float a2 = As[kk][ty * 4 + 2], a3 = As[kk][ty * 4 + 3];
      acc[0][0] += a0 * bq.x; acc[0][1] += a0 * bq.y; acc[0][2] += a0 * bq.z; acc[0][3] += a0 * bq.w;
      acc[1][0] += a1 * bq.x; acc[1][1] += a1 * bq.y; acc[1][2] += a1 * bq.z; acc[1][3] += a1 * bq.w;
      acc[2][0] += a2 * bq.x; acc[2][1] += a2 * bq.y; acc[2][2] += a2 * bq.z; acc[2][3] += a2 * bq.w;
      acc[3][0] += a3 * bq.x; acc[3][1] += a3 * bq.y; acc[3][2] += a3 * bq.z; acc[3][3] += a3 * bq.w;
    }
  }
  if (epi == 0) {
#pragma unroll
    for (int i = 0; i < 4; ++i) {
      int gr = m0 + ty * 4 + i;
#pragma unroll
      for (int j = 0; j < 4; ++j) {
        int gc = n0 + tx * 4 + j;
        C[(size_t)gr * ldc + gc] = alpha * acc[i][j] + (gr == gc ? diag : 0.f);
      }
    }
  } else {  // epi 5: ql/kl scatter; rows b*256+m, cols (q|k)*512 + h*64 + d
#pragma unroll
    for (int i = 0; i < 4; ++i) {
      int gr = m0 + ty * 4 + i;
      int bidx = gr >> 8, nn = gr & 255;
#pragma unroll
      for (int j = 0; j < 4; ++j) {
        int gc = n0 + tx * 4 + j;
        int which = gc >> 9, hh = (gc >> 6) & 7, dd = gc & 63;
        float val = acc[i][j];
        if (which == 0) val *= 0.125f;
        float* dst = which == 0 ? qlp : klp;
        dst[(((size_t)(bidx * 8 + hh)) * 256 + nn) * 64 + dd] = val;
      }
    }
  }
}

// ---------------- GEMM C = A[M,64] @ B[N,64]^T (sim2) ----------------
__global__ __launch_bounds__(256)
void gemm_abt(const float* __restrict__ A, const float* __restrict__ Bm,
              float* __restrict__ C, int Kdim, int lda, int ldb, int ldc,
              long long sA, long long sB, long long sC) {
  __shared__ float As[16][64], Bs[16][64];
  int bz = blockIdx.z;
  A += sA * bz; Bm += sB * bz; C += sC * bz;
  int n0 = blockIdx.x * 64, m0 = blockIdx.y * 64;
  int tid = threadIdx.x, tx = tid & 15, ty = tid >> 4;
  int am = tid >> 2, akg = tid & 3;
  const float* Aload = A + (size_t)(m0 + am) * lda + akg * 4;
  const float* Bload = Bm + (size_t)(n0 + am) * ldb + akg * 4;
  float acc[4][4] = {};
  for (int k0 = 0; k0 < Kdim; k0 += 16) {
    float4 av = *reinterpret_cast<const float4*>(Aload + k0);
    float4 bv = *reinterpret_cast<const float4*>(Bload + k0);
    __syncthreads();
    As[akg * 4 + 0][am] = av.x; As[akg * 4 + 1][am] = av.y;
    As[akg * 4 + 2][am] = av.z; As[akg * 4 + 3][am] = av.w;
    Bs[akg * 4 + 0][am] = bv.x; Bs[akg * 4 + 1][am] = bv.y;
    Bs[akg * 4 + 2][am] = bv.z; Bs[akg * 4 + 3][am] = bv.w;
    __syncthreads();
#pragma unroll
    for (int kk = 0; kk < 16; ++kk) {
      float4 bq = *reinterpret_cast<const float4*>(&Bs[kk][tx * 4]);
      float a0 = As[kk][ty * 4 + 0], a1 = As[kk][ty * 4 + 1];
      float a2 = As[kk][ty * 4 + 2], a3 = As[kk][ty * 4 + 3];
      acc[0][0] += a0 * bq.x; acc[0][1] += a0 * bq.y; acc[0][2] += a0 * bq.z; acc[0][3] += a0 * bq.w;
      acc[1][0] += a1 * bq.x; acc[1][1] += a1 * bq.y; acc[1][2] += a1 * bq.z; acc[1][3] += a1 * bq.w;
      acc[2][0] += a2 * bq.x; acc[2][1] += a2 * bq.y; acc[2][2] += a2 * bq.z; acc[2][3] += a2 * bq.w;
      acc[3][0] += a3 * bq.x; acc[3][1] += a3 * bq.y; acc[3][2] += a3 * bq.z; acc[3][3] += a3 * bq.w;
    }
  }
#pragma unroll
  for (int i = 0; i < 4; ++i) {
    int gr = m0 + ty * 4 + i;
#pragma unroll
    for (int j = 0; j < 4; ++j)
      C[(size_t)gr * ldc + n0 + tx * 4 + j] = acc[i][j];
  }
}

// ---------------- row softmax (256 cols) ----------------
__global__ __launch_bounds__(256) void softmax_rows256(float* __restrict__ buf) {
  __shared__ float red[4];
  size_t row = blockIdx.x;
  float* r = buf + row * 256;
  int tid = threadIdx.x, lane = tid & 63, wid = tid >> 6;
  float v = r[tid];
  float mx = wave_max(v);
  if (!lane) red[wid] = mx;
  __syncthreads();
  mx = fmaxf(fmaxf(red[0], red[1]), fmaxf(red[2], red[3]));
  __syncthreads();
  float e = expf(v - mx);
  float s = wave_sum(e);
  if (!lane) red[wid] = s;
  __syncthreads();
  s = red[0] + red[1] + red[2] + red[3];
  r[tid] = e / s;
}

// ---------------- pinv helpers ----------------
__global__ void init_scalars(float* sc) { if (threadIdx.x < 2) sc[threadIdx.x] = 0.f; }

__global__ __launch_bounds__(256) void rowsum_max(const float* __restrict__ a2, float* sc) {
  __shared__ float red[4];
  size_t row = blockIdx.x;
  float v = wave_sum(a2[row * 256 + threadIdx.x]);
  int lane = threadIdx.x & 63, wid = threadIdx.x >> 6;
  if (!lane) red[wid] = v;
  __syncthreads();
  if (threadIdx.x == 0)
    atomicMax(reinterpret_cast<int*>(sc), __float_as_int(red[0] + red[1] + red[2] + red[3]));
}

__global__ __launch_bounds__(256) void colsum_max(const float* __restrict__ a2, float* sc) {
  __shared__ float red[4];
  int z = blockIdx.x, bh = z >> 8, j = z & 255;
  float v = wave_sum(a2[((size_t)bh * 256 + threadIdx.x) * 256 + j]);
  int lane = threadIdx.x & 63, wid = threadIdx.x >> 6;
  if (!lane) red[wid] = v;
  __syncthreads();
  if (threadIdx.x == 0)
    atomicMax(reinterpret_cast<int*>(sc) + 1, __float_as_int(red[0] + red[1] + red[2] + red[3]));
}

__global__ __launch_bounds__(256) void transpose_scale(const float* __restrict__ a2,
                                                       const float* __restrict__ sc,
                                                       float* __restrict__ z) {
  size_t zz = blockIdx.x;
  int bh = zz >> 8, i = zz & 255, j = threadIdx.x;
  float inv = 1.f / (sc[0] * sc[1]);
  z[((size_t)bh * 256 + i) * 256 + j] = a2[((size_t)bh * 256 + j) * 256 + i] * inv;
}

__global__ __launch_bounds__(256) void neg7_kernel(const float* __restrict__ xz,
                                                   float* __restrict__ ta) {
  size_t idx = (size_t)blockIdx.x * 256 + threadIdx.x;
  int i = (idx >> 8) & 255, j = idx & 255;
  ta[idx] = (i == j ? 7.f : 0.f) - xz[idx];
}

// ---------------- MFMA flash: O = softmax(Q K^T) V, 128 q-rows/block ----------
// mode 0: write unnormalized partial (Opart, MLpart) per split s = blockIdx.z
// mode 1: final, scatter O/l into outh [b][n][h*64]
__global__ __launch_bounds__(256) void flash_mfma(
    const unsigned short* __restrict__ Q, const unsigned short* __restrict__ Kp,
    const unsigned short* __restrict__ Vp, long long sQ, long long sK,
    int kps, int nkt, int mode,
    float* __restrict__ Opart, float* __restrict__ MLpart, float* __restrict__ outh) {
  __shared__ __align__(16) unsigned short Qt[128][72];
  __shared__ __align__(16) unsigned short Kt[64][72];
  __shared__ __align__(16) unsigned short Vt[64][72];
  __shared__ __align__(16) unsigned short Pb[128][72];
  const int tid = threadIdx.x;
  const int l16 = tid & 15, h8 = (tid & 63) >> 4, w = tid >> 6;
  const int bh = blockIdx.y, s = blockIdx.z, qt = blockIdx.x;
  const int q0 = qt * 128;
  const unsigned short* Qb = Q + (size_t)bh * sQ + (size_t)q0 * 64;
  const unsigned short* Kb = Kp + (size_t)bh * sK + (size_t)s * kps * 64;
  const unsigned short* Vb = Vp + (size_t)bh * sK + (size_t)s * kps * 64;
  {
    int row = tid >> 1, c0 = (tid & 1) * 32;
#pragma unroll
    for (int i = 0; i < 4; ++i)
      *(u16x8*)&Qt[row][c0 + 8 * i] = *(const u16x8*)(Qb + (size_t)row * 64 + c0 + 8 * i);
  }
  f32x4 acc_o[2][4] = {};
  float mrow[2][4], lrow[2][4];
#pragma unroll
  for (int mi = 0; mi < 2; ++mi)
#pragma unroll
    for (int r = 0; r < 4; ++r) { mrow[mi][r] = -1e30f; lrow[mi][r] = 0.f; }
  for (int kt = 0; kt < nkt; ++kt) {
    {
      int row = tid >> 2, c0 = (tid & 3) * 16;
      *(u16x8*)&Kt[row][c0] = *(const u16x8*)(Kb + ((size_t)(kt * 64 + row)) * 64 + c0);
      *(u16x8*)&Kt[row][c0 + 8] = *(const u16x8*)(Kb + ((size_t)(kt * 64 + row)) * 64 + c0 + 8);
      int key = tid & 63, d0 = w * 16;
      u16x8 v0 = *(const u16x8*)(Vb + ((size_t)(kt * 64 + key)) * 64 + d0);
      u16x8 v1 = *(const u16x8*)(Vb + ((size_t)(kt * 64 + key)) * 64 + d0 + 8);
#pragma unroll
      for (int i = 0; i < 8; ++i) { Vt[d0 + i][key] = v0[i]; Vt[d0 + 8 + i][key] = v1[i]; }
    }
    __syncthreads();
    f32x4 accs[2][4] = {};
#pragma unroll
    for (int ks = 0; ks < 2; ++ks) {
      bf16x8 a[2], b[4];
      a[0] = *(const bf16x8*)&Qt[w * 32 + l16][ks * 32 + h8 * 8];
      a[1] = *(const bf16x8*)&Qt[w * 32 + 16 + l16][ks * 32 + h8 * 8];
#pragma unroll
      for (int nj = 0; nj < 4; ++nj)
        b[nj] = *(const bf16x8*)&Kt[nj * 16 + l16][ks * 32 + h8 * 8];
#pragma unroll
      for (int mi = 0; mi < 2; ++mi)
#pragma unroll
        for (int nj = 0; nj < 4; ++nj)
          accs[mi][nj] = mfma16(a[mi], b[nj], accs[mi][nj]);
    }
#pragma unroll
    for (int mi = 0; mi < 2; ++mi)
#pragma unroll
      for (int r = 0; r < 4; ++r) {
        float mx = fmaxf(fmaxf(accs[mi][0][r], accs[mi][1][r]),
                         fmaxf(accs[mi][2][r], accs[mi][3][r]));
#pragma unroll
        for (int off = 8; off; off >>= 1) mx = fmaxf(mx, __shfl_xor(mx, off, 64));
        float mn = fmaxf(mrow[mi][r], mx);
        float scf = __expf(mrow[mi][r] - mn);
        float ps = 0.f;
#pragma unroll
        for (int nj = 0; nj < 4; ++nj) {
          float p = __expf(accs[mi][nj][r] - mn);
          accs[mi][nj][r] = p;
          ps += p;
        }
#pragma unroll
        for (int off = 8; off; off >>= 1) ps += __shfl_xor(ps, off, 64);
        lrow[mi][r] = lrow[mi][r] * scf + ps;
        mrow[mi][r] = mn;
#pragma unroll
        for (int dj = 0; dj < 4; ++dj) acc_o[mi][dj][r] *= scf;
        int prow = w * 32 + mi * 16 + 4 * h8 + r;
#pragma unroll
        for (int nj = 0; nj < 4; ++nj)
          Pb[prow][nj * 16 + l16] = f2b(accs[mi][nj][r]);
      }
    __syncthreads();
#pragma unroll
    for (int ks = 0; ks < 2; ++ks) {
      bf16x8 pa[2], vb[4];
      pa[0] = *(const bf16x8*)&Pb[w * 32 + l16][ks * 32 + h8 * 8];
      pa[1] = *(const bf16x8*)&Pb[w * 32 + 16 + l16][ks * 32 + h8 * 8];
#pragma unroll
      for (int dj = 0; dj < 4; ++dj)
        vb[dj] = *(const bf16x8*)&Vt[dj * 16 + l16][ks * 32 + h8 * 8];
#pragma unroll
      for (int mi = 0; mi < 2; ++mi)
#pragma unroll
        for (int dj = 0; dj < 4; ++dj)
          acc_o[mi][dj] = mfma16(pa[mi], vb[dj], acc_o[mi][dj]);
    }
    __syncthreads();
  }
  if (mode == 0) {
    int p = (s * 32 + bh) * 2 + qt;
    float* Ob = Opart + (size_t)p * 8192;
#pragma unroll
    for (int mi = 0; mi < 2; ++mi)
#pragma unroll
      for (int r = 0; r < 4; ++r) {
        int row = w * 32 + mi * 16 + 4 * h8 + r;
#pragma unroll
        for (int dj = 0; dj < 4; ++dj)
          Ob[(size_t)row * 64 + dj * 16 + l16] = acc_o[mi][dj][r];
        if (l16 == 0) {
          MLpart[((size_t)p * 128 + row) * 2] = mrow[mi][r];
          MLpart[((size_t)p * 128 + row) * 2 + 1] = lrow[mi][r];
        }
      }
  } else {
    int bidx = bh >> 3, hh = bh & 7;
#pragma unroll
    for (int mi = 0; mi < 2; ++mi)
#pragma unroll
      for (int r = 0; r < 4; ++r) {
        int row = w * 32 + mi * 16 + 4 * h8 + r;
        float inv = 1.f / lrow[mi][r];
#pragma unroll
        for (int dj = 0; dj < 4; ++dj)
          outh[((size_t)bidx * NTOK + q0 + row) * 512 + hh * 64 + dj * 16 + l16] =
              acc_o[mi][dj][r] * inv;
      }
  }
}

// ---------------- combine split-K flash partials -> T3 ----------------
__global__ __launch_bounds__(256) void flash_combine(const float* __restrict__ Opart,
                                                     const float* __restrict__ MLpart,
                                                     float* __restrict__ T3) {
  int bh = blockIdx.y;
  int row = blockIdx.x * 4 + (threadIdx.x >> 6);
  int d = threadIdx.x & 63;
  int qt = row >> 7, rowin = row & 127;
  float mstar = -1e30f;
#pragma unroll
  for (int s = 0; s < 8; ++s) {
    int p = (s * 32 + bh) * 2 + qt;
    mstar = fmaxf(mstar, MLpart[((size_t)p * 128 + rowin) * 2]);
  }
  float L = 0.f, O = 0.f;
#pragma unroll
  for (int s = 0; s < 8; ++s) {
    int p = (s * 32 + bh) * 2 + qt;
    float ms = MLpart[((size_t)p * 128 + rowin) * 2];
    float ls = MLpart[((size_t)p * 128 + rowin) * 2 + 1];
    float e = __expf(ms - mstar);
    L += ls * e;
    O += Opart[(size_t)p * 8192 + rowin * 64 + d] * e;
  }
  T3[((size_t)bh * 256 + row) * 64 + d] = O / L;
}

// ---------------- depthwise conv residual (bf16 v) into fp32 outh ------------
__global__ __launch_bounds__(256) void conv_add(const unsigned short* __restrict__ v,
                                                const float* __restrict__ cw,
                                                float* __restrict__ outh) {
  __shared__ float vt[96][64];
  __shared__ float wt[33];
  int z = blockIdx.x;
  int bh = z >> 7, n0 = (z & 127) * 64;
  int tid = threadIdx.x;
  if (tid < 33) wt[tid] = cw[(bh & 7) * 33 + tid];
  const unsigned short* vb = v + (size_t)bh * NTOK * 64;
  for (int f = tid; f < 768; f += 256) {
    int rowi = f >> 3, c8 = (f & 7) * 8;
    int rn = n0 - 16 + rowi;
    if (rn >= 0 && rn < NTOK) {
      u16x8 val = *(const u16x8*)(vb + (size_t)rn * 64 + c8);
#pragma unroll
      for (int i = 0; i < 8; ++i) vt[rowi][c8 + i] = b2f(val[i]);
    } else {
#pragma unroll
      for (int i = 0; i < 8; ++i) vt[rowi][c8 + i] = 0.f;
    }
  }
  __syncthreads();
  int dd = tid & 63, rg = tid >> 6;
  int bidx = bh >> 3, hh = bh & 7;
  for (int rr = 0; rr < 16; ++rr) {
    int rloc = rg * 16 + rr;
    float acc = 0.f;
#pragma unroll
    for (int kk = 0; kk < 33; ++kk) acc += wt[kk] * vt[rloc + kk][dd];
    size_t o = ((size_t)bidx * NTOK + n0 + rloc) * 512 + hh * 64 + dd;
    outh[o] += acc;
  }
}

extern "C" void kernel_launch(void* const* d_in, const int* in_sizes, int n_in,
                              void* d_out, int out_size, void* d_ws, size_t ws_size,
                              hipStream_t stream) {
  const float* x = (const float*)d_in[0];
  const float* gamma = (const float*)d_in[1];
  const float* beta = (const float*)d_in[2];
  const float* w_qkv = (const float*)d_in[3];
  const float* w_out = (const float*)d_in[4];
  const float* b_out = (const float*)d_in[5];
  const float* conv_w = (const float*)d_in[6];
  float* out = (float*)d_out;
  float* ws = (float*)d_ws;
  (void)ws_size; (void)in_sizes; (void)n_in; (void)out_size;

  // Workspace layout (floats). Total 51,773,440 floats = 207 MiB.
  float* A0 = ws;                          // 16,777,216: xn -> pinv smalls -> outh
  float* Breg = ws + 16777216;             // 8,388,608: xnb -> Opart/MLpart
  unsigned short* qb = (unsigned short*)(ws + 25165824);
  unsigned short* kb = (unsigned short*)(ws + 33554432);
  unsigned short* vb = (unsigned short*)(ws + 41943040);
  float* Fs = ws + 50331648;               // smalls that must survive into flash B

  float* xn = A0;
  unsigned int* xnb = (unsigned int*)Breg;
  float* Opart = Breg;                     // 4,194,304 (after xnb dead)
  float* MLpart = Breg + 4194304;          // 131,072
  // A-region tenants (valid after pool_x, dead before flash B writes outh)
  float* X2 = A0;
  float* z0 = A0 + 2097152;
  float* z1 = A0 + 4194304;
  float* XZ = A0 + 6291456;
  float* TA = A0 + 8388608;
  float* TB = A0 + 10485760;
  float* ql = A0 + 12582912;
  float* kl = A0 + 13107200;
  float* T3 = A0 + 13631488;
  float* W2 = A0 + 14155776;
  unsigned short* wqkvT = (unsigned short*)(A0 + 14680064);  // 786,432 u16
  float* sc = A0 + 15073280;
  float* outh = A0;
  // F-region
  float* xl = Fs;                                            // 524,288
  unsigned short* qlb = (unsigned short*)(Fs + 524288);      // 524,288 u16
  unsigned short* klb = (unsigned short*)(Fs + 786432);
  unsigned short* W2b = (unsigned short*)(Fs + 1048576);
  unsigned short* woutT = (unsigned short*)(Fs + 1310720);   // 262,144 u16

  // 1. LayerNorm -> xn fp32 + xnb bf16
  ln_kernel<<<TOT, 256, 0, stream>>>(x, gamma, beta, xn, xnb);
  // 2. pool xn -> xl (fp32-exact landmark path; pooling commutes with proj)
  pool_x<<<1024, 256, 0, stream>>>(xn, xl);
  // 3. weight transposes/cvt (A-region free after pool_x)
  transpose_cvt<<<dim3(48, 16), 256, 0, stream>>>(w_qkv, wqkvT, 512, 1536);
  transpose_cvt<<<dim3(16, 16), 256, 0, stream>>>(w_out, woutT, 512, 512);
  // 4. qkv projection bf16 MFMA, scatter q(*0.125)/k/v bf16
  gemm_mfma<0><<<dim3(12, 256), 256, 0, stream>>>(xnb, wqkvT, 512, qb, kb, vb,
                                                  nullptr, nullptr, nullptr);
  // 5. ql/kl = xl @ Wq/Wk fp32 (exact)
  gemm_ab<<<dim3(16, 16, 1), 256, 0, stream>>>(xl, w_qkv, nullptr, 512, 512, 1536, 0,
                                               0, 0, 0, 1.f, 0.f, 5, ql, kl);
  cvt_bf16<<<4096, 256, 0, stream>>>(ql, qlb, 1048576);  // ql+kl contiguous -> qlb+klb
  // 6. sim2 -> attn2 (fp32)
  gemm_abt<<<dim3(4, 4, BH), 256, 0, stream>>>(ql, kl, X2, 64, 64, 64, 256,
                                               16384, 16384, 65536);
  softmax_rows256<<<BH * NM, 256, 0, stream>>>(X2);
  // 7. pinv init + Newton-Schulz (fp32)
  init_scalars<<<1, 64, 0, stream>>>(sc);
  rowsum_max<<<BH * NM, 256, 0, stream>>>(X2, sc);
  colsum_max<<<BH * NM, 256, 0, stream>>>(X2, sc);
  transpose_scale<<<BH * NM, 256, 0, stream>>>(X2, sc, z0);
  float* zc = z0;
  float* zn = z1;
  for (int it = 0; it < 6; ++it) {
    gemm_ab<<<dim3(4, 4, BH), 256, 0, stream>>>(X2, zc, XZ, 256, 256, 256, 256,
                                                65536, 65536, 65536, 1.f, 0.f, 0, nullptr, nullptr);
    neg7_kernel<<<8192, 256, 0, stream>>>(XZ, TA);
    gemm_ab<<<dim3(4, 4, BH), 256, 0, stream>>>(XZ, TA, TB, 256, 256, 256, 256,
                                                65536, 65536, 65536, -1.f, 15.f, 0, nullptr, nullptr);
    gemm_ab<<<dim3(4, 4, BH), 256, 0, stream>>>(XZ, TB, TA, 256, 256, 256, 256,
                                                65536, 65536, 65536, -1.f, 13.f, 0, nullptr, nullptr);
    gemm_ab<<<dim3(4, 4, BH), 256, 0, stream>>>(zc, TA, zn, 256, 256, 256, 256,
                                                65536, 65536, 65536, 0.25f, 0.f, 0, nullptr, nullptr);
    float* t = zc; zc = zn; zn = t;
  }
  // 8. flash A (split-K=8): T3 = softmax(ql k^T) v
  flash_mfma<<<dim3(2, 32, 8), 256, 0, stream>>>(qlb, kb, vb, 16384, 524288,
                                                 1024, 16, 0, Opart, MLpart, nullptr);
  flash_combine<<<dim3(64, 32), 256, 0, stream>>>(Opart, MLpart, T3);
  // 9. W2 = pinv(attn2) @ T3 (fp32), then bf16
  gemm_ab<<<dim3(1, 4, BH), 256, 0, stream>>>(zc, T3, W2, 256, 256, 64, 64,
                                              65536, 16384, 16384, 1.f, 0.f, 0, nullptr, nullptr);
  cvt_bf16<<<2048, 256, 0, stream>>>(W2, W2b, 524288);
  // 10. flash B: outh = softmax(q kl^T) @ W2, scattered [b,n,h*64]
  flash_mfma<<<dim3(64, 32, 1), 256, 0, stream>>>(qb, klb, W2b, 524288, 16384,
                                                  0, 4, 1, nullptr, nullptr, outh);
  // 11. conv residual
  conv_add<<<BH * (NTOK / 64), 256, 0, stream>>>(vb, conv_w, outh);
  // 12. out = x + outh @ w_out + b_out (MFMA, fp32 A cvt on stage)
  gemm_mfma<1><<<dim3(4, 256), 256, 0, stream>>>(outh, woutT, 512, nullptr, nullptr,
                                                 nullptr, out, b_out, x);
}

// Round 5
// 1109.899 us; speedup vs baseline: 2.7649x; 1.0746x over previous
//
#include <hip/hip_runtime.h>

#define NTOK 8192
#define TOT 32768
#define DMODEL 512
#define NM 256
#define BH 32

typedef __attribute__((ext_vector_type(8))) short bf16x8;
typedef __attribute__((ext_vector_type(8))) unsigned short u16x8;
typedef __attribute__((ext_vector_type(4))) float f32x4;

__device__ __forceinline__ unsigned short f2b(float f) {
  unsigned u = __float_as_uint(f);
  return (unsigned short)((u + 0x7fffu + ((u >> 16) & 1u)) >> 16);
}
__device__ __forceinline__ float b2f(unsigned short h) {
  return __uint_as_float((unsigned)h << 16);
}
__device__ __forceinline__ f32x4 mfma16(bf16x8 a, bf16x8 b, f32x4 c) {
  return __builtin_amdgcn_mfma_f32_16x16x32_bf16(a, b, c, 0, 0, 0);
}
__device__ __forceinline__ float wave_sum(float v) {
#pragma unroll
  for (int o = 32; o; o >>= 1) v += __shfl_xor(v, o, 64);
  return v;
}
__device__ __forceinline__ float wave_max(float v) {
#pragma unroll
  for (int o = 32; o; o >>= 1) v = fmaxf(v, __shfl_xor(v, o, 64));
  return v;
}

// ---------------- LayerNorm: fp32 out + bf16 out ----------------
__global__ __launch_bounds__(256) void ln_kernel(const float* __restrict__ x,
                                                 const float* __restrict__ g,
                                                 const float* __restrict__ b,
                                                 float* __restrict__ xn,
                                                 unsigned int* __restrict__ xnb) {
  __shared__ float r1[4], r2[4];
  size_t row = blockIdx.x;
  int tid = threadIdx.x;
  float2 v = reinterpret_cast<const float2*>(x + row * DMODEL)[tid];
  float s = wave_sum(v.x + v.y);
  float ss = wave_sum(v.x * v.x + v.y * v.y);
  int lane = tid & 63, wid = tid >> 6;
  if (!lane) { r1[wid] = s; r2[wid] = ss; }
  __syncthreads();
  s = r1[0] + r1[1] + r1[2] + r1[3];
  ss = r2[0] + r2[1] + r2[2] + r2[3];
  float mu = s * (1.f / DMODEL);
  float var = ss * (1.f / DMODEL) - mu * mu;
  float rstd = rsqrtf(var + 1e-5f);
  float2 gg = reinterpret_cast<const float2*>(g)[tid];
  float2 bb = reinterpret_cast<const float2*>(b)[tid];
  float2 o;
  o.x = (v.x - mu) * rstd * gg.x + bb.x;
  o.y = (v.y - mu) * rstd * gg.y + bb.y;
  reinterpret_cast<float2*>(xn + row * DMODEL)[tid] = o;
  xnb[row * 256 + tid] = (unsigned)f2b(o.x) | ((unsigned)f2b(o.y) << 16);
}

// ---------------- pool xn over 32-token windows -> xl ----------------
__global__ __launch_bounds__(256) void pool_x(const float* __restrict__ xn,
                                              float* __restrict__ xl) {
  int b = blockIdx.x >> 8, m = blockIdx.x & 255;
  int t = threadIdx.x;
  const float2* src = (const float2*)(xn + ((size_t)b * NTOK + m * 32) * DMODEL);
  float sx = 0.f, sy = 0.f;
#pragma unroll 8
  for (int j = 0; j < 32; ++j) { float2 v = src[j * 256 + t]; sx += v.x; sy += v.y; }
  float2 o; o.x = sx * (1.f / 32.f); o.y = sy * (1.f / 32.f);
  ((float2*)(xl + ((size_t)b * 256 + m) * DMODEL))[t] = o;
}

// ---------------- transpose + cvt fp32[K][N] -> bf16[N][K] ----------------
__global__ __launch_bounds__(256) void transpose_cvt(const float* __restrict__ in,
                                                     unsigned short* __restrict__ outp,
                                                     int K, int N) {
  __shared__ float t[32][33];
  int k0 = blockIdx.y * 32, n0 = blockIdx.x * 32;
  int tx = threadIdx.x & 31, ty = threadIdx.x >> 5;
#pragma unroll
  for (int i = 0; i < 32; i += 8)
    t[ty + i][tx] = in[(size_t)(k0 + ty + i) * N + n0 + tx];
  __syncthreads();
#pragma unroll
  for (int i = 0; i < 32; i += 8)
    outp[(size_t)(n0 + ty + i) * K + k0 + tx] = f2b(t[tx][ty + i]);
}

// ---------------- MFMA GEMM NT: C = A[M,Kd] @ Bt[N,Kd]^T ----------------
// EPI 0: A bf16, scatter qkv (q*0.125) to bf16 [bh][n][64]
// EPI 1: A fp32 (cvt on stage), Cf = AB + bias + resid  (out projection)
template <int EPI>
__global__ __launch_bounds__(256) void gemm_mfma(const void* __restrict__ Ap,
                                                 const unsigned short* __restrict__ Bt,
                                                 int Kd,
                                                 unsigned short* __restrict__ qo,
                                                 unsigned short* __restrict__ ko,
                                                 unsigned short* __restrict__ vo,
                                                 float* __restrict__ Cf,
                                                 const float* __restrict__ bias,
                                                 const float* __restrict__ resid) {
  __shared__ __align__(16) unsigned short As[128][72];
  __shared__ __align__(16) unsigned short Bs[128][72];
  const int tid = threadIdx.x;
  const int l16 = tid & 15, h8 = (tid & 63) >> 4, w = tid >> 6;
  const int m0 = blockIdx.y * 128, n0 = blockIdx.x * 128;
  const int wr = (w >> 1) * 64, wc = (w & 1) * 64;
  const int srow = tid >> 1, sc0 = (tid & 1) * 32;
  f32x4 acc[4][4] = {};
  for (int k0 = 0; k0 < Kd; k0 += 64) {
    if (EPI == 0) {
      const unsigned short* Ab = (const unsigned short*)Ap + (size_t)(m0 + srow) * Kd + k0 + sc0;
#pragma unroll
      for (int i = 0; i < 4; ++i)
        *(u16x8*)&As[srow][sc0 + 8 * i] = *(const u16x8*)(Ab + 8 * i);
    } else {
      const float* Af = (const float*)Ap + (size_t)(m0 + srow) * Kd + k0 + sc0;
#pragma unroll
      for (int i = 0; i < 4; ++i) {
        float4 f0 = *(const float4*)(Af + 8 * i);
        float4 f1 = *(const float4*)(Af + 8 * i + 4);
        u16x8 u;
        u[0] = f2b(f0.x); u[1] = f2b(f0.y); u[2] = f2b(f0.z); u[3] = f2b(f0.w);
        u[4] = f2b(f1.x); u[5] = f2b(f1.y); u[6] = f2b(f1.z); u[7] = f2b(f1.w);
        *(u16x8*)&As[srow][sc0 + 8 * i] = u;
      }
    }
    const unsigned short* Bb = Bt + (size_t)(n0 + srow) * Kd + k0 + sc0;
#pragma unroll
    for (int i = 0; i < 4; ++i)
      *(u16x8*)&Bs[srow][sc0 + 8 * i] = *(const u16x8*)(Bb + 8 * i);
    __syncthreads();
#pragma unroll
    for (int ks = 0; ks < 2; ++ks) {
      bf16x8 a[4], b[4];
#pragma unroll
      for (int mi = 0; mi < 4; ++mi)
        a[mi] = *(const bf16x8*)&As[wr + mi * 16 + l16][ks * 32 + h8 * 8];
#pragma unroll
      for (int nj = 0; nj < 4; ++nj)
        b[nj] = *(const bf16x8*)&Bs[wc + nj * 16 + l16][ks * 32 + h8 * 8];
#pragma unroll
      for (int mi = 0; mi < 4; ++mi)
#pragma unroll
        for (int nj = 0; nj < 4; ++nj)
          acc[mi][nj] = mfma16(a[mi], b[nj], acc[mi][nj]);
    }
    __syncthreads();
  }
#pragma unroll
  for (int mi = 0; mi < 4; ++mi)
#pragma unroll
    for (int nj = 0; nj < 4; ++nj)
#pragma unroll
      for (int r = 0; r < 4; ++r) {
        int grow = m0 + wr + mi * 16 + 4 * h8 + r;
        int gcol = n0 + wc + nj * 16 + l16;
        float val = acc[mi][nj][r];
        if (EPI == 0) {
          int which = gcol >> 9, hh = (gcol >> 6) & 7, dd = gcol & 63;
          int bidx = grow >> 13, nn = grow & 8191;
          if (which == 0) val *= 0.125f;
          unsigned short* dst = which == 0 ? qo : (which == 1 ? ko : vo);
          dst[(((size_t)(bidx * 8 + hh)) * NTOK + nn) * 64 + dd] = f2b(val);
        } else {
          Cf[(size_t)grow * 512 + gcol] = val + bias[gcol] + resid[(size_t)grow * 512 + gcol];
        }
      }
}

// ---------------- fp32 GEMM (landmark path), epi 5 / 7 ----------------
// epi 5: ql/kl scatter fp32 + bf16 (q scaled 0.125)
// epi 7: write bf16 only to d16 ([bz][256][64])
__global__ __launch_bounds__(256)
void gemm_ab(const float* __restrict__ A, const float* __restrict__ Bm,
             int Kdim, int lda, int ldb,
             long long sA, long long sB, int epi,
             float* __restrict__ qlp, float* __restrict__ klp,
             unsigned short* __restrict__ q16, unsigned short* __restrict__ k16) {
  __shared__ float As[16][64], Bs[16][64];
  int bz = blockIdx.z;
  A += sA * bz; Bm += sB * bz;
  int n0 = blockIdx.x * 64, m0 = blockIdx.y * 64;
  int tid = threadIdx.x, tx = tid & 15, ty = tid >> 4;
  int am = tid >> 2, akg = tid & 3, bk = tid >> 4, bng = tid & 15;
  const float* Aload = A + (size_t)(m0 + am) * lda + akg * 4;
  const float* Bload = Bm + (size_t)bk * ldb + n0 + bng * 4;
  float acc[4][4] = {};
  for (int k0 = 0; k0 < Kdim; k0 += 16) {
    float4 av = *reinterpret_cast<const float4*>(Aload + k0);
    float4 bv = *reinterpret_cast<const float4*>(Bload + (size_t)k0 * ldb);
    __syncthreads();
    As[akg * 4 + 0][am] = av.x; As[akg * 4 + 1][am] = av.y;
    As[akg * 4 + 2][am] = av.z; As[akg * 4 + 3][am] = av.w;
    *reinterpret_cast<float4*>(&Bs[bk][bng * 4]) = bv;
    __syncthreads();
#pragma unroll
    for (int kk = 0; kk < 16; ++kk) {
      float4 bq = *reinterpret_cast<const float4*>(&Bs[kk][tx * 4]);
      float a0 = As[kk][ty * 4 + 0], a1 = As[kk][ty * 4 + 1];
      float a2 = As[kk][ty * 4 + 2], a3 = As[kk][ty * 4 + 3];
      acc[0][0] += a0 * bq.x; acc[0][1] += a0 * bq.y; acc[0][2] += a0 * bq.z; acc[0][3] += a0 * bq.w;
      acc[1][0] += a1 * bq.x; acc[1][1] += a1 * bq.y; acc[1][2] += a1 * bq.z; acc[1][3] += a1 * bq.w;
      acc[2][0] += a2 * bq.x; acc[2][1] += a2 * bq.y; acc[2][2] += a2 * bq.z; acc[2][3] += a2 * bq.w;
      acc[3][0] += a3 * bq.x; acc[3][1] += a3 * bq.y; acc[3][2] += a3 * bq.z; acc[3][3] += a3 * bq.w;
    }
  }
  if (epi == 5) {
#pragma unroll
    for (int i = 0; i < 4; ++i) {
      int gr = m0 + ty * 4 + i;
      int bidx = gr >> 8, nn = gr & 255;
#pragma unroll
      for (int j = 0; j < 4; ++j) {
        int gc = n0 + tx * 4 + j;
        int which = gc >> 9, hh = (gc >> 6) & 7, dd = gc & 63;
        float val = acc[i][j];
        if (which == 0) val *= 0.125f;
        size_t idx = (((size_t)(bidx * 8 + hh)) * 256 + nn) * 64 + dd;
        float* dst = which == 0 ? qlp : klp;
        unsigned short* dst16 = which == 0 ? q16 : k16;
        dst[idx] = val;
        dst16[idx] = f2b(val);
      }
    }
  } else {  // epi 7
#pragma unroll
    for (int i = 0; i < 4; ++i) {
      int gr = m0 + ty * 4 + i;
#pragma unroll
      for (int j = 0; j < 4; ++j) {
        int gc = n0 + tx * 4 + j;
        q16[(size_t)bz * 16384 + (size_t)gr * 64 + gc] = f2b(acc[i][j]);
      }
    }
  }
}

// ---------------- fp32 NS GEMM 256x256x256, batched 32 ----------------
// C = alpha*(A@B) + diag*I + beta*E    (all [bz][256][256])
__global__ __launch_bounds__(256)
void ns_gemm(const float* __restrict__ A, const float* __restrict__ B,
             float* __restrict__ C, const float* __restrict__ E,
             float alpha, float diag, float beta) {
  __shared__ float As[32][68], Bs[32][68];
  int bz = blockIdx.z;
  A += (size_t)bz * 65536; B += (size_t)bz * 65536; C += (size_t)bz * 65536;
  const float* Eb = E ? E + (size_t)bz * 65536 : nullptr;
  int n0 = blockIdx.x * 64, m0 = blockIdx.y * 64;
  int tid = threadIdx.x, tx = tid & 15, ty = tid >> 4;
  int ar = tid >> 3, ac = tid & 7;
  int br = tid >> 4, bc = tid & 15;
  float acc[4][4] = {};
  for (int k0 = 0; k0 < 256; k0 += 32) {
    float4 a0 = *(const float4*)&A[(size_t)(m0 + ar) * 256 + k0 + ac * 4];
    float4 a1 = *(const float4*)&A[(size_t)(m0 + 32 + ar) * 256 + k0 + ac * 4];
    float4 b0 = *(const float4*)&B[(size_t)(k0 + br) * 256 + n0 + bc * 4];
    float4 b1 = *(const float4*)&B[(size_t)(k0 + 16 + br) * 256 + n0 + bc * 4];
    __syncthreads();
    As[ac * 4 + 0][ar] = a0.x; As[ac * 4 + 1][ar] = a0.y;
    As[ac * 4 + 2][ar] = a0.z; As[ac * 4 + 3][ar] = a0.w;
    As[ac * 4 + 0][32 + ar] = a1.x; As[ac * 4 + 1][32 + ar] = a1.y;
    As[ac * 4 + 2][32 + ar] = a1.z; As[ac * 4 + 3][32 + ar] = a1.w;
    *(float4*)&Bs[br][bc * 4] = b0;
    *(float4*)&Bs[16 + br][bc * 4] = b1;
    __syncthreads();
#pragma unroll
    for (int kk = 0; kk < 32; ++kk) {
      float4 a4 = *(const float4*)&As[kk][ty * 4];
      float4 b4 = *(const float4*)&Bs[kk][tx * 4];
      acc[0][0] += a4.x * b4.x; acc[0][1] += a4.x * b4.y; acc[0][2] += a4.x * b4.z; acc[0][3] += a4.x * b4.w;
      acc[1][0] += a4.y * b4.x; acc[1][1] += a4.y * b4.y; acc[1][2] += a4.y * b4.z; acc[1][3] += a4.y * b4.w;
      acc[2][0] += a4.z * b4.x; acc[2][1] += a4.z * b4.y; acc[2][2] += a4.z * b4.z; acc[2][3] += a4.z * b4.w;
      acc[3][0] += a4.w * b4.x; acc[3][1] += a4.w * b4.y; acc[3][2] += a4.w * b4.z; acc[3][3] += a4.w * b4.w;
    }
  }
  int gc0 = n0 + tx * 4;
#pragma unroll
  for (int i = 0; i < 4; ++i) {
    int gr = m0 + ty * 4 + i;
    float4 r;
    r.x = alpha * acc[i][0]; r.y = alpha * acc[i][1];
    r.z = alpha * acc[i][2]; r.w = alpha * acc[i][3];
    if (Eb) {
      float4 e = *(const float4*)&Eb[(size_t)gr * 256 + gc0];
      r.x += beta * e.x; r.y += beta * e.y; r.z += beta * e.z; r.w += beta * e.w;
    }
    if (gr >= gc0 && gr < gc0 + 4) ((float*)&r)[gr - gc0] += diag;
    *(float4*)&C[(size_t)gr * 256 + gc0] = r;
  }
}

// ---------------- GEMM C = A[M,64] @ B[N,64]^T (sim2) ----------------
__global__ __launch_bounds__(256)
void gemm_abt(const float* __restrict__ A, const float* __restrict__ Bm,
              float* __restrict__ C, int Kdim, int lda, int ldb, int ldc,
              long long sA, long long sB, long long sC) {
  __shared__ float As[16][64], Bs[16][64];
  int bz = blockIdx.z;
  A += sA * bz; Bm += sB * bz; C += sC * bz;
  int n0 = blockIdx.x * 64, m0 = blockIdx.y * 64;
  int tid = threadIdx.x, tx = tid & 15, ty = tid >> 4;
  int am = tid >> 2, akg = tid & 3;
  const float* Aload = A + (size_t)(m0 + am) * lda + akg * 4;
  const float* Bload = Bm + (size_t)(n0 + am) * ldb + akg * 4;
  float acc[4][4] = {};
  for (int k0 = 0; k0 < Kdim; k0 += 16) {
    float4 av = *reinterpret_cast<const float4*>(Aload + k0);
    float4 bv = *reinterpret_cast<const float4*>(Bload + k0);
    __syncthreads();
    As[akg * 4 + 0][am] = av.x; As[akg * 4 + 1][am] = av.y;
    As[akg * 4 + 2][am] = av.z; As[akg * 4 + 3][am] = av.w;
    Bs[akg * 4 + 0][am] = bv.x; Bs[akg * 4 + 1][am] = bv.y;
    Bs[akg * 4 + 2][am] = bv.z; Bs[akg * 4 + 3][am] = bv.w;
    __syncthreads();
#pragma unroll
    for (int kk = 0; kk < 16; ++kk) {
      float4 bq = *reinterpret_cast<const float4*>(&Bs[kk][tx * 4]);
      float a0 = As[kk][ty * 4 + 0], a1 = As[kk][ty * 4 + 1];
      float a2 = As[kk][ty * 4 + 2], a3 = As[kk][ty * 4 + 3];
      acc[0][0] += a0 * bq.x; acc[0][1] += a0 * bq.y; acc[0][2] += a0 * bq.z; acc[0][3] += a0 * bq.w;
      acc[1][0] += a1 * bq.x; acc[1][1] += a1 * bq.y; acc[1][2] += a1 * bq.z; acc[1][3] += a1 * bq.w;
      acc[2][0] += a2 * bq.x; acc[2][1] += a2 * bq.y; acc[2][2] += a2 * bq.z; acc[2][3] += a2 * bq.w;
      acc[3][0] += a3 * bq.x; acc[3][1] += a3 * bq.y; acc[3][2] += a3 * bq.z; acc[3][3] += a3 * bq.w;
    }
  }
#pragma unroll
  for (int i = 0; i < 4; ++i) {
    int gr = m0 + ty * 4 + i;
#pragma unroll
    for (int j = 0; j < 4; ++j)
      C[(size_t)gr * ldc + n0 + tx * 4 + j] = acc[i][j];
  }
}

// ---------------- row softmax (256 cols) ----------------
__global__ __launch_bounds__(256) void softmax_rows256(float* __restrict__ buf) {
  __shared__ float red[4];
  size_t row = blockIdx.x;
  float* r = buf + row * 256;
  int tid = threadIdx.x, lane = tid & 63, wid = tid >> 6;
  float v = r[tid];
  float mx = wave_max(v);
  if (!lane) red[wid] = mx;
  __syncthreads();
  mx = fmaxf(fmaxf(red[0], red[1]), fmaxf(red[2], red[3]));
  __syncthreads();
  float e = expf(v - mx);
  float s = wave_sum(e);
  if (!lane) red[wid] = s;
  __syncthreads();
  s = red[0] + red[1] + red[2] + red[3];
  r[tid] = e / s;
}

// ---------------- pinv scalars: max row-sum and max col-sum ----------------
__global__ void init_scalars(float* sc) { if (threadIdx.x < 2) sc[threadIdx.x] = 0.f; }

__global__ __launch_bounds__(256) void rowcol_max(const float* __restrict__ a2,
                                                  float* __restrict__ sc) {
  __shared__ float rowpart[256][4];
  __shared__ float red[4];
  int bh = blockIdx.x;
  int tid = threadIdx.x, lane = tid & 63, w = tid >> 6;
  const float* M = a2 + (size_t)bh * 65536;
  float colacc = 0.f;
  for (int r = 0; r < 256; ++r) {
    float v = M[r * 256 + tid];
    colacc += v;
    float rs = wave_sum(v);
    if (!lane) rowpart[r][w] = rs;
  }
  __syncthreads();
  float rsum = rowpart[tid][0] + rowpart[tid][1] + rowpart[tid][2] + rowpart[tid][3];
  float rm = wave_max(rsum);
  if (!lane) red[w] = rm;
  __syncthreads();
  if (tid == 0) {
    float m = fmaxf(fmaxf(red[0], red[1]), fmaxf(red[2], red[3]));
    atomicMax(reinterpret_cast<int*>(sc), __float_as_int(m));  // max row-sum
  }
  __syncthreads();
  float cm = wave_max(colacc);
  if (!lane) red[w] = cm;
  __syncthreads();
  if (tid == 0) {
    float m = fmaxf(fmaxf(red[0], red[1]), fmaxf(red[2], red[3]));
    atomicMax(reinterpret_cast<int*>(sc) + 1, __float_as_int(m));  // max col-sum
  }
}

// ---------------- tiled transpose+scale: z = a2^T / (sc0*sc1) ----------------
__global__ __launch_bounds__(256) void transpose_scale(const float* __restrict__ a2,
                                                       const float* __restrict__ sc,
                                                       float* __restrict__ z) {
  __shared__ float t[64][65];
  int bh = blockIdx.z;
  int i0 = blockIdx.y * 64, j0 = blockIdx.x * 64;
  const float* M = a2 + (size_t)bh * 65536;
  float* Z = z + (size_t)bh * 65536;
  int tid = threadIdx.x, tx = tid & 15, ty = tid >> 4;
#pragma unroll
  for (int rr = 0; rr < 64; rr += 16) {
    float4 v = *(const float4*)&M[(size_t)(i0 + rr + ty) * 256 + j0 + tx * 4];
    t[rr + ty][tx * 4 + 0] = v.x; t[rr + ty][tx * 4 + 1] = v.y;
    t[rr + ty][tx * 4 + 2] = v.z; t[rr + ty][tx * 4 + 3] = v.w;
  }
  __syncthreads();
  float inv = 1.f / (sc[0] * sc[1]);
#pragma unroll
  for (int rr = 0; rr < 64; rr += 16) {
    float4 o;
    o.x = t[tx * 4 + 0][rr + ty] * inv;
    o.y = t[tx * 4 + 1][rr + ty] * inv;
    o.z = t[tx * 4 + 2][rr + ty] * inv;
    o.w = t[tx * 4 + 3][rr + ty] * inv;
    *(float4*)&Z[(size_t)(j0 + rr + ty) * 256 + i0 + tx * 4] = o;
  }
}

// ---------------- MFMA flash: O = softmax(Q K^T) V, 128 q-rows/block ----------
__global__ __launch_bounds__(256) void flash_mfma(
    const unsigned short* __restrict__ Q, const unsigned short* __restrict__ Kp,
    const unsigned short* __restrict__ Vp, long long sQ, long long sK,
    int kps, int nkt, int mode,
    float* __restrict__ Opart, float* __restrict__ MLpart, float* __restrict__ outh) {
  __shared__ __align__(16) unsigned short Qt[128][72];
  __shared__ __align__(16) unsigned short Kt[64][72];
  __shared__ __align__(16) unsigned short Vt[64][72];
  __shared__ __align__(16) unsigned short Pb[128][72];
  const int tid = threadIdx.x;
  const int l16 = tid & 15, h8 = (tid & 63) >> 4, w = tid >> 6;
  const int bh = blockIdx.y, s = blockIdx.z, qt = blockIdx.x;
  const int q0 = qt * 128;
  const unsigned short* Qb = Q + (size_t)bh * sQ + (size_t)q0 * 64;
  const unsigned short* Kb = Kp + (size_t)bh * sK + (size_t)s * kps * 64;
  const unsigned short* Vb = Vp + (size_t)bh * sK + (size_t)s * kps * 64;
  {
    int row = tid >> 1, c0 = (tid & 1) * 32;
#pragma unroll
    for (int i = 0; i < 4; ++i)
      *(u16x8*)&Qt[row][c0 + 8 * i] = *(const u16x8*)(Qb + (size_t)row * 64 + c0 + 8 * i);
  }
  f32x4 acc_o[2][4] = {};
  float mrow[2][4], lrow[2][4];
#pragma unroll
  for (int mi = 0; mi < 2; ++mi)
#pragma unroll
    for (int r = 0; r < 4; ++r) { mrow[mi][r] = -1e30f; lrow[mi][r] = 0.f; }
  for (int kt = 0; kt < nkt; ++kt) {
    {
      int row = tid >> 2, c0 = (tid & 3) * 16;
      *(u16x8*)&Kt[row][c0] = *(const u16x8*)(Kb + ((size_t)(kt * 64 + row)) * 64 + c0);
      *(u16x8*)&Kt[row][c0 + 8] = *(const u16x8*)(Kb + ((size_t)(kt * 64 + row)) * 64 + c0 + 8);
      int key = tid & 63, d0 = w * 16;
      u16x8 v0 = *(const u16x8*)(Vb + ((size_t)(kt * 64 + key)) * 64 + d0);
      u16x8 v1 = *(const u16x8*)(Vb + ((size_t)(kt * 64 + key)) * 64 + d0 + 8);
#pragma unroll
      for (int i = 0; i < 8; ++i) { Vt[d0 + i][key] = v0[i]; Vt[d0 + 8 + i][key] = v1[i]; }
    }
    __syncthreads();
    f32x4 accs[2][4] = {};
#pragma unroll
    for (int ks = 0; ks < 2; ++ks) {
      bf16x8 a[2], b[4];
      a[0] = *(const bf16x8*)&Qt[w * 32 + l16][ks * 32 + h8 * 8];
      a[1] = *(const bf16x8*)&Qt[w * 32 + 16 + l16][ks * 32 + h8 * 8];
#pragma unroll
      for (int nj = 0; nj < 4; ++nj)
        b[nj] = *(const bf16x8*)&Kt[nj * 16 + l16][ks * 32 + h8 * 8];
#pragma unroll
      for (int mi = 0; mi < 2; ++mi)
#pragma unroll
        for (int nj = 0; nj < 4; ++nj)
          accs[mi][nj] = mfma16(a[mi], b[nj], accs[mi][nj]);
    }
#pragma unroll
    for (int mi = 0; mi < 2; ++mi)
#pragma unroll
      for (int r = 0; r < 4; ++r) {
        float mx = fmaxf(fmaxf(accs[mi][0][r], accs[mi][1][r]),
                         fmaxf(accs[mi][2][r], accs[mi][3][r]));
#pragma unroll
        for (int off = 8; off; off >>= 1) mx = fmaxf(mx, __shfl_xor(mx, off, 64));
        float mn = fmaxf(mrow[mi][r], mx);
        float scf = __expf(mrow[mi][r] - mn);
        float ps = 0.f;
#pragma unroll
        for (int nj = 0; nj < 4; ++nj) {
          float p = __expf(accs[mi][nj][r] - mn);
          accs[mi][nj][r] = p;
          ps += p;
        }
#pragma unroll
        for (int off = 8; off; off >>= 1) ps += __shfl_xor(ps, off, 64);
        lrow[mi][r] = lrow[mi][r] * scf + ps;
        mrow[mi][r] = mn;
#pragma unroll
        for (int dj = 0; dj < 4; ++dj) acc_o[mi][dj][r] *= scf;
        int prow = w * 32 + mi * 16 + 4 * h8 + r;
#pragma unroll
        for (int nj = 0; nj < 4; ++nj)
          Pb[prow][nj * 16 + l16] = f2b(accs[mi][nj][r]);
      }
    __syncthreads();
#pragma unroll
    for (int ks = 0; ks < 2; ++ks) {
      bf16x8 pa[2], vb[4];
      pa[0] = *(const bf16x8*)&Pb[w * 32 + l16][ks * 32 + h8 * 8];
      pa[1] = *(const bf16x8*)&Pb[w * 32 + 16 + l16][ks * 32 + h8 * 8];
#pragma unroll
      for (int dj = 0; dj < 4; ++dj)
        vb[dj] = *(const bf16x8*)&Vt[dj * 16 + l16][ks * 32 + h8 * 8];
#pragma unroll
      for (int mi = 0; mi < 2; ++mi)
#pragma unroll
        for (int dj = 0; dj < 4; ++dj)
          acc_o[mi][dj] = mfma16(pa[mi], vb[dj], acc_o[mi][dj]);
    }
    __syncthreads();
  }
  if (mode == 0) {
    int p = (s * 32 + bh) * 2 + qt;
    float* Ob = Opart + (size_t)p * 8192;
#pragma unroll
    for (int mi = 0; mi < 2; ++mi)
#pragma unroll
      for (int r = 0; r < 4; ++r) {
        int row = w * 32 + mi * 16 + 4 * h8 + r;
#pragma unroll
        for (int dj = 0; dj < 4; ++dj)
          Ob[(size_t)row * 64 + dj * 16 + l16] = acc_o[mi][dj][r];
        if (l16 == 0) {
          MLpart[((size_t)p * 128 + row) * 2] = mrow[mi][r];
          MLpart[((size_t)p * 128 + row) * 2 + 1] = lrow[mi][r];
        }
      }
  } else {
    int bidx = bh >> 3, hh = bh & 7;
#pragma unroll
    for (int mi = 0; mi < 2; ++mi)
#pragma unroll
      for (int r = 0; r < 4; ++r) {
        int row = w * 32 + mi * 16 + 4 * h8 + r;
        float inv = 1.f / lrow[mi][r];
#pragma unroll
        for (int dj = 0; dj < 4; ++dj)
          outh[((size_t)bidx * NTOK + q0 + row) * 512 + hh * 64 + dj * 16 + l16] =
              acc_o[mi][dj][r] * inv;
      }
  }
}

// ---------------- combine split-K flash partials -> T3 ----------------
__global__ __launch_bounds__(256) void flash_combine(const float* __restrict__ Opart,
                                                     const float* __restrict__ MLpart,
                                                     float* __restrict__ T3) {
  int bh = blockIdx.y;
  int row = blockIdx.x * 4 + (threadIdx.x >> 6);
  int d = threadIdx.x & 63;
  int qt = row >> 7, rowin = row & 127;
  float mstar = -1e30f;
#pragma unroll
  for (int s = 0; s < 8; ++s) {
    int p = (s * 32 + bh) * 2 + qt;
    mstar = fmaxf(mstar, MLpart[((size_t)p * 128 + rowin) * 2]);
  }
  float L = 0.f, O = 0.f;
#pragma unroll
  for (int s = 0; s < 8; ++s) {
    int p = (s * 32 + bh) * 2 + qt;
    float ms = MLpart[((size_t)p * 128 + rowin) * 2];
    float ls = MLpart[((size_t)p * 128 + rowin) * 2 + 1];
    float e = __expf(ms - mstar);
    L += ls * e;
    O += Opart[(size_t)p * 8192 + rowin * 64 + d] * e;
  }
  T3[((size_t)bh * 256 + row) * 64 + d] = O / L;
}

// ---------------- depthwise conv residual (bf16 v) into fp32 outh ------------
__global__ __launch_bounds__(256) void conv_add(const unsigned short* __restrict__ v,
                                                const float* __restrict__ cw,
                                                float* __restrict__ outh) {
  __shared__ float vt[96][64];
  __shared__ float wt[33];
  int z = blockIdx.x;
  int bh = z >> 7, n0 = (z & 127) * 64;
  int tid = threadIdx.x;
  if (tid < 33) wt[tid] = cw[(bh & 7) * 33 + tid];
  const unsigned short* vb = v + (size_t)bh * NTOK * 64;
  for (int f = tid; f < 768; f += 256) {
    int rowi = f >> 3, c8 = (f & 7) * 8;
    int rn = n0 - 16 + rowi;
    if (rn >= 0 && rn < NTOK) {
      u16x8 val = *(const u16x8*)(vb + (size_t)rn * 64 + c8);
#pragma unroll
      for (int i = 0; i < 8; ++i) vt[rowi][c8 + i] = b2f(val[i]);
    } else {
#pragma unroll
      for (int i = 0; i < 8; ++i) vt[rowi][c8 + i] = 0.f;
    }
  }
  __syncthreads();
  int dd = tid & 63, rg = tid >> 6;
  int bidx = bh >> 3, hh = bh & 7;
  for (int rr = 0; rr < 16; ++rr) {
    int rloc = rg * 16 + rr;
    float acc = 0.f;
#pragma unroll
    for (int kk = 0; kk < 33; ++kk) acc += wt[kk] * vt[rloc + kk][dd];
    size_t o = ((size_t)bidx * NTOK + n0 + rloc) * 512 + hh * 64 + dd;
    outh[o] += acc;
  }
}

extern "C" void kernel_launch(void* const* d_in, const int* in_sizes, int n_in,
                              void* d_out, int out_size, void* d_ws, size_t ws_size,
                              hipStream_t stream) {
  const float* x = (const float*)d_in[0];
  const float* gamma = (const float*)d_in[1];
  const float* beta = (const float*)d_in[2];
  const float* w_qkv = (const float*)d_in[3];
  const float* w_out = (const float*)d_in[4];
  const float* b_out = (const float*)d_in[5];
  const float* conv_w = (const float*)d_in[6];
  float* out = (float*)d_out;
  float* ws = (float*)d_ws;
  (void)ws_size; (void)in_sizes; (void)n_in; (void)out_size;

  float* A0 = ws;                          // xn -> pinv smalls -> outh
  float* Breg = ws + 16777216;             // xnb -> Opart/MLpart
  unsigned short* qb = (unsigned short*)(ws + 25165824);
  unsigned short* kb = (unsigned short*)(ws + 33554432);
  unsigned short* vb = (unsigned short*)(ws + 41943040);
  float* Fs = ws + 50331648;               // survives into flash B

  float* xn = A0;
  unsigned int* xnb = (unsigned int*)Breg;
  float* Opart = Breg;
  float* MLpart = Breg + 4194304;
  float* X2 = A0;
  float* z0 = A0 + 2097152;
  float* z1 = A0 + 4194304;
  float* Y  = A0 + 6291456;
  float* TA = A0 + 8388608;
  float* TB = A0 + 10485760;
  float* ql = A0 + 12582912;
  float* kl = A0 + 13107200;
  float* T3 = A0 + 13631488;
  unsigned short* wqkvT = (unsigned short*)(A0 + 14680064);
  float* sc = A0 + 15073280;
  float* outh = A0;
  float* xl = Fs;
  unsigned short* qlb = (unsigned short*)(Fs + 524288);
  unsigned short* klb = (unsigned short*)(Fs + 786432);
  unsigned short* W2b = (unsigned short*)(Fs + 1048576);
  unsigned short* woutT = (unsigned short*)(Fs + 1310720);

  // 1. LayerNorm -> xn fp32 + xnb bf16
  ln_kernel<<<TOT, 256, 0, stream>>>(x, gamma, beta, xn, xnb);
  // 2. pool xn -> xl (fp32-exact landmark path)
  pool_x<<<1024, 256, 0, stream>>>(xn, xl);
  // 3. weight transposes/cvt
  transpose_cvt<<<dim3(48, 16), 256, 0, stream>>>(w_qkv, wqkvT, 512, 1536);
  transpose_cvt<<<dim3(16, 16), 256, 0, stream>>>(w_out, woutT, 512, 512);
  // 4. qkv projection bf16 MFMA
  gemm_mfma<0><<<dim3(12, 256), 256, 0, stream>>>(xnb, wqkvT, 512, qb, kb, vb,
                                                  nullptr, nullptr, nullptr);
  // 5. ql/kl = xl @ Wq/Wk fp32 (+ bf16 copies fused)
  gemm_ab<<<dim3(16, 16, 1), 256, 0, stream>>>(xl, w_qkv, 512, 512, 1536, 0, 0,
                                               5, ql, kl, qlb, klb);
  // 6. sim2 -> attn2 (fp32)
  gemm_abt<<<dim3(4, 4, BH), 256, 0, stream>>>(ql, kl, X2, 64, 64, 64, 256,
                                               16384, 16384, 65536);
  softmax_rows256<<<BH * NM, 256, 0, stream>>>(X2);
  // 7. pinv scalars + z0 = attn2^T/(c*r)
  init_scalars<<<1, 64, 0, stream>>>(sc);
  rowcol_max<<<BH, 256, 0, stream>>>(X2, sc);
  transpose_scale<<<dim3(4, 4, BH), 256, 0, stream>>>(X2, sc, z0);
  // 8. Newton-Schulz: 4 fused GEMMs/iter, no elementwise kernels
  float* zc = z0;
  float* zn = z1;
  for (int it = 0; it < 6; ++it) {
    ns_gemm<<<dim3(4, 4, BH), 256, 0, stream>>>(X2, zc, Y, nullptr, 1.f, 0.f, 0.f);
    ns_gemm<<<dim3(4, 4, BH), 256, 0, stream>>>(Y, Y, TB, Y, 1.f, 15.f, -7.f);
    ns_gemm<<<dim3(4, 4, BH), 256, 0, stream>>>(Y, TB, TA, nullptr, -1.f, 13.f, 0.f);
    ns_gemm<<<dim3(4, 4, BH), 256, 0, stream>>>(zc, TA, zn, nullptr, 0.25f, 0.f, 0.f);
    float* t = zc; zc = zn; zn = t;
  }
  // 9. flash A (split-K=8): T3 = softmax(ql k^T) v
  flash_mfma<<<dim3(2, 32, 8), 256, 0, stream>>>(qlb, kb, vb, 16384, 524288,
                                                 1024, 16, 0, Opart, MLpart, nullptr);
  flash_combine<<<dim3(64, 32), 256, 0, stream>>>(Opart, MLpart, T3);
  // 10. W2 = pinv(attn2) @ T3 -> bf16 directly
  gemm_ab<<<dim3(1, 4, BH), 256, 0, stream>>>(zc, T3, 256, 256, 64, 65536, 16384,
                                              7, nullptr, nullptr, W2b, nullptr);
  // 11. flash B: outh = softmax(q kl^T) @ W2, scattered [b,n,h*64]
  flash_mfma<<<dim3(64, 32, 1), 256, 0, stream>>>(qb, klb, W2b, 524288, 16384,
                                                  0, 4, 1, nullptr, nullptr, outh);
  // 12. conv residual
  conv_add<<<BH * (NTOK / 64), 256, 0, stream>>>(vb, conv_w, outh);
  // 13. out = x + outh @ w_out + b_out
  gemm_mfma<1><<<dim3(4, 256), 256, 0, stream>>>(outh, woutT, 512, nullptr, nullptr,
                                                 nullptr, out, b_out, x);
}

// Round 6
// 782.812 us; speedup vs baseline: 3.9201x; 1.4178x over previous
//
#include <hip/hip_runtime.h>

#define NTOK 8192
#define TOT 32768
#define DMODEL 512
#define NM 256
#define BH 32

typedef __attribute__((ext_vector_type(8))) short bf16x8;
typedef __attribute__((ext_vector_type(8))) unsigned short u16x8;
typedef __attribute__((ext_vector_type(4))) float f32x4;

__device__ __forceinline__ unsigned short f2b(float f) {
  unsigned u = __float_as_uint(f);
  return (unsigned short)((u + 0x7fffu + ((u >> 16) & 1u)) >> 16);
}
__device__ __forceinline__ float b2f(unsigned short h) {
  return __uint_as_float((unsigned)h << 16);
}
__device__ __forceinline__ f32x4 mfma16(bf16x8 a, bf16x8 b, f32x4 c) {
  return __builtin_amdgcn_mfma_f32_16x16x32_bf16(a, b, c, 0, 0, 0);
}
__device__ __forceinline__ float wave_sum(float v) {
#pragma unroll
  for (int o = 32; o; o >>= 1) v += __shfl_xor(v, o, 64);
  return v;
}
__device__ __forceinline__ float wave_max(float v) {
#pragma unroll
  for (int o = 32; o; o >>= 1) v = fmaxf(v, __shfl_xor(v, o, 64));
  return v;
}

// ---------------- fused LayerNorm + landmark pooling ----------------
// block = one 32-token pool window; writes bf16 xnb rows + pooled fp32 xl row
__global__ __launch_bounds__(256) void ln_pool(const float* __restrict__ x,
                                               const float* __restrict__ g,
                                               const float* __restrict__ b,
                                               unsigned int* __restrict__ xnb,
                                               float* __restrict__ xl) {
  __shared__ float r1[4], r2[4];
  size_t row0 = (size_t)blockIdx.x * 32;
  int tid = threadIdx.x, lane = tid & 63, wid = tid >> 6;
  float2 gg = reinterpret_cast<const float2*>(g)[tid];
  float2 bb = reinterpret_cast<const float2*>(b)[tid];
  float ax = 0.f, ay = 0.f;
  for (int r = 0; r < 32; ++r) {
    float2 v = reinterpret_cast<const float2*>(x + (row0 + r) * DMODEL)[tid];
    float s = wave_sum(v.x + v.y);
    float ss = wave_sum(v.x * v.x + v.y * v.y);
    if (!lane) { r1[wid] = s; r2[wid] = ss; }
    __syncthreads();
    s = r1[0] + r1[1] + r1[2] + r1[3];
    ss = r2[0] + r2[1] + r2[2] + r2[3];
    __syncthreads();
    float mu = s * (1.f / DMODEL);
    float var = ss * (1.f / DMODEL) - mu * mu;
    float rstd = rsqrtf(var + 1e-5f);
    float ox = (v.x - mu) * rstd * gg.x + bb.x;
    float oy = (v.y - mu) * rstd * gg.y + bb.y;
    xnb[(row0 + r) * 256 + tid] = (unsigned)f2b(ox) | ((unsigned)f2b(oy) << 16);
    ax += ox; ay += oy;
  }
  float2 o; o.x = ax * (1.f / 32.f); o.y = ay * (1.f / 32.f);
  reinterpret_cast<float2*>(xl + (size_t)blockIdx.x * DMODEL)[tid] = o;
}

// ---------------- transpose + cvt fp32[K][N] -> bf16[N][K] ----------------
__global__ __launch_bounds__(256) void transpose_cvt(const float* __restrict__ in,
                                                     unsigned short* __restrict__ outp,
                                                     int K, int N) {
  __shared__ float t[32][33];
  int k0 = blockIdx.y * 32, n0 = blockIdx.x * 32;
  int tx = threadIdx.x & 31, ty = threadIdx.x >> 5;
#pragma unroll
  for (int i = 0; i < 32; i += 8)
    t[ty + i][tx] = in[(size_t)(k0 + ty + i) * N + n0 + tx];
  __syncthreads();
#pragma unroll
  for (int i = 0; i < 32; i += 8)
    outp[(size_t)(n0 + ty + i) * K + k0 + tx] = f2b(t[tx][ty + i]);
}

// ---------------- MFMA GEMM NT: C = A[M,Kd] @ Bt[N,Kd]^T ----------------
template <int EPI>
__global__ __launch_bounds__(256) void gemm_mfma(const void* __restrict__ Ap,
                                                 const unsigned short* __restrict__ Bt,
                                                 int Kd,
                                                 unsigned short* __restrict__ qo,
                                                 unsigned short* __restrict__ ko,
                                                 unsigned short* __restrict__ vo,
                                                 float* __restrict__ Cf,
                                                 const float* __restrict__ bias,
                                                 const float* __restrict__ resid) {
  __shared__ __align__(16) unsigned short As[128][72];
  __shared__ __align__(16) unsigned short Bs[128][72];
  const int tid = threadIdx.x;
  const int l16 = tid & 15, h8 = (tid & 63) >> 4, w = tid >> 6;
  const int m0 = blockIdx.y * 128, n0 = blockIdx.x * 128;
  const int wr = (w >> 1) * 64, wc = (w & 1) * 64;
  const int srow = tid >> 1, sc0 = (tid & 1) * 32;
  f32x4 acc[4][4] = {};
  for (int k0 = 0; k0 < Kd; k0 += 64) {
    if (EPI == 0) {
      const unsigned short* Ab = (const unsigned short*)Ap + (size_t)(m0 + srow) * Kd + k0 + sc0;
#pragma unroll
      for (int i = 0; i < 4; ++i)
        *(u16x8*)&As[srow][sc0 + 8 * i] = *(const u16x8*)(Ab + 8 * i);
    } else {
      const float* Af = (const float*)Ap + (size_t)(m0 + srow) * Kd + k0 + sc0;
#pragma unroll
      for (int i = 0; i < 4; ++i) {
        float4 f0 = *(const float4*)(Af + 8 * i);
        float4 f1 = *(const float4*)(Af + 8 * i + 4);
        u16x8 u;
        u[0] = f2b(f0.x); u[1] = f2b(f0.y); u[2] = f2b(f0.z); u[3] = f2b(f0.w);
        u[4] = f2b(f1.x); u[5] = f2b(f1.y); u[6] = f2b(f1.z); u[7] = f2b(f1.w);
        *(u16x8*)&As[srow][sc0 + 8 * i] = u;
      }
    }
    const unsigned short* Bb = Bt + (size_t)(n0 + srow) * Kd + k0 + sc0;
#pragma unroll
    for (int i = 0; i < 4; ++i)
      *(u16x8*)&Bs[srow][sc0 + 8 * i] = *(const u16x8*)(Bb + 8 * i);
    __syncthreads();
#pragma unroll
    for (int ks = 0; ks < 2; ++ks) {
      bf16x8 a[4], b[4];
#pragma unroll
      for (int mi = 0; mi < 4; ++mi)
        a[mi] = *(const bf16x8*)&As[wr + mi * 16 + l16][ks * 32 + h8 * 8];
#pragma unroll
      for (int nj = 0; nj < 4; ++nj)
        b[nj] = *(const bf16x8*)&Bs[wc + nj * 16 + l16][ks * 32 + h8 * 8];
#pragma unroll
      for (int mi = 0; mi < 4; ++mi)
#pragma unroll
        for (int nj = 0; nj < 4; ++nj)
          acc[mi][nj] = mfma16(a[mi], b[nj], acc[mi][nj]);
    }
    __syncthreads();
  }
#pragma unroll
  for (int mi = 0; mi < 4; ++mi)
#pragma unroll
    for (int nj = 0; nj < 4; ++nj)
#pragma unroll
      for (int r = 0; r < 4; ++r) {
        int grow = m0 + wr + mi * 16 + 4 * h8 + r;
        int gcol = n0 + wc + nj * 16 + l16;
        float val = acc[mi][nj][r];
        if (EPI == 0) {
          int which = gcol >> 9, hh = (gcol >> 6) & 7, dd = gcol & 63;
          int bidx = grow >> 13, nn = grow & 8191;
          if (which == 0) val *= 0.125f;
          unsigned short* dst = which == 0 ? qo : (which == 1 ? ko : vo);
          dst[(((size_t)(bidx * 8 + hh)) * NTOK + nn) * 64 + dd] = f2b(val);
        } else {
          Cf[(size_t)grow * 512 + gcol] = val + bias[gcol] + resid[(size_t)grow * 512 + gcol];
        }
      }
}

// ---------------- fp32 GEMM (landmark path), epi 5 / 7 ----------------
__global__ __launch_bounds__(256)
void gemm_ab(const float* __restrict__ A, const float* __restrict__ Bm,
             int Kdim, int lda, int ldb,
             long long sA, long long sB, int epi,
             float* __restrict__ qlp, float* __restrict__ klp,
             unsigned short* __restrict__ q16, unsigned short* __restrict__ k16) {
  __shared__ float As[16][64], Bs[16][64];
  int bz = blockIdx.z;
  A += sA * bz; Bm += sB * bz;
  int n0 = blockIdx.x * 64, m0 = blockIdx.y * 64;
  int tid = threadIdx.x, tx = tid & 15, ty = tid >> 4;
  int am = tid >> 2, akg = tid & 3, bk = tid >> 4, bng = tid & 15;
  const float* Aload = A + (size_t)(m0 + am) * lda + akg * 4;
  const float* Bload = Bm + (size_t)bk * ldb + n0 + bng * 4;
  float acc[4][4] = {};
  for (int k0 = 0; k0 < Kdim; k0 += 16) {
    float4 av = *reinterpret_cast<const float4*>(Aload + k0);
    float4 bv = *reinterpret_cast<const float4*>(Bload + (size_t)k0 * ldb);
    __syncthreads();
    As[akg * 4 + 0][am] = av.x; As[akg * 4 + 1][am] = av.y;
    As[akg * 4 + 2][am] = av.z; As[akg * 4 + 3][am] = av.w;
    *reinterpret_cast<float4*>(&Bs[bk][bng * 4]) = bv;
    __syncthreads();
#pragma unroll
    for (int kk = 0; kk < 16; ++kk) {
      float4 bq = *reinterpret_cast<const float4*>(&Bs[kk][tx * 4]);
      float a0 = As[kk][ty * 4 + 0], a1 = As[kk][ty * 4 + 1];
      float a2 = As[kk][ty * 4 + 2], a3 = As[kk][ty * 4 + 3];
      acc[0][0] += a0 * bq.x; acc[0][1] += a0 * bq.y; acc[0][2] += a0 * bq.z; acc[0][3] += a0 * bq.w;
      acc[1][0] += a1 * bq.x; acc[1][1] += a1 * bq.y; acc[1][2] += a1 * bq.z; acc[1][3] += a1 * bq.w;
      acc[2][0] += a2 * bq.x; acc[2][1] += a2 * bq.y; acc[2][2] += a2 * bq.z; acc[2][3] += a2 * bq.w;
      acc[3][0] += a3 * bq.x; acc[3][1] += a3 * bq.y; acc[3][2] += a3 * bq.z; acc[3][3] += a3 * bq.w;
    }
  }
  if (epi == 5) {
#pragma unroll
    for (int i = 0; i < 4; ++i) {
      int gr = m0 + ty * 4 + i;
      int bidx = gr >> 8, nn = gr & 255;
#pragma unroll
      for (int j = 0; j < 4; ++j) {
        int gc = n0 + tx * 4 + j;
        int which = gc >> 9, hh = (gc >> 6) & 7, dd = gc & 63;
        float val = acc[i][j];
        if (which == 0) val *= 0.125f;
        size_t idx = (((size_t)(bidx * 8 + hh)) * 256 + nn) * 64 + dd;
        float* dst = which == 0 ? qlp : klp;
        unsigned short* dst16 = which == 0 ? q16 : k16;
        dst[idx] = val;
        dst16[idx] = f2b(val);
      }
    }
  } else {  // epi 7
#pragma unroll
    for (int i = 0; i < 4; ++i) {
      int gr = m0 + ty * 4 + i;
#pragma unroll
      for (int j = 0; j < 4; ++j) {
        int gc = n0 + tx * 4 + j;
        q16[(size_t)bz * 16384 + (size_t)gr * 64 + gc] = f2b(acc[i][j]);
      }
    }
  }
}

// ---------------- GEMM C = A[M,64] @ B[N,64]^T (sim2) ----------------
__global__ __launch_bounds__(256)
void gemm_abt(const float* __restrict__ A, const float* __restrict__ Bm,
              float* __restrict__ C, int Kdim, int lda, int ldb, int ldc,
              long long sA, long long sB, long long sC) {
  __shared__ float As[16][64], Bs[16][64];
  int bz = blockIdx.z;
  A += sA * bz; Bm += sB * bz; C += sC * bz;
  int n0 = blockIdx.x * 64, m0 = blockIdx.y * 64;
  int tid = threadIdx.x, tx = tid & 15, ty = tid >> 4;
  int am = tid >> 2, akg = tid & 3;
  const float* Aload = A + (size_t)(m0 + am) * lda + akg * 4;
  const float* Bload = Bm + (size_t)(n0 + am) * ldb + akg * 4;
  float acc[4][4] = {};
  for (int k0 = 0; k0 < Kdim; k0 += 16) {
    float4 av = *reinterpret_cast<const float4*>(Aload + k0);
    float4 bv = *reinterpret_cast<const float4*>(Bload + k0);
    __syncthreads();
    As[akg * 4 + 0][am] = av.x; As[akg * 4 + 1][am] = av.y;
    As[akg * 4 + 2][am] = av.z; As[akg * 4 + 3][am] = av.w;
    Bs[akg * 4 + 0][am] = bv.x; Bs[akg * 4 + 1][am] = bv.y;
    Bs[akg * 4 + 2][am] = bv.z; Bs[akg * 4 + 3][am] = bv.w;
    __syncthreads();
#pragma unroll
    for (int kk = 0; kk < 16; ++kk) {
      float4 bq = *reinterpret_cast<const float4*>(&Bs[kk][tx * 4]);
      float a0 = As[kk][ty * 4 + 0], a1 = As[kk][ty * 4 + 1];
      float a2 = As[kk][ty * 4 + 2], a3 = As[kk][ty * 4 + 3];
      acc[0][0] += a0 * bq.x; acc[0][1] += a0 * bq.y; acc[0][2] += a0 * bq.z; acc[0][3] += a0 * bq.w;
      acc[1][0] += a1 * bq.x; acc[1][1] += a1 * bq.y; acc[1][2] += a1 * bq.z; acc[1][3] += a1 * bq.w;
      acc[2][0] += a2 * bq.x; acc[2][1] += a2 * bq.y; acc[2][2] += a2 * bq.z; acc[2][3] += a2 * bq.w;
      acc[3][0] += a3 * bq.x; acc[3][1] += a3 * bq.y; acc[3][2] += a3 * bq.z; acc[3][3] += a3 * bq.w;
    }
  }
#pragma unroll
  for (int i = 0; i < 4; ++i) {
    int gr = m0 + ty * 4 + i;
#pragma unroll
    for (int j = 0; j < 4; ++j)
      C[(size_t)gr * ldc + n0 + tx * 4 + j] = acc[i][j];
  }
}

// ---------------- row softmax (256 cols) ----------------
__global__ __launch_bounds__(256) void softmax_rows256(float* __restrict__ buf) {
  __shared__ float red[4];
  size_t row = blockIdx.x;
  float* r = buf + row * 256;
  int tid = threadIdx.x, lane = tid & 63, wid = tid >> 6;
  float v = r[tid];
  float mx = wave_max(v);
  if (!lane) red[wid] = mx;
  __syncthreads();
  mx = fmaxf(fmaxf(red[0], red[1]), fmaxf(red[2], red[3]));
  __syncthreads();
  float e = expf(v - mx);
  float s = wave_sum(e);
  if (!lane) red[wid] = s;
  __syncthreads();
  s = red[0] + red[1] + red[2] + red[3];
  r[tid] = e / s;
}

// ---------------- pinv scalar: max column-sum (row-sums are exactly 1) -------
__global__ void init_scalars(float* sc) { if (threadIdx.x < 2) sc[threadIdx.x] = 0.f; }

__global__ __launch_bounds__(256) void colsum_part(const float* __restrict__ a2,
                                                   float* __restrict__ part) {
  int bh = blockIdx.x >> 3, chunk = blockIdx.x & 7;
  int tid = threadIdx.x;
  const float* M = a2 + (size_t)bh * 65536 + (size_t)chunk * 32 * 256;
  float acc = 0.f;
#pragma unroll
  for (int r = 0; r < 32; ++r) acc += M[r * 256 + tid];
  part[(size_t)blockIdx.x * 256 + tid] = acc;
}

__global__ __launch_bounds__(256) void colsum_final(const float* __restrict__ part,
                                                    float* __restrict__ sc) {
  __shared__ float red[4];
  int bh = blockIdx.x;
  int tid = threadIdx.x, lane = tid & 63, w = tid >> 6;
  float s = 0.f;
#pragma unroll
  for (int c = 0; c < 8; ++c) s += part[(size_t)(bh * 8 + c) * 256 + tid];
  float m = wave_max(s);
  if (!lane) red[w] = m;
  __syncthreads();
  if (tid == 0) {
    float mm = fmaxf(fmaxf(red[0], red[1]), fmaxf(red[2], red[3]));
    atomicMax(reinterpret_cast<int*>(sc) + 1, __float_as_int(mm));
  }
}

// ---------------- split attn2 into hi/lo bf16: X, z0=X^T/c, z0^T=X/c --------
__global__ __launch_bounds__(256) void hilo_split(
    const float* __restrict__ a2, const float* __restrict__ sc,
    unsigned short* __restrict__ Xh, unsigned short* __restrict__ Xl,
    unsigned short* __restrict__ zth, unsigned short* __restrict__ ztl,
    unsigned short* __restrict__ zh, unsigned short* __restrict__ zl) {
  __shared__ float t[64][65];
  int bz = blockIdx.z;
  size_t base = (size_t)bz * 65536;
  int i0 = blockIdx.y * 64, j0 = blockIdx.x * 64;
  int tid = threadIdx.x, tx = tid & 15, ty = tid >> 4;
  float inv = 1.f / sc[1];
#pragma unroll
  for (int rr = 0; rr < 64; rr += 16) {
    int gr = i0 + rr + ty, gc0 = j0 + tx * 4;
    float4 v = *(const float4*)&a2[base + (size_t)gr * 256 + gc0];
    t[rr + ty][tx * 4 + 0] = v.x; t[rr + ty][tx * 4 + 1] = v.y;
    t[rr + ty][tx * 4 + 2] = v.z; t[rr + ty][tx * 4 + 3] = v.w;
    ushort4 xh, xl2, sh, sl;
    float vv[4] = {v.x, v.y, v.z, v.w};
    unsigned short* ph = (unsigned short*)&xh;
    unsigned short* pl = (unsigned short*)&xl2;
    unsigned short* qh = (unsigned short*)&sh;
    unsigned short* ql2 = (unsigned short*)&sl;
#pragma unroll
    for (int j = 0; j < 4; ++j) {
      ph[j] = f2b(vv[j]);
      pl[j] = f2b(vv[j] - b2f(ph[j]));
      float s = vv[j] * inv;
      qh[j] = f2b(s);
      ql2[j] = f2b(s - b2f(qh[j]));
    }
    *(ushort4*)&Xh[base + (size_t)gr * 256 + gc0] = xh;
    *(ushort4*)&Xl[base + (size_t)gr * 256 + gc0] = xl2;
    *(ushort4*)&zth[base + (size_t)gr * 256 + gc0] = sh;
    *(ushort4*)&ztl[base + (size_t)gr * 256 + gc0] = sl;
  }
  __syncthreads();
#pragma unroll
  for (int rr = 0; rr < 64; rr += 16) {
    int gr = j0 + rr + ty;  // output row = original col
    int gc0 = i0 + tx * 4;
    ushort4 zh4, zl4;
    unsigned short* ph = (unsigned short*)&zh4;
    unsigned short* pl = (unsigned short*)&zl4;
#pragma unroll
    for (int j = 0; j < 4; ++j) {
      float s = t[tx * 4 + j][rr + ty] * inv;
      ph[j] = f2b(s);
      pl[j] = f2b(s - b2f(ph[j]));
    }
    *(ushort4*)&zh[base + (size_t)gr * 256 + gc0] = zh4;
    *(ushort4*)&zl[base + (size_t)gr * 256 + gc0] = zl4;
  }
}

// ---------------- NS hi/lo MFMA GEMM: C = alpha*A@B + diag*I + beta*E -------
// A given row-major (Ah,Al); B given TRANSPOSED row-major (Bth,Btl).
// Optional outputs: row-major hi/lo (Ch,Cl), transposed hi/lo (CTh,CTl), fp32 Cf.
__global__ __launch_bounds__(256) void ns_mfma(
    const unsigned short* __restrict__ Ah, const unsigned short* __restrict__ Al,
    const unsigned short* __restrict__ Bth, const unsigned short* __restrict__ Btl,
    const unsigned short* __restrict__ Eh, const unsigned short* __restrict__ El,
    float alpha, float diag, float beta,
    unsigned short* __restrict__ Ch, unsigned short* __restrict__ Cl,
    unsigned short* __restrict__ CTh, unsigned short* __restrict__ CTl,
    float* __restrict__ Cf) {
  __shared__ __align__(16) unsigned short AhS[64][72], AlS[64][72];
  __shared__ __align__(16) unsigned short BhS[64][72], BlS[64][72];
  const int tid = threadIdx.x;
  const int l16 = tid & 15, h8 = (tid & 63) >> 4, w = tid >> 6;
  const size_t base = (size_t)blockIdx.z * 65536;
  const int m0 = blockIdx.y * 64, n0 = blockIdx.x * 64;
  const int wr = (w >> 1) * 32, wc = (w & 1) * 32;
  const int srow = tid >> 2, scol = (tid & 3) * 16;
  f32x4 acc[2][2] = {};
  for (int k0 = 0; k0 < 256; k0 += 64) {
    const size_t aoff = base + (size_t)(m0 + srow) * 256 + k0 + scol;
    const size_t boff = base + (size_t)(n0 + srow) * 256 + k0 + scol;
    *(u16x8*)&AhS[srow][scol] = *(const u16x8*)(Ah + aoff);
    *(u16x8*)&AhS[srow][scol + 8] = *(const u16x8*)(Ah + aoff + 8);
    *(u16x8*)&AlS[srow][scol] = *(const u16x8*)(Al + aoff);
    *(u16x8*)&AlS[srow][scol + 8] = *(const u16x8*)(Al + aoff + 8);
    *(u16x8*)&BhS[srow][scol] = *(const u16x8*)(Bth + boff);
    *(u16x8*)&BhS[srow][scol + 8] = *(const u16x8*)(Bth + boff + 8);
    *(u16x8*)&BlS[srow][scol] = *(const u16x8*)(Btl + boff);
    *(u16x8*)&BlS[srow][scol + 8] = *(const u16x8*)(Btl + boff + 8);
    __syncthreads();
#pragma unroll
    for (int ks = 0; ks < 2; ++ks) {
      bf16x8 ah[2], al[2], bh[2], bl[2];
#pragma unroll
      for (int mi = 0; mi < 2; ++mi) {
        ah[mi] = *(const bf16x8*)&AhS[wr + mi * 16 + l16][ks * 32 + h8 * 8];
        al[mi] = *(const bf16x8*)&AlS[wr + mi * 16 + l16][ks * 32 + h8 * 8];
      }
#pragma unroll
      for (int nj = 0; nj < 2; ++nj) {
        bh[nj] = *(const bf16x8*)&BhS[wc + nj * 16 + l16][ks * 32 + h8 * 8];
        bl[nj] = *(const bf16x8*)&BlS[wc + nj * 16 + l16][ks * 32 + h8 * 8];
      }
#pragma unroll
      for (int mi = 0; mi < 2; ++mi)
#pragma unroll
        for (int nj = 0; nj < 2; ++nj) {
          acc[mi][nj] = mfma16(ah[mi], bh[nj], acc[mi][nj]);
          acc[mi][nj] = mfma16(ah[mi], bl[nj], acc[mi][nj]);
          acc[mi][nj] = mfma16(al[mi], bh[nj], acc[mi][nj]);
        }
    }
    __syncthreads();
  }
#pragma unroll
  for (int mi = 0; mi < 2; ++mi)
#pragma unroll
    for (int nj = 0; nj < 2; ++nj) {
      int grow0 = m0 + wr + mi * 16 + 4 * h8;
      int gcol = n0 + wc + nj * 16 + l16;
      float vals[4];
      ushort4 th, tl;
      unsigned short* ph = (unsigned short*)&th;
      unsigned short* pl = (unsigned short*)&tl;
#pragma unroll
      for (int r = 0; r < 4; ++r) {
        int grow = grow0 + r;
        float v = alpha * acc[mi][nj][r];
        if (grow == gcol) v += diag;
        if (Eh) v += beta * (b2f(Eh[base + (size_t)grow * 256 + gcol]) +
                             b2f(El[base + (size_t)grow * 256 + gcol]));
        vals[r] = v;
        ph[r] = f2b(v);
        pl[r] = f2b(v - b2f(ph[r]));
      }
      if (Ch) {
#pragma unroll
        for (int r = 0; r < 4; ++r) {
          Ch[base + (size_t)(grow0 + r) * 256 + gcol] = ph[r];
          Cl[base + (size_t)(grow0 + r) * 256 + gcol] = pl[r];
        }
      }
      if (CTh) {
        *(ushort4*)&CTh[base + (size_t)gcol * 256 + grow0] = th;
        *(ushort4*)&CTl[base + (size_t)gcol * 256 + grow0] = tl;
      }
      if (Cf) {
#pragma unroll
        for (int r = 0; r < 4; ++r)
          Cf[base + (size_t)(grow0 + r) * 256 + gcol] = vals[r];
      }
    }
}

// ---------------- MFMA flash: O = softmax(Q K^T) V, 128 q-rows/block ----------
__global__ __launch_bounds__(256) void flash_mfma(
    const unsigned short* __restrict__ Q, const unsigned short* __restrict__ Kp,
    const unsigned short* __restrict__ Vp, long long sQ, long long sK,
    int kps, int nkt, int mode,
    float* __restrict__ Opart, float* __restrict__ MLpart, float* __restrict__ outh) {
  __shared__ __align__(16) unsigned short Qt[128][72];
  __shared__ __align__(16) unsigned short Kt[64][72];
  __shared__ __align__(16) unsigned short Vt[64][72];
  __shared__ __align__(16) unsigned short Pb[128][72];
  const int tid = threadIdx.x;
  const int l16 = tid & 15, h8 = (tid & 63) >> 4, w = tid >> 6;
  const int bh = blockIdx.y, s = blockIdx.z, qt = blockIdx.x;
  const int q0 = qt * 128;
  const unsigned short* Qb = Q + (size_t)bh * sQ + (size_t)q0 * 64;
  const unsigned short* Kb = Kp + (size_t)bh * sK + (size_t)s * kps * 64;
  const unsigned short* Vb = Vp + (size_t)bh * sK + (size_t)s * kps * 64;
  {
    int row = tid >> 1, c0 = (tid & 1) * 32;
#pragma unroll
    for (int i = 0; i < 4; ++i)
      *(u16x8*)&Qt[row][c0 + 8 * i] = *(const u16x8*)(Qb + (size_t)row * 64 + c0 + 8 * i);
  }
  f32x4 acc_o[2][4] = {};
  float mrow[2][4], lrow[2][4];
#pragma unroll
  for (int mi = 0; mi < 2; ++mi)
#pragma unroll
    for (int r = 0; r < 4; ++r) { mrow[mi][r] = -1e30f; lrow[mi][r] = 0.f; }
  for (int kt = 0; kt < nkt; ++kt) {
    {
      int row = tid >> 2, c0 = (tid & 3) * 16;
      *(u16x8*)&Kt[row][c0] = *(const u16x8*)(Kb + ((size_t)(kt * 64 + row)) * 64 + c0);
      *(u16x8*)&Kt[row][c0 + 8] = *(const u16x8*)(Kb + ((size_t)(kt * 64 + row)) * 64 + c0 + 8);
      int key = tid & 63, d0 = w * 16;
      u16x8 v0 = *(const u16x8*)(Vb + ((size_t)(kt * 64 + key)) * 64 + d0);
      u16x8 v1 = *(const u16x8*)(Vb + ((size_t)(kt * 64 + key)) * 64 + d0 + 8);
#pragma unroll
      for (int i = 0; i < 8; ++i) { Vt[d0 + i][key] = v0[i]; Vt[d0 + 8 + i][key] = v1[i]; }
    }
    __syncthreads();
    f32x4 accs[2][4] = {};
#pragma unroll
    for (int ks = 0; ks < 2; ++ks) {
      bf16x8 a[2], b[4];
      a[0] = *(const bf16x8*)&Qt[w * 32 + l16][ks * 32 + h8 * 8];
      a[1] = *(const bf16x8*)&Qt[w * 32 + 16 + l16][ks * 32 + h8 * 8];
#pragma unroll
      for (int nj = 0; nj < 4; ++nj)
        b[nj] = *(const bf16x8*)&Kt[nj * 16 + l16][ks * 32 + h8 * 8];
#pragma unroll
      for (int mi = 0; mi < 2; ++mi)
#pragma unroll
        for (int nj = 0; nj < 4; ++nj)
          accs[mi][nj] = mfma16(a[mi], b[nj], accs[mi][nj]);
    }
#pragma unroll
    for (int mi = 0; mi < 2; ++mi)
#pragma unroll
      for (int r = 0; r < 4; ++r) {
        float mx = fmaxf(fmaxf(accs[mi][0][r], accs[mi][1][r]),
                         fmaxf(accs[mi][2][r], accs[mi][3][r]));
#pragma unroll
        for (int off = 8; off; off >>= 1) mx = fmaxf(mx, __shfl_xor(mx, off, 64));
        float mn = fmaxf(mrow[mi][r], mx);
        float scf = __expf(mrow[mi][r] - mn);
        float ps = 0.f;
#pragma unroll
        for (int nj = 0; nj < 4; ++nj) {
          float p = __expf(accs[mi][nj][r] - mn);
          accs[mi][nj][r] = p;
          ps += p;
        }
#pragma unroll
        for (int off = 8; off; off >>= 1) ps += __shfl_xor(ps, off, 64);
        lrow[mi][r] = lrow[mi][r] * scf + ps;
        mrow[mi][r] = mn;
#pragma unroll
        for (int dj = 0; dj < 4; ++dj) acc_o[mi][dj][r] *= scf;
        int prow = w * 32 + mi * 16 + 4 * h8 + r;
#pragma unroll
        for (int nj = 0; nj < 4; ++nj)
          Pb[prow][nj * 16 + l16] = f2b(accs[mi][nj][r]);
      }
    __syncthreads();
#pragma unroll
    for (int ks = 0; ks < 2; ++ks) {
      bf16x8 pa[2], vb[4];
      pa[0] = *(const bf16x8*)&Pb[w * 32 + l16][ks * 32 + h8 * 8];
      pa[1] = *(const bf16x8*)&Pb[w * 32 + 16 + l16][ks * 32 + h8 * 8];
#pragma unroll
      for (int dj = 0; dj < 4; ++dj)
        vb[dj] = *(const bf16x8*)&Vt[dj * 16 + l16][ks * 32 + h8 * 8];
#pragma unroll
      for (int mi = 0; mi < 2; ++mi)
#pragma unroll
        for (int dj = 0; dj < 4; ++dj)
          acc_o[mi][dj] = mfma16(pa[mi], vb[dj], acc_o[mi][dj]);
    }
    __syncthreads();
  }
  if (mode == 0) {
    int p = (s * 32 + bh) * 2 + qt;
    float* Ob = Opart + (size_t)p * 8192;
#pragma unroll
    for (int mi = 0; mi < 2; ++mi)
#pragma unroll
      for (int r = 0; r < 4; ++r) {
        int row = w * 32 + mi * 16 + 4 * h8 + r;
#pragma unroll
        for (int dj = 0; dj < 4; ++dj)
          Ob[(size_t)row * 64 + dj * 16 + l16] = acc_o[mi][dj][r];
        if (l16 == 0) {
          MLpart[((size_t)p * 128 + row) * 2] = mrow[mi][r];
          MLpart[((size_t)p * 128 + row) * 2 + 1] = lrow[mi][r];
        }
      }
  } else {
    int bidx = bh >> 3, hh = bh & 7;
#pragma unroll
    for (int mi = 0; mi < 2; ++mi)
#pragma unroll
      for (int r = 0; r < 4; ++r) {
        int row = w * 32 + mi * 16 + 4 * h8 + r;
        float inv = 1.f / lrow[mi][r];
#pragma unroll
        for (int dj = 0; dj < 4; ++dj)
          outh[((size_t)bidx * NTOK + q0 + row) * 512 + hh * 64 + dj * 16 + l16] =
              acc_o[mi][dj][r] * inv;
      }
  }
}

// ---------------- combine split-K flash partials -> T3 ----------------
__global__ __launch_bounds__(256) void flash_combine(const float* __restrict__ Opart,
                                                     const float* __restrict__ MLpart,
                                                     float* __restrict__ T3) {
  int bh = blockIdx.y;
  int row = blockIdx.x * 4 + (threadIdx.x >> 6);
  int d = threadIdx.x & 63;
  int qt = row >> 7, rowin = row & 127;
  float mstar = -1e30f;
#pragma unroll
  for (int s = 0; s < 8; ++s) {
    int p = (s * 32 + bh) * 2 + qt;
    mstar = fmaxf(mstar, MLpart[((size_t)p * 128 + rowin) * 2]);
  }
  float L = 0.f, O = 0.f;
#pragma unroll
  for (int s = 0; s < 8; ++s) {
    int p = (s * 32 + bh) * 2 + qt;
    float ms = MLpart[((size_t)p * 128 + rowin) * 2];
    float ls = MLpart[((size_t)p * 128 + rowin) * 2 + 1];
    float e = __expf(ms - mstar);
    L += ls * e;
    O += Opart[(size_t)p * 8192 + rowin * 64 + d] * e;
  }
  T3[((size_t)bh * 256 + row) * 64 + d] = O / L;
}

// ---------------- depthwise conv residual (bf16 v) into fp32 outh ------------
__global__ __launch_bounds__(256) void conv_add(const unsigned short* __restrict__ v,
                                                const float* __restrict__ cw,
                                                float* __restrict__ outh) {
  __shared__ float vt[96][64];
  __shared__ float wt[33];
  int z = blockIdx.x;
  int bh = z >> 7, n0 = (z & 127) * 64;
  int tid = threadIdx.x;
  if (tid < 33) wt[tid] = cw[(bh & 7) * 33 + tid];
  const unsigned short* vb = v + (size_t)bh * NTOK * 64;
  for (int f = tid; f < 768; f += 256) {
    int rowi = f >> 3, c8 = (f & 7) * 8;
    int rn = n0 - 16 + rowi;
    if (rn >= 0 && rn < NTOK) {
      u16x8 val = *(const u16x8*)(vb + (size_t)rn * 64 + c8);
#pragma unroll
      for (int i = 0; i < 8; ++i) vt[rowi][c8 + i] = b2f(val[i]);
    } else {
#pragma unroll
      for (int i = 0; i < 8; ++i) vt[rowi][c8 + i] = 0.f;
    }
  }
  __syncthreads();
  int dd = tid & 63, rg = tid >> 6;
  int bidx = bh >> 3, hh = bh & 7;
  for (int rr = 0; rr < 16; ++rr) {
    int rloc = rg * 16 + rr;
    float acc = 0.f;
#pragma unroll
    for (int kk = 0; kk < 33; ++kk) acc += wt[kk] * vt[rloc + kk][dd];
    size_t o = ((size_t)bidx * NTOK + n0 + rloc) * 512 + hh * 64 + dd;
    outh[o] += acc;
  }
}

extern "C" void kernel_launch(void* const* d_in, const int* in_sizes, int n_in,
                              void* d_out, int out_size, void* d_ws, size_t ws_size,
                              hipStream_t stream) {
  const float* x = (const float*)d_in[0];
  const float* gamma = (const float*)d_in[1];
  const float* beta = (const float*)d_in[2];
  const float* w_qkv = (const float*)d_in[3];
  const float* w_out = (const float*)d_in[4];
  const float* b_out = (const float*)d_in[5];
  const float* conv_w = (const float*)d_in[6];
  float* out = (float*)d_out;
  float* ws = (float*)d_ws;
  (void)ws_size; (void)in_sizes; (void)n_in; (void)out_size;

  float* A0 = ws;                          // X2/zfinal + NS bf16 pool -> outh
  float* Breg = ws + 16777216;             // xnb -> Opart/MLpart/T3
  unsigned short* qb = (unsigned short*)(ws + 25165824);
  unsigned short* kb = (unsigned short*)(ws + 33554432);
  unsigned short* vb = (unsigned short*)(ws + 41943040);
  float* Fs = ws + 50331648;

  // A0 tenants
  float* X2 = A0;                  // [0 .. 2,097,152) ; later zfinal
  float* zfinal = A0;
  float* ql = A0 + 2097152;        // dead before hilo_split writes Xh
  float* kl = A0 + 2621440;
  unsigned short* Xh  = (unsigned short*)(A0 + 2097152);
  unsigned short* Xl  = (unsigned short*)(A0 + 3145728);
  unsigned short* zAh = (unsigned short*)(A0 + 4194304);
  unsigned short* zAl = (unsigned short*)(A0 + 5242880);
  unsigned short* zAth = (unsigned short*)(A0 + 6291456);
  unsigned short* zAtl = (unsigned short*)(A0 + 7340032);
  unsigned short* zYh = (unsigned short*)(A0 + 8388608);
  unsigned short* zYl = (unsigned short*)(A0 + 9437184);
  unsigned short* zYth = (unsigned short*)(A0 + 10485760);
  unsigned short* zYtl = (unsigned short*)(A0 + 11534336);
  unsigned short* TBth = (unsigned short*)(A0 + 12582912);
  unsigned short* TBtl = (unsigned short*)(A0 + 13631488);
  unsigned short* TAth = (unsigned short*)(A0 + 14680064);
  unsigned short* TAtl = (unsigned short*)(A0 + 15728640);
  float* outh = A0;
  // Breg tenants
  unsigned int* xnb = (unsigned int*)Breg;
  float* Opart = Breg;
  float* MLpart = Breg + 4194304;
  float* T3 = Breg + 4325376;
  // Fs tenants
  float* xl = Fs;
  unsigned short* qlb = (unsigned short*)(Fs + 524288);
  unsigned short* klb = (unsigned short*)(Fs + 786432);
  unsigned short* W2b = (unsigned short*)(Fs + 1048576);
  unsigned short* woutT = (unsigned short*)(Fs + 1310720);
  unsigned short* wqkvT = (unsigned short*)(Fs + 1441792);
  float* part = Fs + 1835008;
  float* sc = Fs + 1900544;

  // 1. fused LayerNorm + pooling -> xnb bf16, xl fp32
  ln_pool<<<1024, 256, 0, stream>>>(x, gamma, beta, xnb, xl);
  // 2. weight transposes/cvt
  transpose_cvt<<<dim3(48, 16), 256, 0, stream>>>(w_qkv, wqkvT, 512, 1536);
  transpose_cvt<<<dim3(16, 16), 256, 0, stream>>>(w_out, woutT, 512, 512);
  // 3. qkv projection bf16 MFMA
  gemm_mfma<0><<<dim3(12, 256), 256, 0, stream>>>(xnb, wqkvT, 512, qb, kb, vb,
                                                  nullptr, nullptr, nullptr);
  // 4. ql/kl = xl @ Wq/Wk fp32 (+ bf16 copies fused)
  gemm_ab<<<dim3(16, 16, 1), 256, 0, stream>>>(xl, w_qkv, 512, 512, 1536, 0, 0,
                                               5, ql, kl, qlb, klb);
  // 5. sim2 -> attn2 (fp32)
  gemm_abt<<<dim3(4, 4, BH), 256, 0, stream>>>(ql, kl, X2, 64, 64, 64, 256,
                                               16384, 16384, 65536);
  softmax_rows256<<<BH * NM, 256, 0, stream>>>(X2);
  // 6. pinv scalar (row-sums == 1; need max col-sum) + hi/lo split
  init_scalars<<<1, 64, 0, stream>>>(sc);
  colsum_part<<<BH * 8, 256, 0, stream>>>(X2, part);
  colsum_final<<<BH, 256, 0, stream>>>(part, sc);
  hilo_split<<<dim3(4, 4, BH), 256, 0, stream>>>(X2, sc, Xh, Xl, zAth, zAtl, zAh, zAl);
  // 7. Newton-Schulz, hi/lo bf16 MFMA, 4 GEMMs/iter
  unsigned short *ch = zAh, *cl = zAl, *cth = zAth, *ctl = zAtl;
  unsigned short *yh = zYh, *yl = zYl, *yth = zYth, *ytl = zYtl;
  for (int it = 0; it < 6; ++it) {
    // Y = X @ z
    ns_mfma<<<dim3(4, 4, BH), 256, 0, stream>>>(Xh, Xl, cth, ctl, nullptr, nullptr,
                                                1.f, 0.f, 0.f, yh, yl, yth, ytl, nullptr);
    // TB = Y@Y - 7Y + 15I  (transposed only)
    ns_mfma<<<dim3(4, 4, BH), 256, 0, stream>>>(yh, yl, yth, ytl, yh, yl,
                                                1.f, 15.f, -7.f, nullptr, nullptr,
                                                TBth, TBtl, nullptr);
    // TA = 13I - Y@TB  (transposed only)
    ns_mfma<<<dim3(4, 4, BH), 256, 0, stream>>>(yh, yl, TBth, TBtl, nullptr, nullptr,
                                                -1.f, 13.f, 0.f, nullptr, nullptr,
                                                TAth, TAtl, nullptr);
    // zn = 0.25 z@TA -> into Y slot (+ fp32 on last iter)
    ns_mfma<<<dim3(4, 4, BH), 256, 0, stream>>>(ch, cl, TAth, TAtl, nullptr, nullptr,
                                                0.25f, 0.f, 0.f, yh, yl, yth, ytl,
                                                it == 5 ? zfinal : nullptr);
    unsigned short* t;
    t = ch; ch = yh; yh = t;  t = cl; cl = yl; yl = t;
    t = cth; cth = yth; yth = t;  t = ctl; ctl = ytl; ytl = t;
  }
  // 8. flash A (split-K=8): T3 = softmax(ql k^T) v
  flash_mfma<<<dim3(2, 32, 8), 256, 0, stream>>>(qlb, kb, vb, 16384, 524288,
                                                 1024, 16, 0, Opart, MLpart, nullptr);
  flash_combine<<<dim3(64, 32), 256, 0, stream>>>(Opart, MLpart, T3);
  // 9. W2 = pinv(attn2) @ T3 -> bf16
  gemm_ab<<<dim3(1, 4, BH), 256, 0, stream>>>(zfinal, T3, 256, 256, 64, 65536, 16384,
                                              7, nullptr, nullptr, W2b, nullptr);
  // 10. flash B: outh = softmax(q kl^T) @ W2
  flash_mfma<<<dim3(64, 32, 1), 256, 0, stream>>>(qb, klb, W2b, 524288, 16384,
                                                  0, 4, 1, nullptr, nullptr, outh);
  // 11. conv residual
  conv_add<<<BH * (NTOK / 64), 256, 0, stream>>>(vb, conv_w, outh);
  // 12. out = x + outh @ w_out + b_out
  gemm_mfma<1><<<dim3(4, 256), 256, 0, stream>>>(outh, woutT, 512, nullptr, nullptr,
                                                 nullptr, out, b_out, x);
}

// Round 7
// 759.848 us; speedup vs baseline: 4.0386x; 1.0302x over previous
//
#include <hip/hip_runtime.h>

#define NTOK 8192
#define TOT 32768
#define DMODEL 512
#define NM 256
#define BH 32

typedef __attribute__((ext_vector_type(8))) short bf16x8;
typedef __attribute__((ext_vector_type(8))) unsigned short u16x8;
typedef __attribute__((ext_vector_type(4))) float f32x4;

__device__ __forceinline__ unsigned short f2b(float f) {
  unsigned u = __float_as_uint(f);
  return (unsigned short)((u + 0x7fffu + ((u >> 16) & 1u)) >> 16);
}
__device__ __forceinline__ float b2f(unsigned short h) {
  return __uint_as_float((unsigned)h << 16);
}
__device__ __forceinline__ f32x4 mfma16(bf16x8 a, bf16x8 b, f32x4 c) {
  return __builtin_amdgcn_mfma_f32_16x16x32_bf16(a, b, c, 0, 0, 0);
}
__device__ __forceinline__ float wave_sum(float v) {
#pragma unroll
  for (int o = 32; o; o >>= 1) v += __shfl_xor(v, o, 64);
  return v;
}
__device__ __forceinline__ float wave_max(float v) {
#pragma unroll
  for (int o = 32; o; o >>= 1) v = fmaxf(v, __shfl_xor(v, o, 64));
  return v;
}

// ------------- fused LayerNorm + pooling, wave-per-row -------------
__global__ __launch_bounds__(256) void ln_pool(const float* __restrict__ x,
                                               const float* __restrict__ g,
                                               const float* __restrict__ b,
                                               unsigned short* __restrict__ xnb,
                                               float* __restrict__ xl) {
  __shared__ float pp[4][512];
  int tid = threadIdx.x, lane = tid & 63, w = tid >> 6;
  int c0 = lane * 8;
  float4 g0 = *(const float4*)&g[c0], g1 = *(const float4*)&g[c0 + 4];
  float4 b0 = *(const float4*)&b[c0], b1 = *(const float4*)&b[c0 + 4];
  float pa[8] = {};
  size_t rbase = (size_t)blockIdx.x * 32 + w * 8;
  for (int j = 0; j < 8; ++j) {
    size_t row = rbase + j;
    float4 v0 = *(const float4*)&x[row * DMODEL + c0];
    float4 v1 = *(const float4*)&x[row * DMODEL + c0 + 4];
    float s = v0.x + v0.y + v0.z + v0.w + v1.x + v1.y + v1.z + v1.w;
    float ss = v0.x * v0.x + v0.y * v0.y + v0.z * v0.z + v0.w * v0.w +
               v1.x * v1.x + v1.y * v1.y + v1.z * v1.z + v1.w * v1.w;
    s = wave_sum(s);
    ss = wave_sum(ss);
    float mu = s * (1.f / DMODEL);
    float var = ss * (1.f / DMODEL) - mu * mu;
    float rstd = rsqrtf(var + 1e-5f);
    float o[8];
    o[0] = (v0.x - mu) * rstd * g0.x + b0.x; o[1] = (v0.y - mu) * rstd * g0.y + b0.y;
    o[2] = (v0.z - mu) * rstd * g0.z + b0.z; o[3] = (v0.w - mu) * rstd * g0.w + b0.w;
    o[4] = (v1.x - mu) * rstd * g1.x + b1.x; o[5] = (v1.y - mu) * rstd * g1.y + b1.y;
    o[6] = (v1.z - mu) * rstd * g1.z + b1.z; o[7] = (v1.w - mu) * rstd * g1.w + b1.w;
    u16x8 pk;
#pragma unroll
    for (int i = 0; i < 8; ++i) { pk[i] = f2b(o[i]); pa[i] += o[i]; }
    *(u16x8*)&xnb[row * DMODEL + c0] = pk;
  }
  *(float4*)&pp[w][c0] = make_float4(pa[0], pa[1], pa[2], pa[3]);
  *(float4*)&pp[w][c0 + 4] = make_float4(pa[4], pa[5], pa[6], pa[7]);
  __syncthreads();
#pragma unroll
  for (int c = tid; c < 512; c += 256) {
    float s = pp[0][c] + pp[1][c] + pp[2][c] + pp[3][c];
    xl[(size_t)blockIdx.x * DMODEL + c] = s * (1.f / 32.f);
  }
}

// ------------- transpose + cvt fp32[K][N] -> bf16[N][K] -------------
__global__ __launch_bounds__(256) void transpose_cvt(const float* __restrict__ in,
                                                     unsigned short* __restrict__ outp,
                                                     int K, int N) {
  __shared__ float t[32][33];
  int k0 = blockIdx.y * 32, n0 = blockIdx.x * 32;
  int tx = threadIdx.x & 31, ty = threadIdx.x >> 5;
#pragma unroll
  for (int i = 0; i < 32; i += 8)
    t[ty + i][tx] = in[(size_t)(k0 + ty + i) * N + n0 + tx];
  __syncthreads();
#pragma unroll
  for (int i = 0; i < 32; i += 8)
    outp[(size_t)(n0 + ty + i) * K + k0 + tx] = f2b(t[tx][ty + i]);
}

// ------------- MFMA GEMM NT, swapped-fragment epilogue -------------
// EPI 0: scatter qkv (q*0.125) as bf16, ushort4 stores
// EPI 2: Cf = AB + bias + resid, float4 stores (A bf16)
template <int EPI>
__global__ __launch_bounds__(256) void gemm_mfma(const unsigned short* __restrict__ Ab,
                                                 const unsigned short* __restrict__ Bt,
                                                 int Kd,
                                                 unsigned short* __restrict__ qo,
                                                 unsigned short* __restrict__ ko,
                                                 unsigned short* __restrict__ vo,
                                                 float* __restrict__ Cf,
                                                 const float* __restrict__ bias,
                                                 const float* __restrict__ resid) {
  __shared__ __align__(16) unsigned short As[128][72];
  __shared__ __align__(16) unsigned short Bs[128][72];
  const int tid = threadIdx.x;
  const int l16 = tid & 15, h8 = (tid & 63) >> 4, w = tid >> 6;
  const int m0 = blockIdx.y * 128, n0 = blockIdx.x * 128;
  const int wr = (w >> 1) * 64, wc = (w & 1) * 64;
  const int srow = tid >> 1, sc0 = (tid & 1) * 32;
  f32x4 acc[4][4] = {};
  for (int k0 = 0; k0 < Kd; k0 += 64) {
    const unsigned short* Ap = Ab + (size_t)(m0 + srow) * Kd + k0 + sc0;
#pragma unroll
    for (int i = 0; i < 4; ++i)
      *(u16x8*)&As[srow][sc0 + 8 * i] = *(const u16x8*)(Ap + 8 * i);
    const unsigned short* Bb = Bt + (size_t)(n0 + srow) * Kd + k0 + sc0;
#pragma unroll
    for (int i = 0; i < 4; ++i)
      *(u16x8*)&Bs[srow][sc0 + 8 * i] = *(const u16x8*)(Bb + 8 * i);
    __syncthreads();
#pragma unroll
    for (int ks = 0; ks < 2; ++ks) {
      bf16x8 a[4], b[4];
#pragma unroll
      for (int mi = 0; mi < 4; ++mi)
        a[mi] = *(const bf16x8*)&As[wr + mi * 16 + l16][ks * 32 + h8 * 8];
#pragma unroll
      for (int nj = 0; nj < 4; ++nj)
        b[nj] = *(const bf16x8*)&Bs[wc + nj * 16 + l16][ks * 32 + h8 * 8];
#pragma unroll
      for (int mi = 0; mi < 4; ++mi)
#pragma unroll
        for (int nj = 0; nj < 4; ++nj)
          acc[mi][nj] = mfma16(b[nj], a[mi], acc[mi][nj]);  // swapped
    }
    __syncthreads();
  }
  // fragment: grow = m0+wr+mi*16+l16 ; gcol = n0+wc+nj*16+4*h8 + r (4 consecutive)
#pragma unroll
  for (int mi = 0; mi < 4; ++mi) {
    int grow = m0 + wr + mi * 16 + l16;
#pragma unroll
    for (int nj = 0; nj < 4; ++nj) {
      int gcol0 = n0 + wc + nj * 16 + 4 * h8;
      if (EPI == 0) {
        int which = gcol0 >> 9, hh = (gcol0 >> 6) & 7, dd0 = gcol0 & 63;
        int bidx = grow >> 13, nn = grow & 8191;
        float scl = which == 0 ? 0.125f : 1.f;
        ushort4 o;
        o.x = f2b(acc[mi][nj][0] * scl); o.y = f2b(acc[mi][nj][1] * scl);
        o.z = f2b(acc[mi][nj][2] * scl); o.w = f2b(acc[mi][nj][3] * scl);
        unsigned short* dst = which == 0 ? qo : (which == 1 ? ko : vo);
        *(ushort4*)&dst[(((size_t)(bidx * 8 + hh)) * NTOK + nn) * 64 + dd0] = o;
      } else {
        float4 bi = *(const float4*)&bias[gcol0];
        float4 re = *(const float4*)&resid[(size_t)grow * 512 + gcol0];
        float4 o;
        o.x = acc[mi][nj][0] + bi.x + re.x; o.y = acc[mi][nj][1] + bi.y + re.y;
        o.z = acc[mi][nj][2] + bi.z + re.z; o.w = acc[mi][nj][3] + bi.w + re.w;
        *(float4*)&Cf[(size_t)grow * 512 + gcol0] = o;
      }
    }
  }
}

// ------------- fp32 GEMM (landmark path), epi 5 / 7 -------------
__global__ __launch_bounds__(256)
void gemm_ab(const float* __restrict__ A, const float* __restrict__ Bm,
             int Kdim, int lda, int ldb,
             long long sA, long long sB, int epi,
             float* __restrict__ qlp, float* __restrict__ klp,
             unsigned short* __restrict__ q16, unsigned short* __restrict__ k16) {
  __shared__ float As[16][64], Bs[16][64];
  int bz = blockIdx.z;
  A += sA * bz; Bm += sB * bz;
  int n0 = blockIdx.x * 64, m0 = blockIdx.y * 64;
  int tid = threadIdx.x, tx = tid & 15, ty = tid >> 4;
  int am = tid >> 2, akg = tid & 3, bk = tid >> 4, bng = tid & 15;
  const float* Aload = A + (size_t)(m0 + am) * lda + akg * 4;
  const float* Bload = Bm + (size_t)bk * ldb + n0 + bng * 4;
  float acc[4][4] = {};
  for (int k0 = 0; k0 < Kdim; k0 += 16) {
    float4 av = *reinterpret_cast<const float4*>(Aload + k0);
    float4 bv = *reinterpret_cast<const float4*>(Bload + (size_t)k0 * ldb);
    __syncthreads();
    As[akg * 4 + 0][am] = av.x; As[akg * 4 + 1][am] = av.y;
    As[akg * 4 + 2][am] = av.z; As[akg * 4 + 3][am] = av.w;
    *reinterpret_cast<float4*>(&Bs[bk][bng * 4]) = bv;
    __syncthreads();
#pragma unroll
    for (int kk = 0; kk < 16; ++kk) {
      float4 bq = *reinterpret_cast<const float4*>(&Bs[kk][tx * 4]);
      float a0 = As[kk][ty * 4 + 0], a1 = As[kk][ty * 4 + 1];
      float a2 = As[kk][ty * 4 + 2], a3 = As[kk][ty * 4 + 3];
      acc[0][0] += a0 * bq.x; acc[0][1] += a0 * bq.y; acc[0][2] += a0 * bq.z; acc[0][3] += a0 * bq.w;
      acc[1][0] += a1 * bq.x; acc[1][1] += a1 * bq.y; acc[1][2] += a1 * bq.z; acc[1][3] += a1 * bq.w;
      acc[2][0] += a2 * bq.x; acc[2][1] += a2 * bq.y; acc[2][2] += a2 * bq.z; acc[2][3] += a2 * bq.w;
      acc[3][0] += a3 * bq.x; acc[3][1] += a3 * bq.y; acc[3][2] += a3 * bq.z; acc[3][3] += a3 * bq.w;
    }
  }
  if (epi == 5) {
#pragma unroll
    for (int i = 0; i < 4; ++i) {
      int gr = m0 + ty * 4 + i;
      int bidx = gr >> 8, nn = gr & 255;
#pragma unroll
      for (int j = 0; j < 4; ++j) {
        int gc = n0 + tx * 4 + j;
        int which = gc >> 9, hh = (gc >> 6) & 7, dd = gc & 63;
        float val = acc[i][j];
        if (which == 0) val *= 0.125f;
        size_t idx = (((size_t)(bidx * 8 + hh)) * 256 + nn) * 64 + dd;
        float* dst = which == 0 ? qlp : klp;
        unsigned short* dst16 = which == 0 ? q16 : k16;
        dst[idx] = val;
        dst16[idx] = f2b(val);
      }
    }
  } else {  // epi 7
#pragma unroll
    for (int i = 0; i < 4; ++i) {
      int gr = m0 + ty * 4 + i;
#pragma unroll
      for (int j = 0; j < 4; ++j) {
        int gc = n0 + tx * 4 + j;
        q16[(size_t)bz * 16384 + (size_t)gr * 64 + gc] = f2b(acc[i][j]);
      }
    }
  }
}

// ------------- GEMM C = A[M,64] @ B[N,64]^T (sim2) -------------
__global__ __launch_bounds__(256)
void gemm_abt(const float* __restrict__ A, const float* __restrict__ Bm,
              float* __restrict__ C, int Kdim, int lda, int ldb, int ldc,
              long long sA, long long sB, long long sC) {
  __shared__ float As[16][64], Bs[16][64];
  int bz = blockIdx.z;
  A += sA * bz; Bm += sB * bz; C += sC * bz;
  int n0 = blockIdx.x * 64, m0 = blockIdx.y * 64;
  int tid = threadIdx.x, tx = tid & 15, ty = tid >> 4;
  int am = tid >> 2, akg = tid & 3;
  const float* Aload = A + (size_t)(m0 + am) * lda + akg * 4;
  const float* Bload = Bm + (size_t)(n0 + am) * ldb + akg * 4;
  float acc[4][4] = {};
  for (int k0 = 0; k0 < Kdim; k0 += 16) {
    float4 av = *reinterpret_cast<const float4*>(Aload + k0);
    float4 bv = *reinterpret_cast<const float4*>(Bload + k0);
    __syncthreads();
    As[akg * 4 + 0][am] = av.x; As[akg * 4 + 1][am] = av.y;
    As[akg * 4 + 2][am] = av.z; As[akg * 4 + 3][am] = av.w;
    Bs[akg * 4 + 0][am] = bv.x; Bs[akg * 4 + 1][am] = bv.y;
    Bs[akg * 4 + 2][am] = bv.z; Bs[akg * 4 + 3][am] = bv.w;
    __syncthreads();
#pragma unroll
    for (int kk = 0; kk < 16; ++kk) {
      float4 bq = *reinterpret_cast<const float4*>(&Bs[kk][tx * 4]);
      float a0 = As[kk][ty * 4 + 0], a1 = As[kk][ty * 4 + 1];
      float a2 = As[kk][ty * 4 + 2], a3 = As[kk][ty * 4 + 3];
      acc[0][0] += a0 * bq.x; acc[0][1] += a0 * bq.y; acc[0][2] += a0 * bq.z; acc[0][3] += a0 * bq.w;
      acc[1][0] += a1 * bq.x; acc[1][1] += a1 * bq.y; acc[1][2] += a1 * bq.z; acc[1][3] += a1 * bq.w;
      acc[2][0] += a2 * bq.x; acc[2][1] += a2 * bq.y; acc[2][2] += a2 * bq.z; acc[2][3] += a2 * bq.w;
      acc[3][0] += a3 * bq.x; acc[3][1] += a3 * bq.y; acc[3][2] += a3 * bq.z; acc[3][3] += a3 * bq.w;
    }
  }
#pragma unroll
  for (int i = 0; i < 4; ++i) {
    int gr = m0 + ty * 4 + i;
#pragma unroll
    for (int j = 0; j < 4; ++j)
      C[(size_t)gr * ldc + n0 + tx * 4 + j] = acc[i][j];
  }
}

// ------------- row softmax (256 cols) -------------
__global__ __launch_bounds__(256) void softmax_rows256(float* __restrict__ buf) {
  __shared__ float red[4];
  size_t row = blockIdx.x;
  float* r = buf + row * 256;
  int tid = threadIdx.x, lane = tid & 63, wid = tid >> 6;
  float v = r[tid];
  float mx = wave_max(v);
  if (!lane) red[wid] = mx;
  __syncthreads();
  mx = fmaxf(fmaxf(red[0], red[1]), fmaxf(red[2], red[3]));
  __syncthreads();
  float e = expf(v - mx);
  float s = wave_sum(e);
  if (!lane) red[wid] = s;
  __syncthreads();
  s = red[0] + red[1] + red[2] + red[3];
  r[tid] = e / s;
}

// ------------- pinv scalar: max column-sum -------------
__global__ void init_scalars(float* sc) { if (threadIdx.x < 2) sc[threadIdx.x] = 0.f; }

__global__ __launch_bounds__(256) void colsum_part(const float* __restrict__ a2,
                                                   float* __restrict__ part) {
  int bh = blockIdx.x >> 3, chunk = blockIdx.x & 7;
  int tid = threadIdx.x;
  const float* M = a2 + (size_t)bh * 65536 + (size_t)chunk * 32 * 256;
  float acc = 0.f;
#pragma unroll
  for (int r = 0; r < 32; ++r) acc += M[r * 256 + tid];
  part[(size_t)blockIdx.x * 256 + tid] = acc;
}

__global__ __launch_bounds__(256) void colsum_final(const float* __restrict__ part,
                                                    float* __restrict__ sc) {
  __shared__ float red[4];
  int bh = blockIdx.x;
  int tid = threadIdx.x, lane = tid & 63, w = tid >> 6;
  float s = 0.f;
#pragma unroll
  for (int c = 0; c < 8; ++c) s += part[(size_t)(bh * 8 + c) * 256 + tid];
  float m = wave_max(s);
  if (!lane) red[w] = m;
  __syncthreads();
  if (tid == 0) {
    float mm = fmaxf(fmaxf(red[0], red[1]), fmaxf(red[2], red[3]));
    atomicMax(reinterpret_cast<int*>(sc) + 1, __float_as_int(mm));
  }
}

// ------------- split attn2 hi/lo bf16: X, z0=X^T/c, z0^T=X/c -------------
__global__ __launch_bounds__(256) void hilo_split(
    const float* __restrict__ a2, const float* __restrict__ sc,
    unsigned short* __restrict__ Xh, unsigned short* __restrict__ Xl,
    unsigned short* __restrict__ zth, unsigned short* __restrict__ ztl,
    unsigned short* __restrict__ zh, unsigned short* __restrict__ zl) {
  __shared__ float t[64][65];
  int bz = blockIdx.z;
  size_t base = (size_t)bz * 65536;
  int i0 = blockIdx.y * 64, j0 = blockIdx.x * 64;
  int tid = threadIdx.x, tx = tid & 15, ty = tid >> 4;
  float inv = 1.f / sc[1];
#pragma unroll
  for (int rr = 0; rr < 64; rr += 16) {
    int gr = i0 + rr + ty, gc0 = j0 + tx * 4;
    float4 v = *(const float4*)&a2[base + (size_t)gr * 256 + gc0];
    t[rr + ty][tx * 4 + 0] = v.x; t[rr + ty][tx * 4 + 1] = v.y;
    t[rr + ty][tx * 4 + 2] = v.z; t[rr + ty][tx * 4 + 3] = v.w;
    ushort4 xh, xl2, sh, sl;
    float vv[4] = {v.x, v.y, v.z, v.w};
    unsigned short* ph = (unsigned short*)&xh;
    unsigned short* pl = (unsigned short*)&xl2;
    unsigned short* qh = (unsigned short*)&sh;
    unsigned short* ql2 = (unsigned short*)&sl;
#pragma unroll
    for (int j = 0; j < 4; ++j) {
      ph[j] = f2b(vv[j]);
      pl[j] = f2b(vv[j] - b2f(ph[j]));
      float s = vv[j] * inv;
      qh[j] = f2b(s);
      ql2[j] = f2b(s - b2f(qh[j]));
    }
    *(ushort4*)&Xh[base + (size_t)gr * 256 + gc0] = xh;
    *(ushort4*)&Xl[base + (size_t)gr * 256 + gc0] = xl2;
    *(ushort4*)&zth[base + (size_t)gr * 256 + gc0] = sh;
    *(ushort4*)&ztl[base + (size_t)gr * 256 + gc0] = sl;
  }
  __syncthreads();
#pragma unroll
  for (int rr = 0; rr < 64; rr += 16) {
    int gr = j0 + rr + ty;
    int gc0 = i0 + tx * 4;
    ushort4 zh4, zl4;
    unsigned short* ph = (unsigned short*)&zh4;
    unsigned short* pl = (unsigned short*)&zl4;
#pragma unroll
    for (int j = 0; j < 4; ++j) {
      float s = t[tx * 4 + j][rr + ty] * inv;
      ph[j] = f2b(s);
      pl[j] = f2b(s - b2f(ph[j]));
    }
    *(ushort4*)&zh[base + (size_t)gr * 256 + gc0] = zh4;
    *(ushort4*)&zl[base + (size_t)gr * 256 + gc0] = zl4;
  }
}

// ------------- NS hi/lo MFMA GEMM -------------
__global__ __launch_bounds__(256) void ns_mfma(
    const unsigned short* __restrict__ Ah, const unsigned short* __restrict__ Al,
    const unsigned short* __restrict__ Bth, const unsigned short* __restrict__ Btl,
    const unsigned short* __restrict__ Eh, const unsigned short* __restrict__ El,
    float alpha, float diag, float beta,
    unsigned short* __restrict__ Ch, unsigned short* __restrict__ Cl,
    unsigned short* __restrict__ CTh, unsigned short* __restrict__ CTl,
    float* __restrict__ Cf) {
  __shared__ __align__(16) unsigned short AhS[64][72], AlS[64][72];
  __shared__ __align__(16) unsigned short BhS[64][72], BlS[64][72];
  const int tid = threadIdx.x;
  const int l16 = tid & 15, h8 = (tid & 63) >> 4, w = tid >> 6;
  const size_t base = (size_t)blockIdx.z * 65536;
  const int m0 = blockIdx.y * 64, n0 = blockIdx.x * 64;
  const int wr = (w >> 1) * 32, wc = (w & 1) * 32;
  const int srow = tid >> 2, scol = (tid & 3) * 16;
  f32x4 acc[2][2] = {};
  for (int k0 = 0; k0 < 256; k0 += 64) {
    const size_t aoff = base + (size_t)(m0 + srow) * 256 + k0 + scol;
    const size_t boff = base + (size_t)(n0 + srow) * 256 + k0 + scol;
    *(u16x8*)&AhS[srow][scol] = *(const u16x8*)(Ah + aoff);
    *(u16x8*)&AhS[srow][scol + 8] = *(const u16x8*)(Ah + aoff + 8);
    *(u16x8*)&AlS[srow][scol] = *(const u16x8*)(Al + aoff);
    *(u16x8*)&AlS[srow][scol + 8] = *(const u16x8*)(Al + aoff + 8);
    *(u16x8*)&BhS[srow][scol] = *(const u16x8*)(Bth + boff);
    *(u16x8*)&BhS[srow][scol + 8] = *(const u16x8*)(Bth + boff + 8);
    *(u16x8*)&BlS[srow][scol] = *(const u16x8*)(Btl + boff);
    *(u16x8*)&BlS[srow][scol + 8] = *(const u16x8*)(Btl + boff + 8);
    __syncthreads();
#pragma unroll
    for (int ks = 0; ks < 2; ++ks) {
      bf16x8 ah[2], al[2], bh[2], bl[2];
#pragma unroll
      for (int mi = 0; mi < 2; ++mi) {
        ah[mi] = *(const bf16x8*)&AhS[wr + mi * 16 + l16][ks * 32 + h8 * 8];
        al[mi] = *(const bf16x8*)&AlS[wr + mi * 16 + l16][ks * 32 + h8 * 8];
      }
#pragma unroll
      for (int nj = 0; nj < 2; ++nj) {
        bh[nj] = *(const bf16x8*)&BhS[wc + nj * 16 + l16][ks * 32 + h8 * 8];
        bl[nj] = *(const bf16x8*)&BlS[wc + nj * 16 + l16][ks * 32 + h8 * 8];
      }
#pragma unroll
      for (int mi = 0; mi < 2; ++mi)
#pragma unroll
        for (int nj = 0; nj < 2; ++nj) {
          acc[mi][nj] = mfma16(ah[mi], bh[nj], acc[mi][nj]);
          acc[mi][nj] = mfma16(ah[mi], bl[nj], acc[mi][nj]);
          acc[mi][nj] = mfma16(al[mi], bh[nj], acc[mi][nj]);
        }
    }
    __syncthreads();
  }
#pragma unroll
  for (int mi = 0; mi < 2; ++mi)
#pragma unroll
    for (int nj = 0; nj < 2; ++nj) {
      int grow0 = m0 + wr + mi * 16 + 4 * h8;
      int gcol = n0 + wc + nj * 16 + l16;
      float vals[4];
      ushort4 th, tl;
      unsigned short* ph = (unsigned short*)&th;
      unsigned short* pl = (unsigned short*)&tl;
#pragma unroll
      for (int r = 0; r < 4; ++r) {
        int grow = grow0 + r;
        float v = alpha * acc[mi][nj][r];
        if (grow == gcol) v += diag;
        if (Eh) v += beta * (b2f(Eh[base + (size_t)grow * 256 + gcol]) +
                             b2f(El[base + (size_t)grow * 256 + gcol]));
        vals[r] = v;
        ph[r] = f2b(v);
        pl[r] = f2b(v - b2f(ph[r]));
      }
      if (Ch) {
#pragma unroll
        for (int r = 0; r < 4; ++r) {
          Ch[base + (size_t)(grow0 + r) * 256 + gcol] = ph[r];
          Cl[base + (size_t)(grow0 + r) * 256 + gcol] = pl[r];
        }
      }
      if (CTh) {
        *(ushort4*)&CTh[base + (size_t)gcol * 256 + grow0] = th;
        *(ushort4*)&CTl[base + (size_t)gcol * 256 + grow0] = tl;
      }
      if (Cf) {
#pragma unroll
        for (int r = 0; r < 4; ++r)
          Cf[base + (size_t)(grow0 + r) * 256 + gcol] = vals[r];
      }
    }
}

// ------------- MFMA flash, transposed PV accumulator -------------
// MODE 0: split-K partials (float4 Opart + ML)   MODE 1: fused conv + bf16 outh
template <int MODE>
__global__ __launch_bounds__(256) void flash_mfma(
    const unsigned short* __restrict__ Q, const unsigned short* __restrict__ Kp,
    const unsigned short* __restrict__ Vp, long long sQ, long long sK,
    int kps, int nkt,
    float* __restrict__ Opart, float* __restrict__ MLpart,
    unsigned short* __restrict__ outh16,
    const unsigned short* __restrict__ vconv, const float* __restrict__ cw) {
  __shared__ __align__(16) unsigned short Qt[128][72];
  __shared__ __align__(16) unsigned short Kt[64][72];
  __shared__ __align__(16) unsigned short Vt[64][72];
  __shared__ __align__(16) unsigned short Pb[128][72];
  __shared__ __align__(16) unsigned short Vc[MODE ? 160 : 1][72];
  __shared__ float scfb[128], linvb[128], wt[33];
  const int tid = threadIdx.x;
  const int l16 = tid & 15, h8 = (tid & 63) >> 4, w = tid >> 6;
  const int bh = blockIdx.y, s = blockIdx.z, qt = blockIdx.x;
  const int q0 = qt * 128;
  const unsigned short* Qb = Q + (size_t)bh * sQ + (size_t)q0 * 64;
  const unsigned short* Kb = Kp + (size_t)bh * sK + (size_t)s * kps * 64;
  const unsigned short* Vb = Vp + (size_t)bh * sK + (size_t)s * kps * 64;
  {
    int row = tid >> 1, c0 = (tid & 1) * 32;
#pragma unroll
    for (int i = 0; i < 4; ++i)
      *(u16x8*)&Qt[row][c0 + 8 * i] = *(const u16x8*)(Qb + (size_t)row * 64 + c0 + 8 * i);
  }
  if (MODE == 1) {
    if (tid < 33) wt[tid] = cw[(bh & 7) * 33 + tid];
    const unsigned short* vB = vconv + (size_t)bh * NTOK * 64;
    for (int c = tid; c < 1280; c += 256) {
      int row = c >> 3, c8 = (c & 7) * 8;
      int rn = q0 - 16 + row;
      u16x8 val;
#pragma unroll
      for (int i = 0; i < 8; ++i) val[i] = 0;
      if (rn >= 0 && rn < NTOK) val = *(const u16x8*)(vB + (size_t)rn * 64 + c8);
      *(u16x8*)&Vc[row][c8] = val;
    }
  }
  f32x4 acc_o[2][4] = {};   // transposed: [mi] q-row = w*32+mi*16+l16 ; d = dj*16+4h8+r
  float mrow[2][4], lrow[2][4];
#pragma unroll
  for (int mi = 0; mi < 2; ++mi)
#pragma unroll
    for (int r = 0; r < 4; ++r) { mrow[mi][r] = -1e30f; lrow[mi][r] = 0.f; }
  for (int kt = 0; kt < nkt; ++kt) {
    {
      int row = tid >> 2, c0 = (tid & 3) * 16;
      *(u16x8*)&Kt[row][c0] = *(const u16x8*)(Kb + ((size_t)(kt * 64 + row)) * 64 + c0);
      *(u16x8*)&Kt[row][c0 + 8] = *(const u16x8*)(Kb + ((size_t)(kt * 64 + row)) * 64 + c0 + 8);
      int key = tid & 63, d0 = w * 16;
      u16x8 v0 = *(const u16x8*)(Vb + ((size_t)(kt * 64 + key)) * 64 + d0);
      u16x8 v1 = *(const u16x8*)(Vb + ((size_t)(kt * 64 + key)) * 64 + d0 + 8);
#pragma unroll
      for (int i = 0; i < 8; ++i) { Vt[d0 + i][key] = v0[i]; Vt[d0 + 8 + i][key] = v1[i]; }
    }
    __syncthreads();
    f32x4 accs[2][4] = {};   // QK^T: rows = q (4h8+r), cols = key (l16)
#pragma unroll
    for (int ks = 0; ks < 2; ++ks) {
      bf16x8 a[2], b[4];
      a[0] = *(const bf16x8*)&Qt[w * 32 + l16][ks * 32 + h8 * 8];
      a[1] = *(const bf16x8*)&Qt[w * 32 + 16 + l16][ks * 32 + h8 * 8];
#pragma unroll
      for (int nj = 0; nj < 4; ++nj)
        b[nj] = *(const bf16x8*)&Kt[nj * 16 + l16][ks * 32 + h8 * 8];
#pragma unroll
      for (int mi = 0; mi < 2; ++mi)
#pragma unroll
        for (int nj = 0; nj < 4; ++nj)
          accs[mi][nj] = mfma16(a[mi], b[nj], accs[mi][nj]);
    }
#pragma unroll
    for (int mi = 0; mi < 2; ++mi)
#pragma unroll
      for (int r = 0; r < 4; ++r) {
        float mx = fmaxf(fmaxf(accs[mi][0][r], accs[mi][1][r]),
                         fmaxf(accs[mi][2][r], accs[mi][3][r]));
#pragma unroll
        for (int off = 8; off; off >>= 1) mx = fmaxf(mx, __shfl_xor(mx, off, 64));
        float mn = fmaxf(mrow[mi][r], mx);
        float scf = __expf(mrow[mi][r] - mn);
        float ps = 0.f;
#pragma unroll
        for (int nj = 0; nj < 4; ++nj) {
          float p = __expf(accs[mi][nj][r] - mn);
          accs[mi][nj][r] = p;
          ps += p;
        }
#pragma unroll
        for (int off = 8; off; off >>= 1) ps += __shfl_xor(ps, off, 64);
        lrow[mi][r] = lrow[mi][r] * scf + ps;
        mrow[mi][r] = mn;
        int prow = w * 32 + mi * 16 + 4 * h8 + r;
        scfb[prow] = scf;
#pragma unroll
        for (int nj = 0; nj < 4; ++nj)
          Pb[prow][nj * 16 + l16] = f2b(accs[mi][nj][r]);
      }
    __syncthreads();
#pragma unroll
    for (int mi = 0; mi < 2; ++mi) {
      float sc2 = scfb[w * 32 + mi * 16 + l16];
#pragma unroll
      for (int dj = 0; dj < 4; ++dj) {
        acc_o[mi][dj][0] *= sc2; acc_o[mi][dj][1] *= sc2;
        acc_o[mi][dj][2] *= sc2; acc_o[mi][dj][3] *= sc2;
      }
    }
#pragma unroll
    for (int ks = 0; ks < 2; ++ks) {
      bf16x8 pa[2], vb2[4];
      pa[0] = *(const bf16x8*)&Pb[w * 32 + l16][ks * 32 + h8 * 8];
      pa[1] = *(const bf16x8*)&Pb[w * 32 + 16 + l16][ks * 32 + h8 * 8];
#pragma unroll
      for (int dj = 0; dj < 4; ++dj)
        vb2[dj] = *(const bf16x8*)&Vt[dj * 16 + l16][ks * 32 + h8 * 8];
#pragma unroll
      for (int mi = 0; mi < 2; ++mi)
#pragma unroll
        for (int dj = 0; dj < 4; ++dj)
          acc_o[mi][dj] = mfma16(vb2[dj], pa[mi], acc_o[mi][dj]);  // swapped
    }
    __syncthreads();
  }
  if (MODE == 0) {
    int p = (s * 32 + bh) * 2 + qt;
    float* Ob = Opart + (size_t)p * 8192;
#pragma unroll
    for (int mi = 0; mi < 2; ++mi) {
      int row = w * 32 + mi * 16 + l16;
#pragma unroll
      for (int dj = 0; dj < 4; ++dj) {
        int d0 = dj * 16 + 4 * h8;
        *(float4*)&Ob[(size_t)row * 64 + d0] =
            make_float4(acc_o[mi][dj][0], acc_o[mi][dj][1], acc_o[mi][dj][2], acc_o[mi][dj][3]);
      }
#pragma unroll
      for (int r = 0; r < 4; ++r) {
        int prow = w * 32 + mi * 16 + 4 * h8 + r;
        if (l16 == 0) {
          MLpart[((size_t)p * 128 + prow) * 2] = mrow[mi][r];
          MLpart[((size_t)p * 128 + prow) * 2 + 1] = lrow[mi][r];
        }
      }
    }
  } else {
    int bidx = bh >> 3, hh = bh & 7;
#pragma unroll
    for (int mi = 0; mi < 2; ++mi)
#pragma unroll
      for (int r = 0; r < 4; ++r)
        linvb[w * 32 + mi * 16 + 4 * h8 + r] = 1.f / lrow[mi][r];
    __syncthreads();
#pragma unroll
    for (int mi = 0; mi < 2; ++mi) {
      int jrow = w * 32 + mi * 16 + l16;          // q-row within block
      float linv = linvb[jrow];
      int qr = q0 + jrow;
#pragma unroll
      for (int dj = 0; dj < 4; ++dj) {
        int d0 = dj * 16 + 4 * h8;
        float cv0 = 0.f, cv1 = 0.f, cv2 = 0.f, cv3 = 0.f;
#pragma unroll 11
        for (int k = 0; k < 33; ++k) {
          float wk = wt[k];
          ushort4 vv = *(const ushort4*)&Vc[jrow + k][d0];
          cv0 += wk * b2f(vv.x); cv1 += wk * b2f(vv.y);
          cv2 += wk * b2f(vv.z); cv3 += wk * b2f(vv.w);
        }
        ushort4 o;
        o.x = f2b(acc_o[mi][dj][0] * linv + cv0);
        o.y = f2b(acc_o[mi][dj][1] * linv + cv1);
        o.z = f2b(acc_o[mi][dj][2] * linv + cv2);
        o.w = f2b(acc_o[mi][dj][3] * linv + cv3);
        *(ushort4*)&outh16[((size_t)bidx * NTOK + qr) * 512 + hh * 64 + d0] = o;
      }
    }
  }
}

// ------------- combine split-K flash partials -> T3 -------------
__global__ __launch_bounds__(256) void flash_combine(const float* __restrict__ Opart,
                                                     const float* __restrict__ MLpart,
                                                     float* __restrict__ T3) {
  int bh = blockIdx.y;
  int row = blockIdx.x * 4 + (threadIdx.x >> 6);
  int d = threadIdx.x & 63;
  int qt = row >> 7, rowin = row & 127;
  float mstar = -1e30f;
#pragma unroll
  for (int s = 0; s < 8; ++s) {
    int p = (s * 32 + bh) * 2 + qt;
    mstar = fmaxf(mstar, MLpart[((size_t)p * 128 + rowin) * 2]);
  }
  float L = 0.f, O = 0.f;
#pragma unroll
  for (int s = 0; s < 8; ++s) {
    int p = (s * 32 + bh) * 2 + qt;
    float ms = MLpart[((size_t)p * 128 + rowin) * 2];
    float ls = MLpart[((size_t)p * 128 + rowin) * 2 + 1];
    float e = __expf(ms - mstar);
    L += ls * e;
    O += Opart[(size_t)p * 8192 + rowin * 64 + d] * e;
  }
  T3[((size_t)bh * 256 + row) * 64 + d] = O / L;
}

extern "C" void kernel_launch(void* const* d_in, const int* in_sizes, int n_in,
                              void* d_out, int out_size, void* d_ws, size_t ws_size,
                              hipStream_t stream) {
  const float* x = (const float*)d_in[0];
  const float* gamma = (const float*)d_in[1];
  const float* beta = (const float*)d_in[2];
  const float* w_qkv = (const float*)d_in[3];
  const float* w_out = (const float*)d_in[4];
  const float* b_out = (const float*)d_in[5];
  const float* conv_w = (const float*)d_in[6];
  float* out = (float*)d_out;
  float* ws = (float*)d_ws;
  (void)ws_size; (void)in_sizes; (void)n_in; (void)out_size;

  float* A0 = ws;
  float* Breg = ws + 16777216;
  unsigned short* qb = (unsigned short*)(ws + 25165824);
  unsigned short* kb = (unsigned short*)(ws + 33554432);
  unsigned short* vb = (unsigned short*)(ws + 41943040);
  float* Fs = ws + 50331648;

  // A0 tenants
  float* X2 = A0;
  float* zfinal = A0;
  float* ql = A0 + 2097152;
  float* kl = A0 + 2621440;
  unsigned short* Xh  = (unsigned short*)(A0 + 2097152);
  unsigned short* Xl  = (unsigned short*)(A0 + 3145728);
  unsigned short* zAh = (unsigned short*)(A0 + 4194304);
  unsigned short* zAl = (unsigned short*)(A0 + 5242880);
  unsigned short* zAth = (unsigned short*)(A0 + 6291456);
  unsigned short* zAtl = (unsigned short*)(A0 + 7340032);
  unsigned short* zYh = (unsigned short*)(A0 + 8388608);
  unsigned short* zYl = (unsigned short*)(A0 + 9437184);
  unsigned short* zYth = (unsigned short*)(A0 + 10485760);
  unsigned short* zYtl = (unsigned short*)(A0 + 11534336);
  unsigned short* TBth = (unsigned short*)(A0 + 12582912);
  unsigned short* TBtl = (unsigned short*)(A0 + 13631488);
  unsigned short* TAth = (unsigned short*)(A0 + 14680064);
  unsigned short* TAtl = (unsigned short*)(A0 + 15728640);
  unsigned short* outh16 = (unsigned short*)A0;   // [0 .. 8,388,608 floats)
  // Breg tenants
  unsigned short* xnb = (unsigned short*)Breg;
  float* Opart = Breg;
  float* MLpart = Breg + 4194304;
  float* T3 = Breg + 4325376;
  // Fs tenants
  float* xl = Fs;
  unsigned short* qlb = (unsigned short*)(Fs + 524288);
  unsigned short* klb = (unsigned short*)(Fs + 786432);
  unsigned short* W2b = (unsigned short*)(Fs + 1048576);
  unsigned short* woutT = (unsigned short*)(Fs + 1310720);
  unsigned short* wqkvT = (unsigned short*)(Fs + 1441792);
  float* part = Fs + 1835008;
  float* sc = Fs + 1900544;

  // 1. fused LayerNorm + pooling
  ln_pool<<<1024, 256, 0, stream>>>(x, gamma, beta, xnb, xl);
  // 2. weight transposes
  transpose_cvt<<<dim3(48, 16), 256, 0, stream>>>(w_qkv, wqkvT, 512, 1536);
  transpose_cvt<<<dim3(16, 16), 256, 0, stream>>>(w_out, woutT, 512, 512);
  // 3. qkv projection (swapped-fragment ushort4 scatter)
  gemm_mfma<0><<<dim3(12, 256), 256, 0, stream>>>(xnb, wqkvT, 512, qb, kb, vb,
                                                  nullptr, nullptr, nullptr);
  // 4. ql/kl = xl @ Wq/Wk fp32 (+ bf16 fused)
  gemm_ab<<<dim3(16, 16, 1), 256, 0, stream>>>(xl, w_qkv, 512, 512, 1536, 0, 0,
                                               5, ql, kl, qlb, klb);
  // 5. sim2 -> attn2 (fp32)
  gemm_abt<<<dim3(4, 4, BH), 256, 0, stream>>>(ql, kl, X2, 64, 64, 64, 256,
                                               16384, 16384, 65536);
  softmax_rows256<<<BH * NM, 256, 0, stream>>>(X2);
  // 6. pinv scalar + hi/lo split
  init_scalars<<<1, 64, 0, stream>>>(sc);
  colsum_part<<<BH * 8, 256, 0, stream>>>(X2, part);
  colsum_final<<<BH, 256, 0, stream>>>(part, sc);
  hilo_split<<<dim3(4, 4, BH), 256, 0, stream>>>(X2, sc, Xh, Xl, zAth, zAtl, zAh, zAl);
  // 7. Newton-Schulz hi/lo MFMA
  unsigned short *ch = zAh, *cl = zAl, *cth = zAth, *ctl = zAtl;
  unsigned short *yh = zYh, *yl = zYl, *yth = zYth, *ytl = zYtl;
  for (int it = 0; it < 6; ++it) {
    ns_mfma<<<dim3(4, 4, BH), 256, 0, stream>>>(Xh, Xl, cth, ctl, nullptr, nullptr,
                                                1.f, 0.f, 0.f, yh, yl, yth, ytl, nullptr);
    ns_mfma<<<dim3(4, 4, BH), 256, 0, stream>>>(yh, yl, yth, ytl, yh, yl,
                                                1.f, 15.f, -7.f, nullptr, nullptr,
                                                TBth, TBtl, nullptr);
    ns_mfma<<<dim3(4, 4, BH), 256, 0, stream>>>(yh, yl, TBth, TBtl, nullptr, nullptr,
                                                -1.f, 13.f, 0.f, nullptr, nullptr,
                                                TAth, TAtl, nullptr);
    ns_mfma<<<dim3(4, 4, BH), 256, 0, stream>>>(ch, cl, TAth, TAtl, nullptr, nullptr,
                                                0.25f, 0.f, 0.f, yh, yl, yth, ytl,
                                                it == 5 ? zfinal : nullptr);
    unsigned short* t;
    t = ch; ch = yh; yh = t;  t = cl; cl = yl; yl = t;
    t = cth; cth = yth; yth = t;  t = ctl; ctl = ytl; ytl = t;
  }
  // 8. flash A (split-K=8)
  flash_mfma<0><<<dim3(2, 32, 8), 256, 0, stream>>>(qlb, kb, vb, 16384, 524288,
                                                    1024, 16, Opart, MLpart,
                                                    nullptr, nullptr, nullptr);
  flash_combine<<<dim3(64, 32), 256, 0, stream>>>(Opart, MLpart, T3);
  // 9. W2 = pinv @ T3 -> bf16
  gemm_ab<<<dim3(1, 4, BH), 256, 0, stream>>>(zfinal, T3, 256, 256, 64, 65536, 16384,
                                              7, nullptr, nullptr, W2b, nullptr);
  // 10. flash B + fused conv -> bf16 outh
  flash_mfma<1><<<dim3(64, 32, 1), 256, 0, stream>>>(qb, klb, W2b, 524288, 16384,
                                                     0, 4, nullptr, nullptr,
                                                     outh16, vb, conv_w);
  // 11. out = x + outh @ w_out + b_out
  gemm_mfma<2><<<dim3(4, 256), 256, 0, stream>>>(outh16, woutT, 512, nullptr, nullptr,
                                                 nullptr, out, b_out, x);
}

// Round 9
// 745.471 us; speedup vs baseline: 4.1165x; 1.0193x over previous
//
#include <hip/hip_runtime.h>

#define NTOK 8192
#define TOT 32768
#define DMODEL 512
#define NM 256
#define BH 32

typedef __attribute__((ext_vector_type(8))) short bf16x8;
typedef __attribute__((ext_vector_type(8))) unsigned short u16x8;
typedef __attribute__((ext_vector_type(4))) float f32x4;

__device__ __forceinline__ unsigned short f2b(float f) {
  unsigned u = __float_as_uint(f);
  return (unsigned short)((u + 0x7fffu + ((u >> 16) & 1u)) >> 16);
}
__device__ __forceinline__ float b2f(unsigned short h) {
  return __uint_as_float((unsigned)h << 16);
}
__device__ __forceinline__ f32x4 mfma16(bf16x8 a, bf16x8 b, f32x4 c) {
  return __builtin_amdgcn_mfma_f32_16x16x32_bf16(a, b, c, 0, 0, 0);
}
__device__ __forceinline__ float wave_sum(float v) {
#pragma unroll
  for (int o = 32; o; o >>= 1) v += __shfl_xor(v, o, 64);
  return v;
}
__device__ __forceinline__ float wave_max(float v) {
#pragma unroll
  for (int o = 32; o; o >>= 1) v = fmaxf(v, __shfl_xor(v, o, 64));
  return v;
}

// ------------- fused LayerNorm + pooling, wave-per-row -------------
__global__ __launch_bounds__(256) void ln_pool(const float* __restrict__ x,
                                               const float* __restrict__ g,
                                               const float* __restrict__ b,
                                               unsigned short* __restrict__ xnb,
                                               float* __restrict__ xl) {
  __shared__ float pp[4][512];
  int tid = threadIdx.x, lane = tid & 63, w = tid >> 6;
  int c0 = lane * 8;
  float4 g0 = *(const float4*)&g[c0], g1 = *(const float4*)&g[c0 + 4];
  float4 b0 = *(const float4*)&b[c0], b1 = *(const float4*)&b[c0 + 4];
  float pa[8] = {};
  size_t rbase = (size_t)blockIdx.x * 32 + w * 8;
  for (int j = 0; j < 8; ++j) {
    size_t row = rbase + j;
    float4 v0 = *(const float4*)&x[row * DMODEL + c0];
    float4 v1 = *(const float4*)&x[row * DMODEL + c0 + 4];
    float s = v0.x + v0.y + v0.z + v0.w + v1.x + v1.y + v1.z + v1.w;
    float ss = v0.x * v0.x + v0.y * v0.y + v0.z * v0.z + v0.w * v0.w +
               v1.x * v1.x + v1.y * v1.y + v1.z * v1.z + v1.w * v1.w;
    s = wave_sum(s);
    ss = wave_sum(ss);
    float mu = s * (1.f / DMODEL);
    float var = ss * (1.f / DMODEL) - mu * mu;
    float rstd = rsqrtf(var + 1e-5f);
    float o[8];
    o[0] = (v0.x - mu) * rstd * g0.x + b0.x; o[1] = (v0.y - mu) * rstd * g0.y + b0.y;
    o[2] = (v0.z - mu) * rstd * g0.z + b0.z; o[3] = (v0.w - mu) * rstd * g0.w + b0.w;
    o[4] = (v1.x - mu) * rstd * g1.x + b1.x; o[5] = (v1.y - mu) * rstd * g1.y + b1.y;
    o[6] = (v1.z - mu) * rstd * g1.z + b1.z; o[7] = (v1.w - mu) * rstd * g1.w + b1.w;
    u16x8 pk;
#pragma unroll
    for (int i = 0; i < 8; ++i) { pk[i] = f2b(o[i]); pa[i] += o[i]; }
    *(u16x8*)&xnb[row * DMODEL + c0] = pk;
  }
  *(float4*)&pp[w][c0] = make_float4(pa[0], pa[1], pa[2], pa[3]);
  *(float4*)&pp[w][c0 + 4] = make_float4(pa[4], pa[5], pa[6], pa[7]);
  __syncthreads();
#pragma unroll
  for (int c = tid; c < 512; c += 256) {
    float s = pp[0][c] + pp[1][c] + pp[2][c] + pp[3][c];
    xl[(size_t)blockIdx.x * DMODEL + c] = s * (1.f / 32.f);
  }
}

// ------------- transpose + cvt fp32[K][N] -> bf16[N][K] -------------
__global__ __launch_bounds__(256) void transpose_cvt(const float* __restrict__ in,
                                                     unsigned short* __restrict__ outp,
                                                     int K, int N) {
  __shared__ float t[32][33];
  int k0 = blockIdx.y * 32, n0 = blockIdx.x * 32;
  int tx = threadIdx.x & 31, ty = threadIdx.x >> 5;
#pragma unroll
  for (int i = 0; i < 32; i += 8)
    t[ty + i][tx] = in[(size_t)(k0 + ty + i) * N + n0 + tx];
  __syncthreads();
#pragma unroll
  for (int i = 0; i < 32; i += 8)
    outp[(size_t)(n0 + ty + i) * K + k0 + tx] = f2b(t[tx][ty + i]);
}

// ------------- MFMA GEMM NT, swapped-fragment epilogue -------------
// EPI 0: scatter qkv (q*0.125) as bf16, ushort4 stores
// EPI 2: Cf = AB + bias + resid, float4 stores
template <int EPI>
__global__ __launch_bounds__(256) void gemm_mfma(const unsigned short* __restrict__ Ab,
                                                 const unsigned short* __restrict__ Bt,
                                                 int Kd,
                                                 unsigned short* __restrict__ qo,
                                                 unsigned short* __restrict__ ko,
                                                 unsigned short* __restrict__ vo,
                                                 float* __restrict__ Cf,
                                                 const float* __restrict__ bias,
                                                 const float* __restrict__ resid) {
  __shared__ __align__(16) unsigned short As[128][72];
  __shared__ __align__(16) unsigned short Bs[128][72];
  const int tid = threadIdx.x;
  const int l16 = tid & 15, h8 = (tid & 63) >> 4, w = tid >> 6;
  const int m0 = blockIdx.y * 128, n0 = blockIdx.x * 128;
  const int wr = (w >> 1) * 64, wc = (w & 1) * 64;
  const int srow = tid >> 1, sc0 = (tid & 1) * 32;
  f32x4 acc[4][4] = {};
  for (int k0 = 0; k0 < Kd; k0 += 64) {
    const unsigned short* Ap = Ab + (size_t)(m0 + srow) * Kd + k0 + sc0;
#pragma unroll
    for (int i = 0; i < 4; ++i)
      *(u16x8*)&As[srow][sc0 + 8 * i] = *(const u16x8*)(Ap + 8 * i);
    const unsigned short* Bb = Bt + (size_t)(n0 + srow) * Kd + k0 + sc0;
#pragma unroll
    for (int i = 0; i < 4; ++i)
      *(u16x8*)&Bs[srow][sc0 + 8 * i] = *(const u16x8*)(Bb + 8 * i);
    __syncthreads();
#pragma unroll
    for (int ks = 0; ks < 2; ++ks) {
      bf16x8 a[4], b[4];
#pragma unroll
      for (int mi = 0; mi < 4; ++mi)
        a[mi] = *(const bf16x8*)&As[wr + mi * 16 + l16][ks * 32 + h8 * 8];
#pragma unroll
      for (int nj = 0; nj < 4; ++nj)
        b[nj] = *(const bf16x8*)&Bs[wc + nj * 16 + l16][ks * 32 + h8 * 8];
#pragma unroll
      for (int mi = 0; mi < 4; ++mi)
#pragma unroll
        for (int nj = 0; nj < 4; ++nj)
          acc[mi][nj] = mfma16(b[nj], a[mi], acc[mi][nj]);  // swapped
    }
    __syncthreads();
  }
#pragma unroll
  for (int mi = 0; mi < 4; ++mi) {
    int grow = m0 + wr + mi * 16 + l16;
#pragma unroll
    for (int nj = 0; nj < 4; ++nj) {
      int gcol0 = n0 + wc + nj * 16 + 4 * h8;
      if (EPI == 0) {
        int which = gcol0 >> 9, hh = (gcol0 >> 6) & 7, dd0 = gcol0 & 63;
        int bidx = grow >> 13, nn = grow & 8191;
        float scl = which == 0 ? 0.125f : 1.f;
        ushort4 o;
        o.x = f2b(acc[mi][nj][0] * scl); o.y = f2b(acc[mi][nj][1] * scl);
        o.z = f2b(acc[mi][nj][2] * scl); o.w = f2b(acc[mi][nj][3] * scl);
        unsigned short* dst = which == 0 ? qo : (which == 1 ? ko : vo);
        *(ushort4*)&dst[(((size_t)(bidx * 8 + hh)) * NTOK + nn) * 64 + dd0] = o;
      } else {
        float4 bi = *(const float4*)&bias[gcol0];
        float4 re = *(const float4*)&resid[(size_t)grow * 512 + gcol0];
        float4 o;
        o.x = acc[mi][nj][0] + bi.x + re.x; o.y = acc[mi][nj][1] + bi.y + re.y;
        o.z = acc[mi][nj][2] + bi.z + re.z; o.w = acc[mi][nj][3] + bi.w + re.w;
        *(float4*)&Cf[(size_t)grow * 512 + gcol0] = o;
      }
    }
  }
}

// ------------- fp32 GEMM (landmark path), epi 5 / 7 -------------
__global__ __launch_bounds__(256)
void gemm_ab(const float* __restrict__ A, const float* __restrict__ Bm,
             int Kdim, int lda, int ldb,
             long long sA, long long sB, int epi,
             float* __restrict__ qlp, float* __restrict__ klp,
             unsigned short* __restrict__ q16, unsigned short* __restrict__ k16) {
  __shared__ float As[16][64], Bs[16][64];
  int bz = blockIdx.z;
  A += sA * bz; Bm += sB * bz;
  int n0 = blockIdx.x * 64, m0 = blockIdx.y * 64;
  int tid = threadIdx.x, tx = tid & 15, ty = tid >> 4;
  int am = tid >> 2, akg = tid & 3, bk = tid >> 4, bng = tid & 15;
  const float* Aload = A + (size_t)(m0 + am) * lda + akg * 4;
  const float* Bload = Bm + (size_t)bk * ldb + n0 + bng * 4;
  float acc[4][4] = {};
  for (int k0 = 0; k0 < Kdim; k0 += 16) {
    float4 av = *reinterpret_cast<const float4*>(Aload + k0);
    float4 bv = *reinterpret_cast<const float4*>(Bload + (size_t)k0 * ldb);
    __syncthreads();
    As[akg * 4 + 0][am] = av.x; As[akg * 4 + 1][am] = av.y;
    As[akg * 4 + 2][am] = av.z; As[akg * 4 + 3][am] = av.w;
    *reinterpret_cast<float4*>(&Bs[bk][bng * 4]) = bv;
    __syncthreads();
#pragma unroll
    for (int kk = 0; kk < 16; ++kk) {
      float4 bq = *reinterpret_cast<const float4*>(&Bs[kk][tx * 4]);
      float a0 = As[kk][ty * 4 + 0], a1 = As[kk][ty * 4 + 1];
      float a2 = As[kk][ty * 4 + 2], a3 = As[kk][ty * 4 + 3];
      acc[0][0] += a0 * bq.x; acc[0][1] += a0 * bq.y; acc[0][2] += a0 * bq.z; acc[0][3] += a0 * bq.w;
      acc[1][0] += a1 * bq.x; acc[1][1] += a1 * bq.y; acc[1][2] += a1 * bq.z; acc[1][3] += a1 * bq.w;
      acc[2][0] += a2 * bq.x; acc[2][1] += a2 * bq.y; acc[2][2] += a2 * bq.z; acc[2][3] += a2 * bq.w;
      acc[3][0] += a3 * bq.x; acc[3][1] += a3 * bq.y; acc[3][2] += a3 * bq.z; acc[3][3] += a3 * bq.w;
    }
  }
  if (epi == 5) {
#pragma unroll
    for (int i = 0; i < 4; ++i) {
      int gr = m0 + ty * 4 + i;
      int bidx = gr >> 8, nn = gr & 255;
#pragma unroll
      for (int j = 0; j < 4; ++j) {
        int gc = n0 + tx * 4 + j;
        int which = gc >> 9, hh = (gc >> 6) & 7, dd = gc & 63;
        float val = acc[i][j];
        if (which == 0) val *= 0.125f;
        size_t idx = (((size_t)(bidx * 8 + hh)) * 256 + nn) * 64 + dd;
        float* dst = which == 0 ? qlp : klp;
        unsigned short* dst16 = which == 0 ? q16 : k16;
        dst[idx] = val;
        dst16[idx] = f2b(val);
      }
    }
  } else {  // epi 7
#pragma unroll
    for (int i = 0; i < 4; ++i) {
      int gr = m0 + ty * 4 + i;
#pragma unroll
      for (int j = 0; j < 4; ++j) {
        int gc = n0 + tx * 4 + j;
        q16[(size_t)bz * 16384 + (size_t)gr * 64 + gc] = f2b(acc[i][j]);
      }
    }
  }
}

// ------------- GEMM C = A[M,64] @ B[N,64]^T (sim2) -------------
__global__ __launch_bounds__(256)
void gemm_abt(const float* __restrict__ A, const float* __restrict__ Bm,
              float* __restrict__ C, int Kdim, int lda, int ldb, int ldc,
              long long sA, long long sB, long long sC) {
  __shared__ float As[16][64], Bs[16][64];
  int bz = blockIdx.z;
  A += sA * bz; Bm += sB * bz; C += sC * bz;
  int n0 = blockIdx.x * 64, m0 = blockIdx.y * 64;
  int tid = threadIdx.x, tx = tid & 15, ty = tid >> 4;
  int am = tid >> 2, akg = tid & 3;
  const float* Aload = A + (size_t)(m0 + am) * lda + akg * 4;
  const float* Bload = Bm + (size_t)(n0 + am) * ldb + akg * 4;
  float acc[4][4] = {};
  for (int k0 = 0; k0 < Kdim; k0 += 16) {
    float4 av = *reinterpret_cast<const float4*>(Aload + k0);
    float4 bv = *reinterpret_cast<const float4*>(Bload + k0);
    __syncthreads();
    As[akg * 4 + 0][am] = av.x; As[akg * 4 + 1][am] = av.y;
    As[akg * 4 + 2][am] = av.z; As[akg * 4 + 3][am] = av.w;
    Bs[akg * 4 + 0][am] = bv.x; Bs[akg * 4 + 1][am] = bv.y;
    Bs[akg * 4 + 2][am] = bv.z; Bs[akg * 4 + 3][am] = bv.w;
    __syncthreads();
#pragma unroll
    for (int kk = 0; kk < 16; ++kk) {
      float4 bq = *reinterpret_cast<const float4*>(&Bs[kk][tx * 4]);
      float a0 = As[kk][ty * 4 + 0], a1 = As[kk][ty * 4 + 1];
      float a2 = As[kk][ty * 4 + 2], a3 = As[kk][ty * 4 + 3];
      acc[0][0] += a0 * bq.x; acc[0][1] += a0 * bq.y; acc[0][2] += a0 * bq.z; acc[0][3] += a0 * bq.w;
      acc[1][0] += a1 * bq.x; acc[1][1] += a1 * bq.y; acc[1][2] += a1 * bq.z; acc[1][3] += a1 * bq.w;
      acc[2][0] += a2 * bq.x; acc[2][1] += a2 * bq.y; acc[2][2] += a2 * bq.z; acc[2][3] += a2 * bq.w;
      acc[3][0] += a3 * bq.x; acc[3][1] += a3 * bq.y; acc[3][2] += a3 * bq.z; acc[3][3] += a3 * bq.w;
    }
  }
#pragma unroll
  for (int i = 0; i < 4; ++i) {
    int gr = m0 + ty * 4 + i;
#pragma unroll
    for (int j = 0; j < 4; ++j)
      C[(size_t)gr * ldc + n0 + tx * 4 + j] = acc[i][j];
  }
}

// ------------- row softmax (256 cols) -------------
__global__ __launch_bounds__(256) void softmax_rows256(float* __restrict__ buf) {
  __shared__ float red[4];
  size_t row = blockIdx.x;
  float* r = buf + row * 256;
  int tid = threadIdx.x, lane = tid & 63, wid = tid >> 6;
  float v = r[tid];
  float mx = wave_max(v);
  if (!lane) red[wid] = mx;
  __syncthreads();
  mx = fmaxf(fmaxf(red[0], red[1]), fmaxf(red[2], red[3]));
  __syncthreads();
  float e = expf(v - mx);
  float s = wave_sum(e);
  if (!lane) red[wid] = s;
  __syncthreads();
  s = red[0] + red[1] + red[2] + red[3];
  r[tid] = e / s;
}

// ------------- pinv scalar: max column-sum -------------
__global__ void init_scalars(float* sc) { if (threadIdx.x < 2) sc[threadIdx.x] = 0.f; }

__global__ __launch_bounds__(256) void colsum_part(const float* __restrict__ a2,
                                                   float* __restrict__ part) {
  int bh = blockIdx.x >> 3, chunk = blockIdx.x & 7;
  int tid = threadIdx.x;
  const float* M = a2 + (size_t)bh * 65536 + (size_t)chunk * 32 * 256;
  float acc = 0.f;
#pragma unroll
  for (int r = 0; r < 32; ++r) acc += M[r * 256 + tid];
  part[(size_t)blockIdx.x * 256 + tid] = acc;
}

__global__ __launch_bounds__(256) void colsum_final(const float* __restrict__ part,
                                                    float* __restrict__ sc) {
  __shared__ float red[4];
  int bh = blockIdx.x;
  int tid = threadIdx.x, lane = tid & 63, w = tid >> 6;
  float s = 0.f;
#pragma unroll
  for (int c = 0; c < 8; ++c) s += part[(size_t)(bh * 8 + c) * 256 + tid];
  float m = wave_max(s);
  if (!lane) red[w] = m;
  __syncthreads();
  if (tid == 0) {
    float mm = fmaxf(fmaxf(red[0], red[1]), fmaxf(red[2], red[3]));
    atomicMax(reinterpret_cast<int*>(sc) + 1, __float_as_int(mm));
  }
}

// ------------- split attn2 hi/lo bf16: X, z0=X^T/c, z0^T=X/c -------------
__global__ __launch_bounds__(256) void hilo_split(
    const float* __restrict__ a2, const float* __restrict__ sc,
    unsigned short* __restrict__ Xh, unsigned short* __restrict__ Xl,
    unsigned short* __restrict__ zth, unsigned short* __restrict__ ztl,
    unsigned short* __restrict__ zh, unsigned short* __restrict__ zl) {
  __shared__ float t[64][65];
  int bz = blockIdx.z;
  size_t base = (size_t)bz * 65536;
  int i0 = blockIdx.y * 64, j0 = blockIdx.x * 64;
  int tid = threadIdx.x, tx = tid & 15, ty = tid >> 4;
  float inv = 1.f / sc[1];
#pragma unroll
  for (int rr = 0; rr < 64; rr += 16) {
    int gr = i0 + rr + ty, gc0 = j0 + tx * 4;
    float4 v = *(const float4*)&a2[base + (size_t)gr * 256 + gc0];
    t[rr + ty][tx * 4 + 0] = v.x; t[rr + ty][tx * 4 + 1] = v.y;
    t[rr + ty][tx * 4 + 2] = v.z; t[rr + ty][tx * 4 + 3] = v.w;
    ushort4 xh, xl2, sh, sl;
    float vv[4] = {v.x, v.y, v.z, v.w};
    unsigned short* ph = (unsigned short*)&xh;
    unsigned short* pl = (unsigned short*)&xl2;
    unsigned short* qh = (unsigned short*)&sh;
    unsigned short* ql2 = (unsigned short*)&sl;
#pragma unroll
    for (int j = 0; j < 4; ++j) {
      ph[j] = f2b(vv[j]);
      pl[j] = f2b(vv[j] - b2f(ph[j]));
      float s = vv[j] * inv;
      qh[j] = f2b(s);
      ql2[j] = f2b(s - b2f(qh[j]));
    }
    *(ushort4*)&Xh[base + (size_t)gr * 256 + gc0] = xh;
    *(ushort4*)&Xl[base + (size_t)gr * 256 + gc0] = xl2;
    *(ushort4*)&zth[base + (size_t)gr * 256 + gc0] = sh;
    *(ushort4*)&ztl[base + (size_t)gr * 256 + gc0] = sl;
  }
  __syncthreads();
#pragma unroll
  for (int rr = 0; rr < 64; rr += 16) {
    int gr = j0 + rr + ty;
    int gc0 = i0 + tx * 4;
    ushort4 zh4, zl4;
    unsigned short* ph = (unsigned short*)&zh4;
    unsigned short* pl = (unsigned short*)&zl4;
#pragma unroll
    for (int j = 0; j < 4; ++j) {
      float s = t[tx * 4 + j][rr + ty] * inv;
      ph[j] = f2b(s);
      pl[j] = f2b(s - b2f(ph[j]));
    }
    *(ushort4*)&zh[base + (size_t)gr * 256 + gc0] = zh4;
    *(ushort4*)&zl[base + (size_t)gr * 256 + gc0] = zl4;
  }
}

// ------------- NS hi/lo MFMA GEMM -------------
__global__ __launch_bounds__(256) void ns_mfma(
    const unsigned short* __restrict__ Ah, const unsigned short* __restrict__ Al,
    const unsigned short* __restrict__ Bth, const unsigned short* __restrict__ Btl,
    const unsigned short* __restrict__ Eh, const unsigned short* __restrict__ El,
    float alpha, float diag, float beta,
    unsigned short* __restrict__ Ch, unsigned short* __restrict__ Cl,
    unsigned short* __restrict__ CTh, unsigned short* __restrict__ CTl,
    float* __restrict__ Cf) {
  __shared__ __align__(16) unsigned short AhS[64][72], AlS[64][72];
  __shared__ __align__(16) unsigned short BhS[64][72], BlS[64][72];
  const int tid = threadIdx.x;
  const int l16 = tid & 15, h8 = (tid & 63) >> 4, w = tid >> 6;
  const size_t base = (size_t)blockIdx.z * 65536;
  const int m0 = blockIdx.y * 64, n0 = blockIdx.x * 64;
  const int wr = (w >> 1) * 32, wc = (w & 1) * 32;
  const int srow = tid >> 2, scol = (tid & 3) * 16;
  f32x4 acc[2][2] = {};
  for (int k0 = 0; k0 < 256; k0 += 64) {
    const size_t aoff = base + (size_t)(m0 + srow) * 256 + k0 + scol;
    const size_t boff = base + (size_t)(n0 + srow) * 256 + k0 + scol;
    *(u16x8*)&AhS[srow][scol] = *(const u16x8*)(Ah + aoff);
    *(u16x8*)&AhS[srow][scol + 8] = *(const u16x8*)(Ah + aoff + 8);
    *(u16x8*)&AlS[srow][scol] = *(const u16x8*)(Al + aoff);
    *(u16x8*)&AlS[srow][scol + 8] = *(const u16x8*)(Al + aoff + 8);
    *(u16x8*)&BhS[srow][scol] = *(const u16x8*)(Bth + boff);
    *(u16x8*)&BhS[srow][scol + 8] = *(const u16x8*)(Bth + boff + 8);
    *(u16x8*)&BlS[srow][scol] = *(const u16x8*)(Btl + boff);
    *(u16x8*)&BlS[srow][scol + 8] = *(const u16x8*)(Btl + boff + 8);
    __syncthreads();
#pragma unroll
    for (int ks = 0; ks < 2; ++ks) {
      bf16x8 ah[2], al[2], bh[2], bl[2];
#pragma unroll
      for (int mi = 0; mi < 2; ++mi) {
        ah[mi] = *(const bf16x8*)&AhS[wr + mi * 16 + l16][ks * 32 + h8 * 8];
        al[mi] = *(const bf16x8*)&AlS[wr + mi * 16 + l16][ks * 32 + h8 * 8];
      }
#pragma unroll
      for (int nj = 0; nj < 2; ++nj) {
        bh[nj] = *(const bf16x8*)&BhS[wc + nj * 16 + l16][ks * 32 + h8 * 8];
        bl[nj] = *(const bf16x8*)&BlS[wc + nj * 16 + l16][ks * 32 + h8 * 8];
      }
#pragma unroll
      for (int mi = 0; mi < 2; ++mi)
#pragma unroll
        for (int nj = 0; nj < 2; ++nj) {
          acc[mi][nj] = mfma16(ah[mi], bh[nj], acc[mi][nj]);
          acc[mi][nj] = mfma16(ah[mi], bl[nj], acc[mi][nj]);
          acc[mi][nj] = mfma16(al[mi], bh[nj], acc[mi][nj]);
        }
    }
    __syncthreads();
  }
#pragma unroll
  for (int mi = 0; mi < 2; ++mi)
#pragma unroll
    for (int nj = 0; nj < 2; ++nj) {
      int grow0 = m0 + wr + mi * 16 + 4 * h8;
      int gcol = n0 + wc + nj * 16 + l16;
      float vals[4];
      ushort4 th, tl;
      unsigned short* ph = (unsigned short*)&th;
      unsigned short* pl = (unsigned short*)&tl;
#pragma unroll
      for (int r = 0; r < 4; ++r) {
        int grow = grow0 + r;
        float v = alpha * acc[mi][nj][r];
        if (grow == gcol) v += diag;
        if (Eh) v += beta * (b2f(Eh[base + (size_t)grow * 256 + gcol]) +
                             b2f(El[base + (size_t)grow * 256 + gcol]));
        vals[r] = v;
        ph[r] = f2b(v);
        pl[r] = f2b(v - b2f(ph[r]));
      }
      if (Ch) {
#pragma unroll
        for (int r = 0; r < 4; ++r) {
          Ch[base + (size_t)(grow0 + r) * 256 + gcol] = ph[r];
          Cl[base + (size_t)(grow0 + r) * 256 + gcol] = pl[r];
        }
      }
      if (CTh) {
        *(ushort4*)&CTh[base + (size_t)gcol * 256 + grow0] = th;
        *(ushort4*)&CTl[base + (size_t)gcol * 256 + grow0] = tl;
      }
      if (Cf) {
#pragma unroll
        for (int r = 0; r < 4; ++r)
          Cf[base + (size_t)(grow0 + r) * 256 + gcol] = vals[r];
      }
    }
}

// ------------- MFMA flash, transposed PV accumulator -------------
// MODE 0: split-K partials (float4 Opart + ML)   MODE 1: normalize + bf16 outh
template <int MODE>
__global__ __launch_bounds__(256) void flash_mfma(
    const unsigned short* __restrict__ Q, const unsigned short* __restrict__ Kp,
    const unsigned short* __restrict__ Vp, long long sQ, long long sK,
    int kps, int nkt,
    float* __restrict__ Opart, float* __restrict__ MLpart,
    unsigned short* __restrict__ outh16) {
  __shared__ __align__(16) unsigned short Qt[128][72];
  __shared__ __align__(16) unsigned short Kt[64][72];
  __shared__ __align__(16) unsigned short Vt[64][72];
  __shared__ __align__(16) unsigned short Pb[128][72];
  __shared__ float scfb[128], linvb[128];
  const int tid = threadIdx.x;
  const int l16 = tid & 15, h8 = (tid & 63) >> 4, w = tid >> 6;
  const int bh = blockIdx.y, s = blockIdx.z, qt = blockIdx.x;
  const int q0 = qt * 128;
  const unsigned short* Qb = Q + (size_t)bh * sQ + (size_t)q0 * 64;
  const unsigned short* Kb = Kp + (size_t)bh * sK + (size_t)s * kps * 64;
  const unsigned short* Vb = Vp + (size_t)bh * sK + (size_t)s * kps * 64;
  {
    int row = tid >> 1, c0 = (tid & 1) * 32;
#pragma unroll
    for (int i = 0; i < 4; ++i)
      *(u16x8*)&Qt[row][c0 + 8 * i] = *(const u16x8*)(Qb + (size_t)row * 64 + c0 + 8 * i);
  }
  f32x4 acc_o[2][4] = {};
  float mrow[2][4], lrow[2][4];
#pragma unroll
  for (int mi = 0; mi < 2; ++mi)
#pragma unroll
    for (int r = 0; r < 4; ++r) { mrow[mi][r] = -1e30f; lrow[mi][r] = 0.f; }
  for (int kt = 0; kt < nkt; ++kt) {
    {
      int row = tid >> 2, c0 = (tid & 3) * 16;
      *(u16x8*)&Kt[row][c0] = *(const u16x8*)(Kb + ((size_t)(kt * 64 + row)) * 64 + c0);
      *(u16x8*)&Kt[row][c0 + 8] = *(const u16x8*)(Kb + ((size_t)(kt * 64 + row)) * 64 + c0 + 8);
      int key = tid & 63, d0 = w * 16;
      u16x8 v0 = *(const u16x8*)(Vb + ((size_t)(kt * 64 + key)) * 64 + d0);
      u16x8 v1 = *(const u16x8*)(Vb + ((size_t)(kt * 64 + key)) * 64 + d0 + 8);
#pragma unroll
      for (int i = 0; i < 8; ++i) { Vt[d0 + i][key] = v0[i]; Vt[d0 + 8 + i][key] = v1[i]; }
    }
    __syncthreads();
    f32x4 accs[2][4] = {};
#pragma unroll
    for (int ks = 0; ks < 2; ++ks) {
      bf16x8 a[2], b[4];
      a[0] = *(const bf16x8*)&Qt[w * 32 + l16][ks * 32 + h8 * 8];
      a[1] = *(const bf16x8*)&Qt[w * 32 + 16 + l16][ks * 32 + h8 * 8];
#pragma unroll
      for (int nj = 0; nj < 4; ++nj)
        b[nj] = *(const bf16x8*)&Kt[nj * 16 + l16][ks * 32 + h8 * 8];
#pragma unroll
      for (int mi = 0; mi < 2; ++mi)
#pragma unroll
        for (int nj = 0; nj < 4; ++nj)
          accs[mi][nj] = mfma16(a[mi], b[nj], accs[mi][nj]);
    }
#pragma unroll
    for (int mi = 0; mi < 2; ++mi)
#pragma unroll
      for (int r = 0; r < 4; ++r) {
        float mx = fmaxf(fmaxf(accs[mi][0][r], accs[mi][1][r]),
                         fmaxf(accs[mi][2][r], accs[mi][3][r]));
#pragma unroll
        for (int off = 8; off; off >>= 1) mx = fmaxf(mx, __shfl_xor(mx, off, 64));
        float mn = fmaxf(mrow[mi][r], mx);
        float scf = __expf(mrow[mi][r] - mn);
        float ps = 0.f;
#pragma unroll
        for (int nj = 0; nj < 4; ++nj) {
          float p = __expf(accs[mi][nj][r] - mn);
          accs[mi][nj][r] = p;
          ps += p;
        }
#pragma unroll
        for (int off = 8; off; off >>= 1) ps += __shfl_xor(ps, off, 64);
        lrow[mi][r] = lrow[mi][r] * scf + ps;
        mrow[mi][r] = mn;
        int prow = w * 32 + mi * 16 + 4 * h8 + r;
        scfb[prow] = scf;
#pragma unroll
        for (int nj = 0; nj < 4; ++nj)
          Pb[prow][nj * 16 + l16] = f2b(accs[mi][nj][r]);
      }
    __syncthreads();
#pragma unroll
    for (int mi = 0; mi < 2; ++mi) {
      float sc2 = scfb[w * 32 + mi * 16 + l16];
#pragma unroll
      for (int dj = 0; dj < 4; ++dj) {
        acc_o[mi][dj][0] *= sc2; acc_o[mi][dj][1] *= sc2;
        acc_o[mi][dj][2] *= sc2; acc_o[mi][dj][3] *= sc2;
      }
    }
#pragma unroll
    for (int ks = 0; ks < 2; ++ks) {
      bf16x8 pa[2], vb2[4];
      pa[0] = *(const bf16x8*)&Pb[w * 32 + l16][ks * 32 + h8 * 8];
      pa[1] = *(const bf16x8*)&Pb[w * 32 + 16 + l16][ks * 32 + h8 * 8];
#pragma unroll
      for (int dj = 0; dj < 4; ++dj)
        vb2[dj] = *(const bf16x8*)&Vt[dj * 16 + l16][ks * 32 + h8 * 8];
#pragma unroll
      for (int mi = 0; mi < 2; ++mi)
#pragma unroll
        for (int dj = 0; dj < 4; ++dj)
          acc_o[mi][dj] = mfma16(vb2[dj], pa[mi], acc_o[mi][dj]);  // swapped
    }
    __syncthreads();
  }
  if (MODE == 0) {
    int p = (s * 32 + bh) * 2 + qt;
    float* Ob = Opart + (size_t)p * 8192;
#pragma unroll
    for (int mi = 0; mi < 2; ++mi) {
      int row = w * 32 + mi * 16 + l16;
#pragma unroll
      for (int dj = 0; dj < 4; ++dj) {
        int d0 = dj * 16 + 4 * h8;
        *(float4*)&Ob[(size_t)row * 64 + d0] =
            make_float4(acc_o[mi][dj][0], acc_o[mi][dj][1], acc_o[mi][dj][2], acc_o[mi][dj][3]);
      }
#pragma unroll
      for (int r = 0; r < 4; ++r) {
        int prow = w * 32 + mi * 16 + 4 * h8 + r;
        if (l16 == 0) {
          MLpart[((size_t)p * 128 + prow) * 2] = mrow[mi][r];
          MLpart[((size_t)p * 128 + prow) * 2 + 1] = lrow[mi][r];
        }
      }
    }
  } else {
    int bidx = bh >> 3, hh = bh & 7;
#pragma unroll
    for (int mi = 0; mi < 2; ++mi)
#pragma unroll
      for (int r = 0; r < 4; ++r)
        linvb[w * 32 + mi * 16 + 4 * h8 + r] = 1.f / lrow[mi][r];
    __syncthreads();
#pragma unroll
    for (int mi = 0; mi < 2; ++mi) {
      int jrow = w * 32 + mi * 16 + l16;
      float linv = linvb[jrow];
      int qr = q0 + jrow;
#pragma unroll
      for (int dj = 0; dj < 4; ++dj) {
        int d0 = dj * 16 + 4 * h8;
        ushort4 o;
        o.x = f2b(acc_o[mi][dj][0] * linv);
        o.y = f2b(acc_o[mi][dj][1] * linv);
        o.z = f2b(acc_o[mi][dj][2] * linv);
        o.w = f2b(acc_o[mi][dj][3] * linv);
        *(ushort4*)&outh16[((size_t)bidx * NTOK + qr) * 512 + hh * 64 + d0] = o;
      }
    }
  }
}

// ------------- combine split-K flash partials -> T3 -------------
__global__ __launch_bounds__(256) void flash_combine(const float* __restrict__ Opart,
                                                     const float* __restrict__ MLpart,
                                                     float* __restrict__ T3) {
  int bh = blockIdx.y;
  int row = blockIdx.x * 4 + (threadIdx.x >> 6);
  int d = threadIdx.x & 63;
  int qt = row >> 7, rowin = row & 127;
  float mstar = -1e30f;
#pragma unroll
  for (int s = 0; s < 8; ++s) {
    int p = (s * 32 + bh) * 2 + qt;
    mstar = fmaxf(mstar, MLpart[((size_t)p * 128 + rowin) * 2]);
  }
  float L = 0.f, O = 0.f;
#pragma unroll
  for (int s = 0; s < 8; ++s) {
    int p = (s * 32 + bh) * 2 + qt;
    float ms = MLpart[((size_t)p * 128 + rowin) * 2];
    float ls = MLpart[((size_t)p * 128 + rowin) * 2 + 1];
    float e = __expf(ms - mstar);
    L += ls * e;
    O += Opart[(size_t)p * 8192 + rowin * 64 + d] * e;
  }
  T3[((size_t)bh * 256 + row) * 64 + d] = O / L;
}

// ------------- depthwise conv, input-major sliding accumulation -------------
__global__ __launch_bounds__(256) void conv_add_bf16(const unsigned short* __restrict__ v,
                                                     const float* __restrict__ cw,
                                                     unsigned short* __restrict__ outh16) {
  __shared__ float vt[96][68];
  int z = blockIdx.x;
  int bh = z >> 7, n0 = (z & 127) * 64;
  int tid = threadIdx.x;
  const unsigned short* vb = v + (size_t)bh * NTOK * 64;
  for (int f = tid; f < 768; f += 256) {
    int rowi = f >> 3, c8 = (f & 7) * 8;
    int rn = n0 - 16 + rowi;
    if (rn >= 0 && rn < NTOK) {
      u16x8 val = *(const u16x8*)(vb + (size_t)rn * 64 + c8);
#pragma unroll
      for (int i = 0; i < 8; ++i) vt[rowi][c8 + i] = b2f(val[i]);
    } else {
#pragma unroll
      for (int i = 0; i < 8; ++i) vt[rowi][c8 + i] = 0.f;
    }
  }
  float wreg[33];
#pragma unroll
  for (int k = 0; k < 33; ++k) wreg[k] = cw[(bh & 7) * 33 + k];
  __syncthreads();
  int dd = tid & 63, rg = tid >> 6;
  int bidx = bh >> 3, hh = bh & 7;
  float acc[16];
#pragma unroll
  for (int r = 0; r < 16; ++r) acc[r] = 0.f;
#pragma unroll
  for (int j = 0; j < 48; ++j) {
    float vv = vt[rg * 16 + j][dd];
    int rlo = j - 32 < 0 ? 0 : j - 32;
    int rhi = j < 15 ? j : 15;
#pragma unroll
    for (int r = 0; r < 16; ++r)
      if (r >= rlo && r <= rhi) acc[r] += wreg[j - r] * vv;
  }
#pragma unroll
  for (int r = 0; r < 16; ++r) {
    size_t o = ((size_t)bidx * NTOK + n0 + rg * 16 + r) * 512 + hh * 64 + dd;
    outh16[o] = f2b(b2f(outh16[o]) + acc[r]);
  }
}

extern "C" void kernel_launch(void* const* d_in, const int* in_sizes, int n_in,
                              void* d_out, int out_size, void* d_ws, size_t ws_size,
                              hipStream_t stream) {
  const float* x = (const float*)d_in[0];
  const float* gamma = (const float*)d_in[1];
  const float* beta = (const float*)d_in[2];
  const float* w_qkv = (const float*)d_in[3];
  const float* w_out = (const float*)d_in[4];
  const float* b_out = (const float*)d_in[5];
  const float* conv_w = (const float*)d_in[6];
  float* out = (float*)d_out;
  float* ws = (float*)d_ws;
  (void)ws_size; (void)in_sizes; (void)n_in; (void)out_size;

  float* A0 = ws;
  float* Breg = ws + 16777216;
  unsigned short* qb = (unsigned short*)(ws + 25165824);
  unsigned short* kb = (unsigned short*)(ws + 33554432);
  unsigned short* vb = (unsigned short*)(ws + 41943040);
  float* Fs = ws + 50331648;

  // A0 tenants
  float* X2 = A0;
  float* zfinal = A0;
  float* ql = A0 + 2097152;
  float* kl = A0 + 2621440;
  unsigned short* Xh  = (unsigned short*)(A0 + 2097152);
  unsigned short* Xl  = (unsigned short*)(A0 + 3145728);
  unsigned short* zAh = (unsigned short*)(A0 + 4194304);
  unsigned short* zAl = (unsigned short*)(A0 + 5242880);
  unsigned short* zAth = (unsigned short*)(A0 + 6291456);
  unsigned short* zAtl = (unsigned short*)(A0 + 7340032);
  unsigned short* zYh = (unsigned short*)(A0 + 8388608);
  unsigned short* zYl = (unsigned short*)(A0 + 9437184);
  unsigned short* zYth = (unsigned short*)(A0 + 10485760);
  unsigned short* zYtl = (unsigned short*)(A0 + 11534336);
  unsigned short* TBth = (unsigned short*)(A0 + 12582912);
  unsigned short* TBtl = (unsigned short*)(A0 + 13631488);
  unsigned short* TAth = (unsigned short*)(A0 + 14680064);
  unsigned short* TAtl = (unsigned short*)(A0 + 15728640);
  unsigned short* outh16 = (unsigned short*)A0;
  // Breg tenants
  unsigned short* xnb = (unsigned short*)Breg;
  float* Opart = Breg;
  float* MLpart = Breg + 4194304;
  float* T3 = Breg + 4325376;
  // Fs tenants
  float* xl = Fs;
  unsigned short* qlb = (unsigned short*)(Fs + 524288);
  unsigned short* klb = (unsigned short*)(Fs + 786432);
  unsigned short* W2b = (unsigned short*)(Fs + 1048576);
  unsigned short* woutT = (unsigned short*)(Fs + 1310720);
  unsigned short* wqkvT = (unsigned short*)(Fs + 1441792);
  float* part = Fs + 1835008;
  float* sc = Fs + 1900544;

  // 1. fused LayerNorm + pooling
  ln_pool<<<1024, 256, 0, stream>>>(x, gamma, beta, xnb, xl);
  // 2. weight transposes
  transpose_cvt<<<dim3(48, 16), 256, 0, stream>>>(w_qkv, wqkvT, 512, 1536);
  transpose_cvt<<<dim3(16, 16), 256, 0, stream>>>(w_out, woutT, 512, 512);
  // 3. qkv projection
  gemm_mfma<0><<<dim3(12, 256), 256, 0, stream>>>(xnb, wqkvT, 512, qb, kb, vb,
                                                  nullptr, nullptr, nullptr);
  // 4. ql/kl = xl @ Wq/Wk fp32 (+ bf16 fused)
  gemm_ab<<<dim3(16, 16, 1), 256, 0, stream>>>(xl, w_qkv, 512, 512, 1536, 0, 0,
                                               5, ql, kl, qlb, klb);
  // 5. sim2 -> attn2 (fp32)
  gemm_abt<<<dim3(4, 4, BH), 256, 0, stream>>>(ql, kl, X2, 64, 64, 64, 256,
                                               16384, 16384, 65536);
  softmax_rows256<<<BH * NM, 256, 0, stream>>>(X2);
  // 6. pinv scalar + hi/lo split
  init_scalars<<<1, 64, 0, stream>>>(sc);
  colsum_part<<<BH * 8, 256, 0, stream>>>(X2, part);
  colsum_final<<<BH, 256, 0, stream>>>(part, sc);
  hilo_split<<<dim3(4, 4, BH), 256, 0, stream>>>(X2, sc, Xh, Xl, zAth, zAtl, zAh, zAl);
  // 7. Newton-Schulz hi/lo MFMA
  unsigned short *ch = zAh, *cl = zAl, *cth = zAth, *ctl = zAtl;
  unsigned short *yh = zYh, *yl = zYl, *yth = zYth, *ytl = zYtl;
  for (int it = 0; it < 6; ++it) {
    ns_mfma<<<dim3(4, 4, BH), 256, 0, stream>>>(Xh, Xl, cth, ctl, nullptr, nullptr,
                                                1.f, 0.f, 0.f, yh, yl, yth, ytl, nullptr);
    ns_mfma<<<dim3(4, 4, BH), 256, 0, stream>>>(yh, yl, yth, ytl, yh, yl,
                                                1.f, 15.f, -7.f, nullptr, nullptr,
                                                TBth, TBtl, nullptr);
    ns_mfma<<<dim3(4, 4, BH), 256, 0, stream>>>(yh, yl, TBth, TBtl, nullptr, nullptr,
                                                -1.f, 13.f, 0.f, nullptr, nullptr,
                                                TAth, TAtl, nullptr);
    ns_mfma<<<dim3(4, 4, BH), 256, 0, stream>>>(ch, cl, TAth, TAtl, nullptr, nullptr,
                                                0.25f, 0.f, 0.f, yh, yl, yth, ytl,
                                                it == 5 ? zfinal : nullptr);
    unsigned short* t;
    t = ch; ch = yh; yh = t;  t = cl; cl = yl; yl = t;
    t = cth; cth = yth; yth = t;  t = ctl; ctl = ytl; ytl = t;
  }
  // 8. flash A (split-K=8)
  flash_mfma<0><<<dim3(2, 32, 8), 256, 0, stream>>>(qlb, kb, vb, 16384, 524288,
                                                    1024, 16, Opart, MLpart, nullptr);
  flash_combine<<<dim3(64, 32), 256, 0, stream>>>(Opart, MLpart, T3);
  // 9. W2 = pinv @ T3 -> bf16
  gemm_ab<<<dim3(1, 4, BH), 256, 0, stream>>>(zfinal, T3, 256, 256, 64, 65536, 16384,
                                              7, nullptr, nullptr, W2b, nullptr);
  // 10. flash B -> bf16 outh (plain epilogue)
  flash_mfma<1><<<dim3(64, 32, 1), 256, 0, stream>>>(qb, klb, W2b, 524288, 16384,
                                                     0, 4, nullptr, nullptr, outh16);
  // 11. conv residual (separate, fp32-LDS, register taps)
  conv_add_bf16<<<BH * (NTOK / 64), 256, 0, stream>>>(vb, conv_w, outh16);
  // 12. out = x + outh @ w_out + b_out
  gemm_mfma<2><<<dim3(4, 256), 256, 0, stream>>>(outh16, woutT, 512, nullptr, nullptr,
                                                 nullptr, out, b_out, x);
}

// Round 10
// 662.543 us; speedup vs baseline: 4.6317x; 1.1252x over previous
//
#include <hip/hip_runtime.h>

#define NTOK 8192
#define TOT 32768
#define DMODEL 512
#define NM 256
#define BH 32

typedef __attribute__((ext_vector_type(8))) short bf16x8;
typedef __attribute__((ext_vector_type(8))) unsigned short u16x8;
typedef __attribute__((ext_vector_type(4))) float f32x4;

__device__ __forceinline__ unsigned short f2b(float f) {
  unsigned u = __float_as_uint(f);
  return (unsigned short)((u + 0x7fffu + ((u >> 16) & 1u)) >> 16);
}
__device__ __forceinline__ float b2f(unsigned short h) {
  return __uint_as_float((unsigned)h << 16);
}
__device__ __forceinline__ f32x4 mfma16(bf16x8 a, bf16x8 b, f32x4 c) {
  return __builtin_amdgcn_mfma_f32_16x16x32_bf16(a, b, c, 0, 0, 0);
}
__device__ __forceinline__ float wave_sum(float v) {
#pragma unroll
  for (int o = 32; o; o >>= 1) v += __shfl_xor(v, o, 64);
  return v;
}
__device__ __forceinline__ float wave_max(float v) {
#pragma unroll
  for (int o = 32; o; o >>= 1) v = fmaxf(v, __shfl_xor(v, o, 64));
  return v;
}
// bijective XCD swizzle (requires nwg % 8 == 0): XCD k owns contiguous chunk k
__device__ __forceinline__ int xcd_swz(int wg, int nwg) {
  return (wg & 7) * (nwg >> 3) + (wg >> 3);
}

// ------------- fused LayerNorm + pooling, wave-per-row -------------
__global__ __launch_bounds__(256) void ln_pool(const float* __restrict__ x,
                                               const float* __restrict__ g,
                                               const float* __restrict__ b,
                                               unsigned short* __restrict__ xnb,
                                               float* __restrict__ xl) {
  __shared__ float pp[4][512];
  int tid = threadIdx.x, lane = tid & 63, w = tid >> 6;
  int c0 = lane * 8;
  float4 g0 = *(const float4*)&g[c0], g1 = *(const float4*)&g[c0 + 4];
  float4 b0 = *(const float4*)&b[c0], b1 = *(const float4*)&b[c0 + 4];
  float pa[8] = {};
  size_t rbase = (size_t)blockIdx.x * 32 + w * 8;
  for (int j = 0; j < 8; ++j) {
    size_t row = rbase + j;
    float4 v0 = *(const float4*)&x[row * DMODEL + c0];
    float4 v1 = *(const float4*)&x[row * DMODEL + c0 + 4];
    float s = v0.x + v0.y + v0.z + v0.w + v1.x + v1.y + v1.z + v1.w;
    float ss = v0.x * v0.x + v0.y * v0.y + v0.z * v0.z + v0.w * v0.w +
               v1.x * v1.x + v1.y * v1.y + v1.z * v1.z + v1.w * v1.w;
    s = wave_sum(s);
    ss = wave_sum(ss);
    float mu = s * (1.f / DMODEL);
    float var = ss * (1.f / DMODEL) - mu * mu;
    float rstd = rsqrtf(var + 1e-5f);
    float o[8];
    o[0] = (v0.x - mu) * rstd * g0.x + b0.x; o[1] = (v0.y - mu) * rstd * g0.y + b0.y;
    o[2] = (v0.z - mu) * rstd * g0.z + b0.z; o[3] = (v0.w - mu) * rstd * g0.w + b0.w;
    o[4] = (v1.x - mu) * rstd * g1.x + b1.x; o[5] = (v1.y - mu) * rstd * g1.y + b1.y;
    o[6] = (v1.z - mu) * rstd * g1.z + b1.z; o[7] = (v1.w - mu) * rstd * g1.w + b1.w;
    u16x8 pk;
#pragma unroll
    for (int i = 0; i < 8; ++i) { pk[i] = f2b(o[i]); pa[i] += o[i]; }
    *(u16x8*)&xnb[row * DMODEL + c0] = pk;
  }
  *(float4*)&pp[w][c0] = make_float4(pa[0], pa[1], pa[2], pa[3]);
  *(float4*)&pp[w][c0 + 4] = make_float4(pa[4], pa[5], pa[6], pa[7]);
  __syncthreads();
#pragma unroll
  for (int c = tid; c < 512; c += 256) {
    float s = pp[0][c] + pp[1][c] + pp[2][c] + pp[3][c];
    xl[(size_t)blockIdx.x * DMODEL + c] = s * (1.f / 32.f);
  }
}

// ------------- transpose + cvt fp32[K][N] -> bf16[N][K] -------------
__global__ __launch_bounds__(256) void transpose_cvt(const float* __restrict__ in,
                                                     unsigned short* __restrict__ outp,
                                                     int K, int N) {
  __shared__ float t[32][33];
  int k0 = blockIdx.y * 32, n0 = blockIdx.x * 32;
  int tx = threadIdx.x & 31, ty = threadIdx.x >> 5;
#pragma unroll
  for (int i = 0; i < 32; i += 8)
    t[ty + i][tx] = in[(size_t)(k0 + ty + i) * N + n0 + tx];
  __syncthreads();
#pragma unroll
  for (int i = 0; i < 32; i += 8)
    outp[(size_t)(n0 + ty + i) * K + k0 + tx] = f2b(t[tx][ty + i]);
}

// ------------- MFMA GEMM NT, swapped-fragment epilogue, XCD-swizzled --------
// EPI 0: scatter qkv (q*0.125) as bf16, ushort4 stores
// EPI 2: Cf = AB + bias + resid, float4 stores
template <int EPI>
__global__ __launch_bounds__(256) void gemm_mfma(const unsigned short* __restrict__ Ab,
                                                 const unsigned short* __restrict__ Bt,
                                                 int Kd,
                                                 unsigned short* __restrict__ qo,
                                                 unsigned short* __restrict__ ko,
                                                 unsigned short* __restrict__ vo,
                                                 float* __restrict__ Cf,
                                                 const float* __restrict__ bias,
                                                 const float* __restrict__ resid) {
  __shared__ __align__(16) unsigned short As[128][72];
  __shared__ __align__(16) unsigned short Bs[128][72];
  const int tid = threadIdx.x;
  const int l16 = tid & 15, h8 = (tid & 63) >> 4, w = tid >> 6;
  const int nwg = gridDim.x * gridDim.y;
  int wg = xcd_swz(blockIdx.y * gridDim.x + blockIdx.x, nwg);
  const int m0 = (wg / gridDim.x) * 128, n0 = (wg % gridDim.x) * 128;
  const int wr = (w >> 1) * 64, wc = (w & 1) * 64;
  const int srow = tid >> 1, sc0 = (tid & 1) * 32;
  f32x4 acc[4][4] = {};
  for (int k0 = 0; k0 < Kd; k0 += 64) {
    const unsigned short* Ap = Ab + (size_t)(m0 + srow) * Kd + k0 + sc0;
#pragma unroll
    for (int i = 0; i < 4; ++i)
      *(u16x8*)&As[srow][sc0 + 8 * i] = *(const u16x8*)(Ap + 8 * i);
    const unsigned short* Bb = Bt + (size_t)(n0 + srow) * Kd + k0 + sc0;
#pragma unroll
    for (int i = 0; i < 4; ++i)
      *(u16x8*)&Bs[srow][sc0 + 8 * i] = *(const u16x8*)(Bb + 8 * i);
    __syncthreads();
#pragma unroll
    for (int ks = 0; ks < 2; ++ks) {
      bf16x8 a[4], b[4];
#pragma unroll
      for (int mi = 0; mi < 4; ++mi)
        a[mi] = *(const bf16x8*)&As[wr + mi * 16 + l16][ks * 32 + h8 * 8];
#pragma unroll
      for (int nj = 0; nj < 4; ++nj)
        b[nj] = *(const bf16x8*)&Bs[wc + nj * 16 + l16][ks * 32 + h8 * 8];
#pragma unroll
      for (int mi = 0; mi < 4; ++mi)
#pragma unroll
        for (int nj = 0; nj < 4; ++nj)
          acc[mi][nj] = mfma16(b[nj], a[mi], acc[mi][nj]);  // swapped
    }
    __syncthreads();
  }
#pragma unroll
  for (int mi = 0; mi < 4; ++mi) {
    int grow = m0 + wr + mi * 16 + l16;
#pragma unroll
    for (int nj = 0; nj < 4; ++nj) {
      int gcol0 = n0 + wc + nj * 16 + 4 * h8;
      if (EPI == 0) {
        int which = gcol0 >> 9, hh = (gcol0 >> 6) & 7, dd0 = gcol0 & 63;
        int bidx = grow >> 13, nn = grow & 8191;
        float scl = which == 0 ? 0.125f : 1.f;
        ushort4 o;
        o.x = f2b(acc[mi][nj][0] * scl); o.y = f2b(acc[mi][nj][1] * scl);
        o.z = f2b(acc[mi][nj][2] * scl); o.w = f2b(acc[mi][nj][3] * scl);
        unsigned short* dst = which == 0 ? qo : (which == 1 ? ko : vo);
        *(ushort4*)&dst[(((size_t)(bidx * 8 + hh)) * NTOK + nn) * 64 + dd0] = o;
      } else {
        float4 bi = *(const float4*)&bias[gcol0];
        float4 re = *(const float4*)&resid[(size_t)grow * 512 + gcol0];
        float4 o;
        o.x = acc[mi][nj][0] + bi.x + re.x; o.y = acc[mi][nj][1] + bi.y + re.y;
        o.z = acc[mi][nj][2] + bi.z + re.z; o.w = acc[mi][nj][3] + bi.w + re.w;
        *(float4*)&Cf[(size_t)grow * 512 + gcol0] = o;
      }
    }
  }
}

// ------------- fp32 GEMM (landmark path), epi 5 / 7 -------------
__global__ __launch_bounds__(256)
void gemm_ab(const float* __restrict__ A, const float* __restrict__ Bm,
             int Kdim, int lda, int ldb,
             long long sA, long long sB, int epi,
             float* __restrict__ qlp, float* __restrict__ klp,
             unsigned short* __restrict__ q16, unsigned short* __restrict__ k16) {
  __shared__ float As[16][64], Bs[16][64];
  int bz = blockIdx.z;
  A += sA * bz; Bm += sB * bz;
  int n0 = blockIdx.x * 64, m0 = blockIdx.y * 64;
  int tid = threadIdx.x, tx = tid & 15, ty = tid >> 4;
  int am = tid >> 2, akg = tid & 3, bk = tid >> 4, bng = tid & 15;
  const float* Aload = A + (size_t)(m0 + am) * lda + akg * 4;
  const float* Bload = Bm + (size_t)bk * ldb + n0 + bng * 4;
  float acc[4][4] = {};
  for (int k0 = 0; k0 < Kdim; k0 += 16) {
    float4 av = *reinterpret_cast<const float4*>(Aload + k0);
    float4 bv = *reinterpret_cast<const float4*>(Bload + (size_t)k0 * ldb);
    __syncthreads();
    As[akg * 4 + 0][am] = av.x; As[akg * 4 + 1][am] = av.y;
    As[akg * 4 + 2][am] = av.z; As[akg * 4 + 3][am] = av.w;
    *reinterpret_cast<float4*>(&Bs[bk][bng * 4]) = bv;
    __syncthreads();
#pragma unroll
    for (int kk = 0; kk < 16; ++kk) {
      float4 bq = *reinterpret_cast<const float4*>(&Bs[kk][tx * 4]);
      float a0 = As[kk][ty * 4 + 0], a1 = As[kk][ty * 4 + 1];
      float a2 = As[kk][ty * 4 + 2], a3 = As[kk][ty * 4 + 3];
      acc[0][0] += a0 * bq.x; acc[0][1] += a0 * bq.y; acc[0][2] += a0 * bq.z; acc[0][3] += a0 * bq.w;
      acc[1][0] += a1 * bq.x; acc[1][1] += a1 * bq.y; acc[1][2] += a1 * bq.z; acc[1][3] += a1 * bq.w;
      acc[2][0] += a2 * bq.x; acc[2][1] += a2 * bq.y; acc[2][2] += a2 * bq.z; acc[2][3] += a2 * bq.w;
      acc[3][0] += a3 * bq.x; acc[3][1] += a3 * bq.y; acc[3][2] += a3 * bq.z; acc[3][3] += a3 * bq.w;
    }
  }
  if (epi == 5) {
#pragma unroll
    for (int i = 0; i < 4; ++i) {
      int gr = m0 + ty * 4 + i;
      int bidx = gr >> 8, nn = gr & 255;
#pragma unroll
      for (int j = 0; j < 4; ++j) {
        int gc = n0 + tx * 4 + j;
        int which = gc >> 9, hh = (gc >> 6) & 7, dd = gc & 63;
        float val = acc[i][j];
        if (which == 0) val *= 0.125f;
        size_t idx = (((size_t)(bidx * 8 + hh)) * 256 + nn) * 64 + dd;
        float* dst = which == 0 ? qlp : klp;
        unsigned short* dst16 = which == 0 ? q16 : k16;
        dst[idx] = val;
        dst16[idx] = f2b(val);
      }
    }
  } else {  // epi 7
#pragma unroll
    for (int i = 0; i < 4; ++i) {
      int gr = m0 + ty * 4 + i;
#pragma unroll
      for (int j = 0; j < 4; ++j) {
        int gc = n0 + tx * 4 + j;
        q16[(size_t)bz * 16384 + (size_t)gr * 64 + gc] = f2b(acc[i][j]);
      }
    }
  }
}

// ------------- GEMM C = A[M,64] @ B[N,64]^T (sim2) -------------
__global__ __launch_bounds__(256)
void gemm_abt(const float* __restrict__ A, const float* __restrict__ Bm,
              float* __restrict__ C, int Kdim, int lda, int ldb, int ldc,
              long long sA, long long sB, long long sC) {
  __shared__ float As[16][64], Bs[16][64];
  int bz = blockIdx.z;
  A += sA * bz; Bm += sB * bz; C += sC * bz;
  int n0 = blockIdx.x * 64, m0 = blockIdx.y * 64;
  int tid = threadIdx.x, tx = tid & 15, ty = tid >> 4;
  int am = tid >> 2, akg = tid & 3;
  const float* Aload = A + (size_t)(m0 + am) * lda + akg * 4;
  const float* Bload = Bm + (size_t)(n0 + am) * ldb + akg * 4;
  float acc[4][4] = {};
  for (int k0 = 0; k0 < Kdim; k0 += 16) {
    float4 av = *reinterpret_cast<const float4*>(Aload + k0);
    float4 bv = *reinterpret_cast<const float4*>(Bload + k0);
    __syncthreads();
    As[akg * 4 + 0][am] = av.x; As[akg * 4 + 1][am] = av.y;
    As[akg * 4 + 2][am] = av.z; As[akg * 4 + 3][am] = av.w;
    Bs[akg * 4 + 0][am] = bv.x; Bs[akg * 4 + 1][am] = bv.y;
    Bs[akg * 4 + 2][am] = bv.z; Bs[akg * 4 + 3][am] = bv.w;
    __syncthreads();
#pragma unroll
    for (int kk = 0; kk < 16; ++kk) {
      float4 bq = *reinterpret_cast<const float4*>(&Bs[kk][tx * 4]);
      float a0 = As[kk][ty * 4 + 0], a1 = As[kk][ty * 4 + 1];
      float a2 = As[kk][ty * 4 + 2], a3 = As[kk][ty * 4 + 3];
      acc[0][0] += a0 * bq.x; acc[0][1] += a0 * bq.y; acc[0][2] += a0 * bq.z; acc[0][3] += a0 * bq.w;
      acc[1][0] += a1 * bq.x; acc[1][1] += a1 * bq.y; acc[1][2] += a1 * bq.z; acc[1][3] += a1 * bq.w;
      acc[2][0] += a2 * bq.x; acc[2][1] += a2 * bq.y; acc[2][2] += a2 * bq.z; acc[2][3] += a2 * bq.w;
      acc[3][0] += a3 * bq.x; acc[3][1] += a3 * bq.y; acc[3][2] += a3 * bq.z; acc[3][3] += a3 * bq.w;
    }
  }
#pragma unroll
  for (int i = 0; i < 4; ++i) {
    int gr = m0 + ty * 4 + i;
#pragma unroll
    for (int j = 0; j < 4; ++j)
      C[(size_t)gr * ldc + n0 + tx * 4 + j] = acc[i][j];
  }
}

// ------------- row softmax (256 cols) -------------
__global__ __launch_bounds__(256) void softmax_rows256(float* __restrict__ buf) {
  __shared__ float red[4];
  size_t row = blockIdx.x;
  float* r = buf + row * 256;
  int tid = threadIdx.x, lane = tid & 63, wid = tid >> 6;
  float v = r[tid];
  float mx = wave_max(v);
  if (!lane) red[wid] = mx;
  __syncthreads();
  mx = fmaxf(fmaxf(red[0], red[1]), fmaxf(red[2], red[3]));
  __syncthreads();
  float e = expf(v - mx);
  float s = wave_sum(e);
  if (!lane) red[wid] = s;
  __syncthreads();
  s = red[0] + red[1] + red[2] + red[3];
  r[tid] = e / s;
}

// ------------- pinv scalar: max column-sum -------------
__global__ void init_scalars(float* sc) { if (threadIdx.x < 2) sc[threadIdx.x] = 0.f; }

__global__ __launch_bounds__(256) void colsum_part(const float* __restrict__ a2,
                                                   float* __restrict__ part) {
  int bh = blockIdx.x >> 3, chunk = blockIdx.x & 7;
  int tid = threadIdx.x;
  const float* M = a2 + (size_t)bh * 65536 + (size_t)chunk * 32 * 256;
  float acc = 0.f;
#pragma unroll
  for (int r = 0; r < 32; ++r) acc += M[r * 256 + tid];
  part[(size_t)blockIdx.x * 256 + tid] = acc;
}

__global__ __launch_bounds__(256) void colsum_final(const float* __restrict__ part,
                                                    float* __restrict__ sc) {
  __shared__ float red[4];
  int bh = blockIdx.x;
  int tid = threadIdx.x, lane = tid & 63, w = tid >> 6;
  float s = 0.f;
#pragma unroll
  for (int c = 0; c < 8; ++c) s += part[(size_t)(bh * 8 + c) * 256 + tid];
  float m = wave_max(s);
  if (!lane) red[w] = m;
  __syncthreads();
  if (tid == 0) {
    float mm = fmaxf(fmaxf(red[0], red[1]), fmaxf(red[2], red[3]));
    atomicMax(reinterpret_cast<int*>(sc) + 1, __float_as_int(mm));
  }
}

// ------------- split attn2 hi/lo bf16: X, z0=X^T/c, z0^T=X/c -------------
__global__ __launch_bounds__(256) void hilo_split(
    const float* __restrict__ a2, const float* __restrict__ sc,
    unsigned short* __restrict__ Xh, unsigned short* __restrict__ Xl,
    unsigned short* __restrict__ zth, unsigned short* __restrict__ ztl,
    unsigned short* __restrict__ zh, unsigned short* __restrict__ zl) {
  __shared__ float t[64][65];
  int bz = blockIdx.z;
  size_t base = (size_t)bz * 65536;
  int i0 = blockIdx.y * 64, j0 = blockIdx.x * 64;
  int tid = threadIdx.x, tx = tid & 15, ty = tid >> 4;
  float inv = 1.f / sc[1];
#pragma unroll
  for (int rr = 0; rr < 64; rr += 16) {
    int gr = i0 + rr + ty, gc0 = j0 + tx * 4;
    float4 v = *(const float4*)&a2[base + (size_t)gr * 256 + gc0];
    t[rr + ty][tx * 4 + 0] = v.x; t[rr + ty][tx * 4 + 1] = v.y;
    t[rr + ty][tx * 4 + 2] = v.z; t[rr + ty][tx * 4 + 3] = v.w;
    ushort4 xh, xl2, sh, sl;
    float vv[4] = {v.x, v.y, v.z, v.w};
    unsigned short* ph = (unsigned short*)&xh;
    unsigned short* pl = (unsigned short*)&xl2;
    unsigned short* qh = (unsigned short*)&sh;
    unsigned short* ql2 = (unsigned short*)&sl;
#pragma unroll
    for (int j = 0; j < 4; ++j) {
      ph[j] = f2b(vv[j]);
      pl[j] = f2b(vv[j] - b2f(ph[j]));
      float s = vv[j] * inv;
      qh[j] = f2b(s);
      ql2[j] = f2b(s - b2f(qh[j]));
    }
    *(ushort4*)&Xh[base + (size_t)gr * 256 + gc0] = xh;
    *(ushort4*)&Xl[base + (size_t)gr * 256 + gc0] = xl2;
    *(ushort4*)&zth[base + (size_t)gr * 256 + gc0] = sh;
    *(ushort4*)&ztl[base + (size_t)gr * 256 + gc0] = sl;
  }
  __syncthreads();
#pragma unroll
  for (int rr = 0; rr < 64; rr += 16) {
    int gr = j0 + rr + ty;
    int gc0 = i0 + tx * 4;
    ushort4 zh4, zl4;
    unsigned short* ph = (unsigned short*)&zh4;
    unsigned short* pl = (unsigned short*)&zl4;
#pragma unroll
    for (int j = 0; j < 4; ++j) {
      float s = t[tx * 4 + j][rr + ty] * inv;
      ph[j] = f2b(s);
      pl[j] = f2b(s - b2f(ph[j]));
    }
    *(ushort4*)&zh[base + (size_t)gr * 256 + gc0] = zh4;
    *(ushort4*)&zl[base + (size_t)gr * 256 + gc0] = zl4;
  }
}

// ------------- NS hi/lo MFMA GEMM, XCD-swizzled -------------
__global__ __launch_bounds__(256) void ns_mfma(
    const unsigned short* __restrict__ Ah, const unsigned short* __restrict__ Al,
    const unsigned short* __restrict__ Bth, const unsigned short* __restrict__ Btl,
    const unsigned short* __restrict__ Eh, const unsigned short* __restrict__ El,
    float alpha, float diag, float beta,
    unsigned short* __restrict__ Ch, unsigned short* __restrict__ Cl,
    unsigned short* __restrict__ CTh, unsigned short* __restrict__ CTl,
    float* __restrict__ Cf) {
  __shared__ __align__(16) unsigned short AhS[64][72], AlS[64][72];
  __shared__ __align__(16) unsigned short BhS[64][72], BlS[64][72];
  const int tid = threadIdx.x;
  const int l16 = tid & 15, h8 = (tid & 63) >> 4, w = tid >> 6;
  int wg = (blockIdx.z * gridDim.y + blockIdx.y) * gridDim.x + blockIdx.x;
  wg = xcd_swz(wg, gridDim.x * gridDim.y * gridDim.z);
  const size_t base = (size_t)(wg >> 4) * 65536;   // batch: 16 tiles each
  const int m0 = ((wg >> 2) & 3) * 64, n0 = (wg & 3) * 64;
  const int wr = (w >> 1) * 32, wc = (w & 1) * 32;
  const int srow = tid >> 2, scol = (tid & 3) * 16;
  f32x4 acc[2][2] = {};
  for (int k0 = 0; k0 < 256; k0 += 64) {
    const size_t aoff = base + (size_t)(m0 + srow) * 256 + k0 + scol;
    const size_t boff = base + (size_t)(n0 + srow) * 256 + k0 + scol;
    *(u16x8*)&AhS[srow][scol] = *(const u16x8*)(Ah + aoff);
    *(u16x8*)&AhS[srow][scol + 8] = *(const u16x8*)(Ah + aoff + 8);
    *(u16x8*)&AlS[srow][scol] = *(const u16x8*)(Al + aoff);
    *(u16x8*)&AlS[srow][scol + 8] = *(const u16x8*)(Al + aoff + 8);
    *(u16x8*)&BhS[srow][scol] = *(const u16x8*)(Bth + boff);
    *(u16x8*)&BhS[srow][scol + 8] = *(const u16x8*)(Bth + boff + 8);
    *(u16x8*)&BlS[srow][scol] = *(const u16x8*)(Btl + boff);
    *(u16x8*)&BlS[srow][scol + 8] = *(const u16x8*)(Btl + boff + 8);
    __syncthreads();
#pragma unroll
    for (int ks = 0; ks < 2; ++ks) {
      bf16x8 ah[2], al[2], bh[2], bl[2];
#pragma unroll
      for (int mi = 0; mi < 2; ++mi) {
        ah[mi] = *(const bf16x8*)&AhS[wr + mi * 16 + l16][ks * 32 + h8 * 8];
        al[mi] = *(const bf16x8*)&AlS[wr + mi * 16 + l16][ks * 32 + h8 * 8];
      }
#pragma unroll
      for (int nj = 0; nj < 2; ++nj) {
        bh[nj] = *(const bf16x8*)&BhS[wc + nj * 16 + l16][ks * 32 + h8 * 8];
        bl[nj] = *(const bf16x8*)&BlS[wc + nj * 16 + l16][ks * 32 + h8 * 8];
      }
#pragma unroll
      for (int mi = 0; mi < 2; ++mi)
#pragma unroll
        for (int nj = 0; nj < 2; ++nj) {
          acc[mi][nj] = mfma16(ah[mi], bh[nj], acc[mi][nj]);
          acc[mi][nj] = mfma16(ah[mi], bl[nj], acc[mi][nj]);
          acc[mi][nj] = mfma16(al[mi], bh[nj], acc[mi][nj]);
        }
    }
    __syncthreads();
  }
#pragma unroll
  for (int mi = 0; mi < 2; ++mi)
#pragma unroll
    for (int nj = 0; nj < 2; ++nj) {
      int grow0 = m0 + wr + mi * 16 + 4 * h8;
      int gcol = n0 + wc + nj * 16 + l16;
      float vals[4];
      ushort4 th, tl;
      unsigned short* ph = (unsigned short*)&th;
      unsigned short* pl = (unsigned short*)&tl;
#pragma unroll
      for (int r = 0; r < 4; ++r) {
        int grow = grow0 + r;
        float v = alpha * acc[mi][nj][r];
        if (grow == gcol) v += diag;
        if (Eh) v += beta * (b2f(Eh[base + (size_t)grow * 256 + gcol]) +
                             b2f(El[base + (size_t)grow * 256 + gcol]));
        vals[r] = v;
        ph[r] = f2b(v);
        pl[r] = f2b(v - b2f(ph[r]));
      }
      if (Ch) {
#pragma unroll
        for (int r = 0; r < 4; ++r) {
          Ch[base + (size_t)(grow0 + r) * 256 + gcol] = ph[r];
          Cl[base + (size_t)(grow0 + r) * 256 + gcol] = pl[r];
        }
      }
      if (CTh) {
        *(ushort4*)&CTh[base + (size_t)gcol * 256 + grow0] = th;
        *(ushort4*)&CTl[base + (size_t)gcol * 256 + grow0] = tl;
      }
      if (Cf) {
#pragma unroll
        for (int r = 0; r < 4; ++r)
          Cf[base + (size_t)(grow0 + r) * 256 + gcol] = vals[r];
      }
    }
}

// ------------- MFMA flash, transposed PV accumulator -------------
// MODE 0: split-K partials (float4 Opart + ML)   MODE 1: normalize + bf16 outh
template <int MODE>
__global__ __launch_bounds__(256) void flash_mfma(
    const unsigned short* __restrict__ Q, const unsigned short* __restrict__ Kp,
    const unsigned short* __restrict__ Vp, long long sQ, long long sK,
    int kps, int nkt,
    float* __restrict__ Opart, float* __restrict__ MLpart,
    unsigned short* __restrict__ outh16) {
  __shared__ __align__(16) unsigned short Qt[128][72];
  __shared__ __align__(16) unsigned short Kt[64][72];
  __shared__ __align__(16) unsigned short Vt[64][72];
  __shared__ __align__(16) unsigned short Pb[128][72];
  __shared__ float scfb[128], linvb[128];
  const int tid = threadIdx.x;
  const int l16 = tid & 15, h8 = (tid & 63) >> 4, w = tid >> 6;
  const int bh = blockIdx.y, s = blockIdx.z, qt = blockIdx.x;
  const int q0 = qt * 128;
  const unsigned short* Qb = Q + (size_t)bh * sQ + (size_t)q0 * 64;
  const unsigned short* Kb = Kp + (size_t)bh * sK + (size_t)s * kps * 64;
  const unsigned short* Vb = Vp + (size_t)bh * sK + (size_t)s * kps * 64;
  {
    int row = tid >> 1, c0 = (tid & 1) * 32;
#pragma unroll
    for (int i = 0; i < 4; ++i)
      *(u16x8*)&Qt[row][c0 + 8 * i] = *(const u16x8*)(Qb + (size_t)row * 64 + c0 + 8 * i);
  }
  f32x4 acc_o[2][4] = {};
  float mrow[2][4], lrow[2][4];
#pragma unroll
  for (int mi = 0; mi < 2; ++mi)
#pragma unroll
    for (int r = 0; r < 4; ++r) { mrow[mi][r] = -1e30f; lrow[mi][r] = 0.f; }
  for (int kt = 0; kt < nkt; ++kt) {
    {
      int row = tid >> 2, c0 = (tid & 3) * 16;
      *(u16x8*)&Kt[row][c0] = *(const u16x8*)(Kb + ((size_t)(kt * 64 + row)) * 64 + c0);
      *(u16x8*)&Kt[row][c0 + 8] = *(const u16x8*)(Kb + ((size_t)(kt * 64 + row)) * 64 + c0 + 8);
      int key = tid & 63, d0 = w * 16;
      u16x8 v0 = *(const u16x8*)(Vb + ((size_t)(kt * 64 + key)) * 64 + d0);
      u16x8 v1 = *(const u16x8*)(Vb + ((size_t)(kt * 64 + key)) * 64 + d0 + 8);
#pragma unroll
      for (int i = 0; i < 8; ++i) { Vt[d0 + i][key] = v0[i]; Vt[d0 + 8 + i][key] = v1[i]; }
    }
    __syncthreads();
    f32x4 accs[2][4] = {};
#pragma unroll
    for (int ks = 0; ks < 2; ++ks) {
      bf16x8 a[2], b[4];
      a[0] = *(const bf16x8*)&Qt[w * 32 + l16][ks * 32 + h8 * 8];
      a[1] = *(const bf16x8*)&Qt[w * 32 + 16 + l16][ks * 32 + h8 * 8];
#pragma unroll
      for (int nj = 0; nj < 4; ++nj)
        b[nj] = *(const bf16x8*)&Kt[nj * 16 + l16][ks * 32 + h8 * 8];
#pragma unroll
      for (int mi = 0; mi < 2; ++mi)
#pragma unroll
        for (int nj = 0; nj < 4; ++nj)
          accs[mi][nj] = mfma16(a[mi], b[nj], accs[mi][nj]);
    }
#pragma unroll
    for (int mi = 0; mi < 2; ++mi)
#pragma unroll
      for (int r = 0; r < 4; ++r) {
        float mx = fmaxf(fmaxf(accs[mi][0][r], accs[mi][1][r]),
                         fmaxf(accs[mi][2][r], accs[mi][3][r]));
#pragma unroll
        for (int off = 8; off; off >>= 1) mx = fmaxf(mx, __shfl_xor(mx, off, 64));
        float mn = fmaxf(mrow[mi][r], mx);
        float scf = __expf(mrow[mi][r] - mn);
        float ps = 0.f;
#pragma unroll
        for (int nj = 0; nj < 4; ++nj) {
          float p = __expf(accs[mi][nj][r] - mn);
          accs[mi][nj][r] = p;
          ps += p;
        }
#pragma unroll
        for (int off = 8; off; off >>= 1) ps += __shfl_xor(ps, off, 64);
        lrow[mi][r] = lrow[mi][r] * scf + ps;
        mrow[mi][r] = mn;
        int prow = w * 32 + mi * 16 + 4 * h8 + r;
        scfb[prow] = scf;
#pragma unroll
        for (int nj = 0; nj < 4; ++nj)
          Pb[prow][nj * 16 + l16] = f2b(accs[mi][nj][r]);
      }
    __syncthreads();
#pragma unroll
    for (int mi = 0; mi < 2; ++mi) {
      float sc2 = scfb[w * 32 + mi * 16 + l16];
#pragma unroll
      for (int dj = 0; dj < 4; ++dj) {
        acc_o[mi][dj][0] *= sc2; acc_o[mi][dj][1] *= sc2;
        acc_o[mi][dj][2] *= sc2; acc_o[mi][dj][3] *= sc2;
      }
    }
#pragma unroll
    for (int ks = 0; ks < 2; ++ks) {
      bf16x8 pa[2], vb2[4];
      pa[0] = *(const bf16x8*)&Pb[w * 32 + l16][ks * 32 + h8 * 8];
      pa[1] = *(const bf16x8*)&Pb[w * 32 + 16 + l16][ks * 32 + h8 * 8];
#pragma unroll
      for (int dj = 0; dj < 4; ++dj)
        vb2[dj] = *(const bf16x8*)&Vt[dj * 16 + l16][ks * 32 + h8 * 8];
#pragma unroll
      for (int mi = 0; mi < 2; ++mi)
#pragma unroll
        for (int dj = 0; dj < 4; ++dj)
          acc_o[mi][dj] = mfma16(vb2[dj], pa[mi], acc_o[mi][dj]);  // swapped
    }
    __syncthreads();
  }
  if (MODE == 0) {
    int p = (s * 32 + bh) * 2 + qt;
    float* Ob = Opart + (size_t)p * 8192;
#pragma unroll
    for (int mi = 0; mi < 2; ++mi) {
      int row = w * 32 + mi * 16 + l16;
#pragma unroll
      for (int dj = 0; dj < 4; ++dj) {
        int d0 = dj * 16 + 4 * h8;
        *(float4*)&Ob[(size_t)row * 64 + d0] =
            make_float4(acc_o[mi][dj][0], acc_o[mi][dj][1], acc_o[mi][dj][2], acc_o[mi][dj][3]);
      }
#pragma unroll
      for (int r = 0; r < 4; ++r) {
        int prow = w * 32 + mi * 16 + 4 * h8 + r;
        if (l16 == 0) {
          MLpart[((size_t)p * 128 + prow) * 2] = mrow[mi][r];
          MLpart[((size_t)p * 128 + prow) * 2 + 1] = lrow[mi][r];
        }
      }
    }
  } else {
    int bidx = bh >> 3, hh = bh & 7;
#pragma unroll
    for (int mi = 0; mi < 2; ++mi)
#pragma unroll
      for (int r = 0; r < 4; ++r)
        linvb[w * 32 + mi * 16 + 4 * h8 + r] = 1.f / lrow[mi][r];
    __syncthreads();
#pragma unroll
    for (int mi = 0; mi < 2; ++mi) {
      int jrow = w * 32 + mi * 16 + l16;
      float linv = linvb[jrow];
      int qr = q0 + jrow;
#pragma unroll
      for (int dj = 0; dj < 4; ++dj) {
        int d0 = dj * 16 + 4 * h8;
        ushort4 o;
        o.x = f2b(acc_o[mi][dj][0] * linv);
        o.y = f2b(acc_o[mi][dj][1] * linv);
        o.z = f2b(acc_o[mi][dj][2] * linv);
        o.w = f2b(acc_o[mi][dj][3] * linv);
        *(ushort4*)&outh16[((size_t)bidx * NTOK + qr) * 512 + hh * 64 + d0] = o;
      }
    }
  }
}

// ------------- combine split-K flash partials -> T3 -------------
__global__ __launch_bounds__(256) void flash_combine(const float* __restrict__ Opart,
                                                     const float* __restrict__ MLpart,
                                                     float* __restrict__ T3) {
  int bh = blockIdx.y;
  int row = blockIdx.x * 4 + (threadIdx.x >> 6);
  int d = threadIdx.x & 63;
  int qt = row >> 7, rowin = row & 127;
  float mstar = -1e30f;
#pragma unroll
  for (int s = 0; s < 8; ++s) {
    int p = (s * 32 + bh) * 2 + qt;
    mstar = fmaxf(mstar, MLpart[((size_t)p * 128 + rowin) * 2]);
  }
  float L = 0.f, O = 0.f;
#pragma unroll
  for (int s = 0; s < 8; ++s) {
    int p = (s * 32 + bh) * 2 + qt;
    float ms = MLpart[((size_t)p * 128 + rowin) * 2];
    float ls = MLpart[((size_t)p * 128 + rowin) * 2 + 1];
    float e = __expf(ms - mstar);
    L += ls * e;
    O += Opart[(size_t)p * 8192 + rowin * 64 + d] * e;
  }
  T3[((size_t)bh * 256 + row) * 64 + d] = O / L;
}

// ------------- depthwise conv, input-major sliding accumulation -------------
__global__ __launch_bounds__(256) void conv_add_bf16(const unsigned short* __restrict__ v,
                                                     const float* __restrict__ cw,
                                                     unsigned short* __restrict__ outh16) {
  __shared__ float vt[96][68];
  int z = blockIdx.x;
  int bh = z >> 7, n0 = (z & 127) * 64;
  int tid = threadIdx.x;
  const unsigned short* vb = v + (size_t)bh * NTOK * 64;
  for (int f = tid; f < 768; f += 256) {
    int rowi = f >> 3, c8 = (f & 7) * 8;
    int rn = n0 - 16 + rowi;
    if (rn >= 0 && rn < NTOK) {
      u16x8 val = *(const u16x8*)(vb + (size_t)rn * 64 + c8);
#pragma unroll
      for (int i = 0; i < 8; ++i) vt[rowi][c8 + i] = b2f(val[i]);
    } else {
#pragma unroll
      for (int i = 0; i < 8; ++i) vt[rowi][c8 + i] = 0.f;
    }
  }
  float wreg[33];
#pragma unroll
  for (int k = 0; k < 33; ++k) wreg[k] = cw[(bh & 7) * 33 + k];
  __syncthreads();
  int dd = tid & 63, rg = tid >> 6;
  int bidx = bh >> 3, hh = bh & 7;
  float acc[16];
#pragma unroll
  for (int r = 0; r < 16; ++r) acc[r] = 0.f;
#pragma unroll
  for (int j = 0; j < 48; ++j) {
    float vv = vt[rg * 16 + j][dd];
    int rlo = j - 32 < 0 ? 0 : j - 32;
    int rhi = j < 15 ? j : 15;
#pragma unroll
    for (int r = 0; r < 16; ++r)
      if (r >= rlo && r <= rhi) acc[r] += wreg[j - r] * vv;
  }
#pragma unroll
  for (int r = 0; r < 16; ++r) {
    size_t o = ((size_t)bidx * NTOK + n0 + rg * 16 + r) * 512 + hh * 64 + dd;
    outh16[o] = f2b(b2f(outh16[o]) + acc[r]);
  }
}

extern "C" void kernel_launch(void* const* d_in, const int* in_sizes, int n_in,
                              void* d_out, int out_size, void* d_ws, size_t ws_size,
                              hipStream_t stream) {
  const float* x = (const float*)d_in[0];
  const float* gamma = (const float*)d_in[1];
  const float* beta = (const float*)d_in[2];
  const float* w_qkv = (const float*)d_in[3];
  const float* w_out = (const float*)d_in[4];
  const float* b_out = (const float*)d_in[5];
  const float* conv_w = (const float*)d_in[6];
  float* out = (float*)d_out;
  float* ws = (float*)d_ws;
  (void)ws_size; (void)in_sizes; (void)n_in; (void)out_size;

  float* A0 = ws;
  float* Breg = ws + 16777216;
  unsigned short* qb = (unsigned short*)(ws + 25165824);
  unsigned short* kb = (unsigned short*)(ws + 33554432);
  unsigned short* vb = (unsigned short*)(ws + 41943040);
  float* Fs = ws + 50331648;

  // A0 tenants
  float* X2 = A0;
  float* zfinal = A0;
  float* ql = A0 + 2097152;
  float* kl = A0 + 2621440;
  unsigned short* Xh  = (unsigned short*)(A0 + 2097152);
  unsigned short* Xl  = (unsigned short*)(A0 + 3145728);
  unsigned short* zAh = (unsigned short*)(A0 + 4194304);
  unsigned short* zAl = (unsigned short*)(A0 + 5242880);
  unsigned short* zAth = (unsigned short*)(A0 + 6291456);
  unsigned short* zAtl = (unsigned short*)(A0 + 7340032);
  unsigned short* zYh = (unsigned short*)(A0 + 8388608);
  unsigned short* zYl = (unsigned short*)(A0 + 9437184);
  unsigned short* zYth = (unsigned short*)(A0 + 10485760);
  unsigned short* zYtl = (unsigned short*)(A0 + 11534336);
  unsigned short* TBth = (unsigned short*)(A0 + 12582912);
  unsigned short* TBtl = (unsigned short*)(A0 + 13631488);
  unsigned short* TAth = (unsigned short*)(A0 + 14680064);
  unsigned short* TAtl = (unsigned short*)(A0 + 15728640);
  unsigned short* outh16 = (unsigned short*)A0;
  // Breg tenants
  unsigned short* xnb = (unsigned short*)Breg;
  float* Opart = Breg;
  float* MLpart = Breg + 4194304;
  float* T3 = Breg + 4325376;
  // Fs tenants
  float* xl = Fs;
  unsigned short* qlb = (unsigned short*)(Fs + 524288);
  unsigned short* klb = (unsigned short*)(Fs + 786432);
  unsigned short* W2b = (unsigned short*)(Fs + 1048576);
  unsigned short* woutT = (unsigned short*)(Fs + 1310720);
  unsigned short* wqkvT = (unsigned short*)(Fs + 1441792);
  float* part = Fs + 1835008;
  float* sc = Fs + 1900544;

  // 1. fused LayerNorm + pooling
  ln_pool<<<1024, 256, 0, stream>>>(x, gamma, beta, xnb, xl);
  // 2. weight transposes
  transpose_cvt<<<dim3(48, 16), 256, 0, stream>>>(w_qkv, wqkvT, 512, 1536);
  transpose_cvt<<<dim3(16, 16), 256, 0, stream>>>(w_out, woutT, 512, 512);
  // 3. qkv projection (XCD-swizzled)
  gemm_mfma<0><<<dim3(12, 256), 256, 0, stream>>>(xnb, wqkvT, 512, qb, kb, vb,
                                                  nullptr, nullptr, nullptr);
  // 4. ql/kl = xl @ Wq/Wk fp32 (+ bf16 fused)
  gemm_ab<<<dim3(16, 16, 1), 256, 0, stream>>>(xl, w_qkv, 512, 512, 1536, 0, 0,
                                               5, ql, kl, qlb, klb);
  // 5. sim2 -> attn2 (fp32)
  gemm_abt<<<dim3(4, 4, BH), 256, 0, stream>>>(ql, kl, X2, 64, 64, 64, 256,
                                               16384, 16384, 65536);
  softmax_rows256<<<BH * NM, 256, 0, stream>>>(X2);
  // 6. pinv scalar + hi/lo split
  init_scalars<<<1, 64, 0, stream>>>(sc);
  colsum_part<<<BH * 8, 256, 0, stream>>>(X2, part);
  colsum_final<<<BH, 256, 0, stream>>>(part, sc);
  hilo_split<<<dim3(4, 4, BH), 256, 0, stream>>>(X2, sc, Xh, Xl, zAth, zAtl, zAh, zAl);
  // 7. Newton-Schulz hi/lo MFMA (XCD-swizzled)
  unsigned short *ch = zAh, *cl = zAl, *cth = zAth, *ctl = zAtl;
  unsigned short *yh = zYh, *yl = zYl, *yth = zYth, *ytl = zYtl;
  for (int it = 0; it < 6; ++it) {
    ns_mfma<<<dim3(4, 4, BH), 256, 0, stream>>>(Xh, Xl, cth, ctl, nullptr, nullptr,
                                                1.f, 0.f, 0.f, yh, yl, yth, ytl, nullptr);
    ns_mfma<<<dim3(4, 4, BH), 256, 0, stream>>>(yh, yl, yth, ytl, yh, yl,
                                                1.f, 15.f, -7.f, nullptr, nullptr,
                                                TBth, TBtl, nullptr);
    ns_mfma<<<dim3(4, 4, BH), 256, 0, stream>>>(yh, yl, TBth, TBtl, nullptr, nullptr,
                                                -1.f, 13.f, 0.f, nullptr, nullptr,
                                                TAth, TAtl, nullptr);
    ns_mfma<<<dim3(4, 4, BH), 256, 0, stream>>>(ch, cl, TAth, TAtl, nullptr, nullptr,
                                                0.25f, 0.f, 0.f, yh, yl, yth, ytl,
                                                it == 5 ? zfinal : nullptr);
    unsigned short* t;
    t = ch; ch = yh; yh = t;  t = cl; cl = yl; yl = t;
    t = cth; cth = yth; yth = t;  t = ctl; ctl = ytl; ytl = t;
  }
  // 8. flash A (split-K=8)
  flash_mfma<0><<<dim3(2, 32, 8), 256, 0, stream>>>(qlb, kb, vb, 16384, 524288,
                                                    1024, 16, Opart, MLpart, nullptr);
  flash_combine<<<dim3(64, 32), 256, 0, stream>>>(Opart, MLpart, T3);
  // 9. W2 = pinv @ T3 -> bf16
  gemm_ab<<<dim3(1, 4, BH), 256, 0, stream>>>(zfinal, T3, 256, 256, 64, 65536, 16384,
                                              7, nullptr, nullptr, W2b, nullptr);
  // 10. flash B -> bf16 outh (plain epilogue)
  flash_mfma<1><<<dim3(64, 32, 1), 256, 0, stream>>>(qb, klb, W2b, 524288, 16384,
                                                     0, 4, nullptr, nullptr, outh16);
  // 11. conv residual
  conv_add_bf16<<<BH * (NTOK / 64), 256, 0, stream>>>(vb, conv_w, outh16);
  // 12. out = x + outh @ w_out + b_out (XCD-swizzled)
  gemm_mfma<2><<<dim3(4, 256), 256, 0, stream>>>(outh16, woutT, 512, nullptr, nullptr,
                                                 nullptr, out, b_out, x);
}

// Round 11
// 626.953 us; speedup vs baseline: 4.8947x; 1.0568x over previous
//
#include <hip/hip_runtime.h>

#define NTOK 8192
#define TOT 32768
#define DMODEL 512
#define NM 256
#define BH 32

typedef __attribute__((ext_vector_type(8))) short bf16x8;
typedef __attribute__((ext_vector_type(8))) unsigned short u16x8;
typedef __attribute__((ext_vector_type(4))) float f32x4;

__device__ __forceinline__ unsigned short f2b(float f) {
  unsigned u = __float_as_uint(f);
  return (unsigned short)((u + 0x7fffu + ((u >> 16) & 1u)) >> 16);
}
__device__ __forceinline__ float b2f(unsigned short h) {
  return __uint_as_float((unsigned)h << 16);
}
__device__ __forceinline__ f32x4 mfma16(bf16x8 a, bf16x8 b, f32x4 c) {
  return __builtin_amdgcn_mfma_f32_16x16x32_bf16(a, b, c, 0, 0, 0);
}
__device__ __forceinline__ float wave_sum(float v) {
#pragma unroll
  for (int o = 32; o; o >>= 1) v += __shfl_xor(v, o, 64);
  return v;
}
__device__ __forceinline__ float wave_max(float v) {
#pragma unroll
  for (int o = 32; o; o >>= 1) v = fmaxf(v, __shfl_xor(v, o, 64));
  return v;
}
// bijective XCD swizzle (requires nwg % 8 == 0): XCD k owns contiguous chunk k
__device__ __forceinline__ int xcd_swz(int wg, int nwg) {
  return (wg & 7) * (nwg >> 3) + (wg >> 3);
}

// ------------- fused LayerNorm + pooling, wave-per-row -------------
__global__ __launch_bounds__(256) void ln_pool(const float* __restrict__ x,
                                               const float* __restrict__ g,
                                               const float* __restrict__ b,
                                               unsigned short* __restrict__ xnb,
                                               float* __restrict__ xl) {
  __shared__ float pp[4][512];
  int tid = threadIdx.x, lane = tid & 63, w = tid >> 6;
  int c0 = lane * 8;
  float4 g0 = *(const float4*)&g[c0], g1 = *(const float4*)&g[c0 + 4];
  float4 b0 = *(const float4*)&b[c0], b1 = *(const float4*)&b[c0 + 4];
  float pa[8] = {};
  size_t rbase = (size_t)blockIdx.x * 32 + w * 8;
  for (int j = 0; j < 8; ++j) {
    size_t row = rbase + j;
    float4 v0 = *(const float4*)&x[row * DMODEL + c0];
    float4 v1 = *(const float4*)&x[row * DMODEL + c0 + 4];
    float s = v0.x + v0.y + v0.z + v0.w + v1.x + v1.y + v1.z + v1.w;
    float ss = v0.x * v0.x + v0.y * v0.y + v0.z * v0.z + v0.w * v0.w +
               v1.x * v1.x + v1.y * v1.y + v1.z * v1.z + v1.w * v1.w;
    s = wave_sum(s);
    ss = wave_sum(ss);
    float mu = s * (1.f / DMODEL);
    float var = ss * (1.f / DMODEL) - mu * mu;
    float rstd = rsqrtf(var + 1e-5f);
    float o[8];
    o[0] = (v0.x - mu) * rstd * g0.x + b0.x; o[1] = (v0.y - mu) * rstd * g0.y + b0.y;
    o[2] = (v0.z - mu) * rstd * g0.z + b0.z; o[3] = (v0.w - mu) * rstd * g0.w + b0.w;
    o[4] = (v1.x - mu) * rstd * g1.x + b1.x; o[5] = (v1.y - mu) * rstd * g1.y + b1.y;
    o[6] = (v1.z - mu) * rstd * g1.z + b1.z; o[7] = (v1.w - mu) * rstd * g1.w + b1.w;
    u16x8 pk;
#pragma unroll
    for (int i = 0; i < 8; ++i) { pk[i] = f2b(o[i]); pa[i] += o[i]; }
    *(u16x8*)&xnb[row * DMODEL + c0] = pk;
  }
  *(float4*)&pp[w][c0] = make_float4(pa[0], pa[1], pa[2], pa[3]);
  *(float4*)&pp[w][c0 + 4] = make_float4(pa[4], pa[5], pa[6], pa[7]);
  __syncthreads();
#pragma unroll
  for (int c = tid; c < 512; c += 256) {
    float s = pp[0][c] + pp[1][c] + pp[2][c] + pp[3][c];
    xl[(size_t)blockIdx.x * DMODEL + c] = s * (1.f / 32.f);
  }
}

// ------------- transpose + cvt fp32[K][N] -> bf16[N][K] -------------
__global__ __launch_bounds__(256) void transpose_cvt(const float* __restrict__ in,
                                                     unsigned short* __restrict__ outp,
                                                     int K, int N) {
  __shared__ float t[32][33];
  int k0 = blockIdx.y * 32, n0 = blockIdx.x * 32;
  int tx = threadIdx.x & 31, ty = threadIdx.x >> 5;
#pragma unroll
  for (int i = 0; i < 32; i += 8)
    t[ty + i][tx] = in[(size_t)(k0 + ty + i) * N + n0 + tx];
  __syncthreads();
#pragma unroll
  for (int i = 0; i < 32; i += 8)
    outp[(size_t)(n0 + ty + i) * K + k0 + tx] = f2b(t[tx][ty + i]);
}

// ------------- MFMA GEMM NT, swapped-fragment epilogue, XCD-swizzled --------
// EPI 0: scatter qkv (q*0.125) as bf16, ushort4 stores
// EPI 2: Cf = AB + bias + resid, float4 stores
template <int EPI>
__global__ __launch_bounds__(256) void gemm_mfma(const unsigned short* __restrict__ Ab,
                                                 const unsigned short* __restrict__ Bt,
                                                 int Kd,
                                                 unsigned short* __restrict__ qo,
                                                 unsigned short* __restrict__ ko,
                                                 unsigned short* __restrict__ vo,
                                                 float* __restrict__ Cf,
                                                 const float* __restrict__ bias,
                                                 const float* __restrict__ resid) {
  __shared__ __align__(16) unsigned short As[128][72];
  __shared__ __align__(16) unsigned short Bs[128][72];
  const int tid = threadIdx.x;
  const int l16 = tid & 15, h8 = (tid & 63) >> 4, w = tid >> 6;
  const int nwg = gridDim.x * gridDim.y;
  int wg = xcd_swz(blockIdx.y * gridDim.x + blockIdx.x, nwg);
  const int m0 = (wg / gridDim.x) * 128, n0 = (wg % gridDim.x) * 128;
  const int wr = (w >> 1) * 64, wc = (w & 1) * 64;
  const int srow = tid >> 1, sc0 = (tid & 1) * 32;
  f32x4 acc[4][4] = {};
  for (int k0 = 0; k0 < Kd; k0 += 64) {
    const unsigned short* Ap = Ab + (size_t)(m0 + srow) * Kd + k0 + sc0;
#pragma unroll
    for (int i = 0; i < 4; ++i)
      *(u16x8*)&As[srow][sc0 + 8 * i] = *(const u16x8*)(Ap + 8 * i);
    const unsigned short* Bb = Bt + (size_t)(n0 + srow) * Kd + k0 + sc0;
#pragma unroll
    for (int i = 0; i < 4; ++i)
      *(u16x8*)&Bs[srow][sc0 + 8 * i] = *(const u16x8*)(Bb + 8 * i);
    __syncthreads();
#pragma unroll
    for (int ks = 0; ks < 2; ++ks) {
      bf16x8 a[4], b[4];
#pragma unroll
      for (int mi = 0; mi < 4; ++mi)
        a[mi] = *(const bf16x8*)&As[wr + mi * 16 + l16][ks * 32 + h8 * 8];
#pragma unroll
      for (int nj = 0; nj < 4; ++nj)
        b[nj] = *(const bf16x8*)&Bs[wc + nj * 16 + l16][ks * 32 + h8 * 8];
#pragma unroll
      for (int mi = 0; mi < 4; ++mi)
#pragma unroll
        for (int nj = 0; nj < 4; ++nj)
          acc[mi][nj] = mfma16(b[nj], a[mi], acc[mi][nj]);  // swapped
    }
    __syncthreads();
  }
#pragma unroll
  for (int mi = 0; mi < 4; ++mi) {
    int grow = m0 + wr + mi * 16 + l16;
#pragma unroll
    for (int nj = 0; nj < 4; ++nj) {
      int gcol0 = n0 + wc + nj * 16 + 4 * h8;
      if (EPI == 0) {
        int which = gcol0 >> 9, hh = (gcol0 >> 6) & 7, dd0 = gcol0 & 63;
        int bidx = grow >> 13, nn = grow & 8191;
        float scl = which == 0 ? 0.125f : 1.f;
        ushort4 o;
        o.x = f2b(acc[mi][nj][0] * scl); o.y = f2b(acc[mi][nj][1] * scl);
        o.z = f2b(acc[mi][nj][2] * scl); o.w = f2b(acc[mi][nj][3] * scl);
        unsigned short* dst = which == 0 ? qo : (which == 1 ? ko : vo);
        *(ushort4*)&dst[(((size_t)(bidx * 8 + hh)) * NTOK + nn) * 64 + dd0] = o;
      } else {
        float4 bi = *(const float4*)&bias[gcol0];
        float4 re = *(const float4*)&resid[(size_t)grow * 512 + gcol0];
        float4 o;
        o.x = acc[mi][nj][0] + bi.x + re.x; o.y = acc[mi][nj][1] + bi.y + re.y;
        o.z = acc[mi][nj][2] + bi.z + re.z; o.w = acc[mi][nj][3] + bi.w + re.w;
        *(float4*)&Cf[(size_t)grow * 512 + gcol0] = o;
      }
    }
  }
}

// ------------- fp32 GEMM (landmark path), epi 5 / 7 -------------
__global__ __launch_bounds__(256)
void gemm_ab(const float* __restrict__ A, const float* __restrict__ Bm,
             int Kdim, int lda, int ldb,
             long long sA, long long sB, int epi,
             float* __restrict__ qlp, float* __restrict__ klp,
             unsigned short* __restrict__ q16, unsigned short* __restrict__ k16) {
  __shared__ float As[16][64], Bs[16][64];
  int bz = blockIdx.z;
  A += sA * bz; Bm += sB * bz;
  int n0 = blockIdx.x * 64, m0 = blockIdx.y * 64;
  int tid = threadIdx.x, tx = tid & 15, ty = tid >> 4;
  int am = tid >> 2, akg = tid & 3, bk = tid >> 4, bng = tid & 15;
  const float* Aload = A + (size_t)(m0 + am) * lda + akg * 4;
  const float* Bload = Bm + (size_t)bk * ldb + n0 + bng * 4;
  float acc[4][4] = {};
  for (int k0 = 0; k0 < Kdim; k0 += 16) {
    float4 av = *reinterpret_cast<const float4*>(Aload + k0);
    float4 bv = *reinterpret_cast<const float4*>(Bload + (size_t)k0 * ldb);
    __syncthreads();
    As[akg * 4 + 0][am] = av.x; As[akg * 4 + 1][am] = av.y;
    As[akg * 4 + 2][am] = av.z; As[akg * 4 + 3][am] = av.w;
    *reinterpret_cast<float4*>(&Bs[bk][bng * 4]) = bv;
    __syncthreads();
#pragma unroll
    for (int kk = 0; kk < 16; ++kk) {
      float4 bq = *reinterpret_cast<const float4*>(&Bs[kk][tx * 4]);
      float a0 = As[kk][ty * 4 + 0], a1 = As[kk][ty * 4 + 1];
      float a2 = As[kk][ty * 4 + 2], a3 = As[kk][ty * 4 + 3];
      acc[0][0] += a0 * bq.x; acc[0][1] += a0 * bq.y; acc[0][2] += a0 * bq.z; acc[0][3] += a0 * bq.w;
      acc[1][0] += a1 * bq.x; acc[1][1] += a1 * bq.y; acc[1][2] += a1 * bq.z; acc[1][3] += a1 * bq.w;
      acc[2][0] += a2 * bq.x; acc[2][1] += a2 * bq.y; acc[2][2] += a2 * bq.z; acc[2][3] += a2 * bq.w;
      acc[3][0] += a3 * bq.x; acc[3][1] += a3 * bq.y; acc[3][2] += a3 * bq.z; acc[3][3] += a3 * bq.w;
    }
  }
  if (epi == 5) {
#pragma unroll
    for (int i = 0; i < 4; ++i) {
      int gr = m0 + ty * 4 + i;
      int bidx = gr >> 8, nn = gr & 255;
#pragma unroll
      for (int j = 0; j < 4; ++j) {
        int gc = n0 + tx * 4 + j;
        int which = gc >> 9, hh = (gc >> 6) & 7, dd = gc & 63;
        float val = acc[i][j];
        if (which == 0) val *= 0.125f;
        size_t idx = (((size_t)(bidx * 8 + hh)) * 256 + nn) * 64 + dd;
        float* dst = which == 0 ? qlp : klp;
        unsigned short* dst16 = which == 0 ? q16 : k16;
        dst[idx] = val;
        dst16[idx] = f2b(val);
      }
    }
  } else {  // epi 7
#pragma unroll
    for (int i = 0; i < 4; ++i) {
      int gr = m0 + ty * 4 + i;
#pragma unroll
      for (int j = 0; j < 4; ++j) {
        int gc = n0 + tx * 4 + j;
        q16[(size_t)bz * 16384 + (size_t)gr * 64 + gc] = f2b(acc[i][j]);
      }
    }
  }
}

// ------------- GEMM C = A[M,64] @ B[N,64]^T (sim2) -------------
__global__ __launch_bounds__(256)
void gemm_abt(const float* __restrict__ A, const float* __restrict__ Bm,
              float* __restrict__ C, int Kdim, int lda, int ldb, int ldc,
              long long sA, long long sB, long long sC) {
  __shared__ float As[16][64], Bs[16][64];
  int bz = blockIdx.z;
  A += sA * bz; Bm += sB * bz; C += sC * bz;
  int n0 = blockIdx.x * 64, m0 = blockIdx.y * 64;
  int tid = threadIdx.x, tx = tid & 15, ty = tid >> 4;
  int am = tid >> 2, akg = tid & 3;
  const float* Aload = A + (size_t)(m0 + am) * lda + akg * 4;
  const float* Bload = Bm + (size_t)(n0 + am) * ldb + akg * 4;
  float acc[4][4] = {};
  for (int k0 = 0; k0 < Kdim; k0 += 16) {
    float4 av = *reinterpret_cast<const float4*>(Aload + k0);
    float4 bv = *reinterpret_cast<const float4*>(Bload + k0);
    __syncthreads();
    As[akg * 4 + 0][am] = av.x; As[akg * 4 + 1][am] = av.y;
    As[akg * 4 + 2][am] = av.z; As[akg * 4 + 3][am] = av.w;
    Bs[akg * 4 + 0][am] = bv.x; Bs[akg * 4 + 1][am] = bv.y;
    Bs[akg * 4 + 2][am] = bv.z; Bs[akg * 4 + 3][am] = bv.w;
    __syncthreads();
#pragma unroll
    for (int kk = 0; kk < 16; ++kk) {
      float4 bq = *reinterpret_cast<const float4*>(&Bs[kk][tx * 4]);
      float a0 = As[kk][ty * 4 + 0], a1 = As[kk][ty * 4 + 1];
      float a2 = As[kk][ty * 4 + 2], a3 = As[kk][ty * 4 + 3];
      acc[0][0] += a0 * bq.x; acc[0][1] += a0 * bq.y; acc[0][2] += a0 * bq.z; acc[0][3] += a0 * bq.w;
      acc[1][0] += a1 * bq.x; acc[1][1] += a1 * bq.y; acc[1][2] += a1 * bq.z; acc[1][3] += a1 * bq.w;
      acc[2][0] += a2 * bq.x; acc[2][1] += a2 * bq.y; acc[2][2] += a2 * bq.z; acc[2][3] += a2 * bq.w;
      acc[3][0] += a3 * bq.x; acc[3][1] += a3 * bq.y; acc[3][2] += a3 * bq.z; acc[3][3] += a3 * bq.w;
    }
  }
#pragma unroll
  for (int i = 0; i < 4; ++i) {
    int gr = m0 + ty * 4 + i;
#pragma unroll
    for (int j = 0; j < 4; ++j)
      C[(size_t)gr * ldc + n0 + tx * 4 + j] = acc[i][j];
  }
}

// ------------- row softmax (256 cols) -------------
__global__ __launch_bounds__(256) void softmax_rows256(float* __restrict__ buf) {
  __shared__ float red[4];
  size_t row = blockIdx.x;
  float* r = buf + row * 256;
  int tid = threadIdx.x, lane = tid & 63, wid = tid >> 6;
  float v = r[tid];
  float mx = wave_max(v);
  if (!lane) red[wid] = mx;
  __syncthreads();
  mx = fmaxf(fmaxf(red[0], red[1]), fmaxf(red[2], red[3]));
  __syncthreads();
  float e = expf(v - mx);
  float s = wave_sum(e);
  if (!lane) red[wid] = s;
  __syncthreads();
  s = red[0] + red[1] + red[2] + red[3];
  r[tid] = e / s;
}

// ------------- pinv scalar: max column-sum -------------
__global__ void init_scalars(float* sc) { if (threadIdx.x < 2) sc[threadIdx.x] = 0.f; }

__global__ __launch_bounds__(256) void colsum_part(const float* __restrict__ a2,
                                                   float* __restrict__ part) {
  int bh = blockIdx.x >> 3, chunk = blockIdx.x & 7;
  int tid = threadIdx.x;
  const float* M = a2 + (size_t)bh * 65536 + (size_t)chunk * 32 * 256;
  float acc = 0.f;
#pragma unroll
  for (int r = 0; r < 32; ++r) acc += M[r * 256 + tid];
  part[(size_t)blockIdx.x * 256 + tid] = acc;
}

__global__ __launch_bounds__(256) void colsum_final(const float* __restrict__ part,
                                                    float* __restrict__ sc) {
  __shared__ float red[4];
  int bh = blockIdx.x;
  int tid = threadIdx.x, lane = tid & 63, w = tid >> 6;
  float s = 0.f;
#pragma unroll
  for (int c = 0; c < 8; ++c) s += part[(size_t)(bh * 8 + c) * 256 + tid];
  float m = wave_max(s);
  if (!lane) red[w] = m;
  __syncthreads();
  if (tid == 0) {
    float mm = fmaxf(fmaxf(red[0], red[1]), fmaxf(red[2], red[3]));
    atomicMax(reinterpret_cast<int*>(sc) + 1, __float_as_int(mm));
  }
}

// ------------- split attn2 hi/lo bf16: X, z0=X^T/c, z0^T=X/c -------------
__global__ __launch_bounds__(256) void hilo_split(
    const float* __restrict__ a2, const float* __restrict__ sc,
    unsigned short* __restrict__ Xh, unsigned short* __restrict__ Xl,
    unsigned short* __restrict__ zth, unsigned short* __restrict__ ztl,
    unsigned short* __restrict__ zh, unsigned short* __restrict__ zl) {
  __shared__ float t[64][65];
  int bz = blockIdx.z;
  size_t base = (size_t)bz * 65536;
  int i0 = blockIdx.y * 64, j0 = blockIdx.x * 64;
  int tid = threadIdx.x, tx = tid & 15, ty = tid >> 4;
  float inv = 1.f / sc[1];
#pragma unroll
  for (int rr = 0; rr < 64; rr += 16) {
    int gr = i0 + rr + ty, gc0 = j0 + tx * 4;
    float4 v = *(const float4*)&a2[base + (size_t)gr * 256 + gc0];
    t[rr + ty][tx * 4 + 0] = v.x; t[rr + ty][tx * 4 + 1] = v.y;
    t[rr + ty][tx * 4 + 2] = v.z; t[rr + ty][tx * 4 + 3] = v.w;
    ushort4 xh, xl2, sh, sl;
    float vv[4] = {v.x, v.y, v.z, v.w};
    unsigned short* ph = (unsigned short*)&xh;
    unsigned short* pl = (unsigned short*)&xl2;
    unsigned short* qh = (unsigned short*)&sh;
    unsigned short* ql2 = (unsigned short*)&sl;
#pragma unroll
    for (int j = 0; j < 4; ++j) {
      ph[j] = f2b(vv[j]);
      pl[j] = f2b(vv[j] - b2f(ph[j]));
      float s = vv[j] * inv;
      qh[j] = f2b(s);
      ql2[j] = f2b(s - b2f(qh[j]));
    }
    *(ushort4*)&Xh[base + (size_t)gr * 256 + gc0] = xh;
    *(ushort4*)&Xl[base + (size_t)gr * 256 + gc0] = xl2;
    *(ushort4*)&zth[base + (size_t)gr * 256 + gc0] = sh;
    *(ushort4*)&ztl[base + (size_t)gr * 256 + gc0] = sl;
  }
  __syncthreads();
#pragma unroll
  for (int rr = 0; rr < 64; rr += 16) {
    int gr = j0 + rr + ty;
    int gc0 = i0 + tx * 4;
    ushort4 zh4, zl4;
    unsigned short* ph = (unsigned short*)&zh4;
    unsigned short* pl = (unsigned short*)&zl4;
#pragma unroll
    for (int j = 0; j < 4; ++j) {
      float s = t[tx * 4 + j][rr + ty] * inv;
      ph[j] = f2b(s);
      pl[j] = f2b(s - b2f(ph[j]));
    }
    *(ushort4*)&zh[base + (size_t)gr * 256 + gc0] = zh4;
    *(ushort4*)&zl[base + (size_t)gr * 256 + gc0] = zl4;
  }
}

// ------------- NS hi/lo MFMA GEMM, XCD-swizzled -------------
__global__ __launch_bounds__(256) void ns_mfma(
    const unsigned short* __restrict__ Ah, const unsigned short* __restrict__ Al,
    const unsigned short* __restrict__ Bth, const unsigned short* __restrict__ Btl,
    const unsigned short* __restrict__ Eh, const unsigned short* __restrict__ El,
    float alpha, float diag, float beta,
    unsigned short* __restrict__ Ch, unsigned short* __restrict__ Cl,
    unsigned short* __restrict__ CTh, unsigned short* __restrict__ CTl,
    float* __restrict__ Cf) {
  __shared__ __align__(16) unsigned short AhS[64][72], AlS[64][72];
  __shared__ __align__(16) unsigned short BhS[64][72], BlS[64][72];
  const int tid = threadIdx.x;
  const int l16 = tid & 15, h8 = (tid & 63) >> 4, w = tid >> 6;
  int wg = (blockIdx.z * gridDim.y + blockIdx.y) * gridDim.x + blockIdx.x;
  wg = xcd_swz(wg, gridDim.x * gridDim.y * gridDim.z);
  const size_t base = (size_t)(wg >> 4) * 65536;   // batch: 16 tiles each
  const int m0 = ((wg >> 2) & 3) * 64, n0 = (wg & 3) * 64;
  const int wr = (w >> 1) * 32, wc = (w & 1) * 32;
  const int srow = tid >> 2, scol = (tid & 3) * 16;
  f32x4 acc[2][2] = {};
  for (int k0 = 0; k0 < 256; k0 += 64) {
    const size_t aoff = base + (size_t)(m0 + srow) * 256 + k0 + scol;
    const size_t boff = base + (size_t)(n0 + srow) * 256 + k0 + scol;
    *(u16x8*)&AhS[srow][scol] = *(const u16x8*)(Ah + aoff);
    *(u16x8*)&AhS[srow][scol + 8] = *(const u16x8*)(Ah + aoff + 8);
    *(u16x8*)&AlS[srow][scol] = *(const u16x8*)(Al + aoff);
    *(u16x8*)&AlS[srow][scol + 8] = *(const u16x8*)(Al + aoff + 8);
    *(u16x8*)&BhS[srow][scol] = *(const u16x8*)(Bth + boff);
    *(u16x8*)&BhS[srow][scol + 8] = *(const u16x8*)(Bth + boff + 8);
    *(u16x8*)&BlS[srow][scol] = *(const u16x8*)(Btl + boff);
    *(u16x8*)&BlS[srow][scol + 8] = *(const u16x8*)(Btl + boff + 8);
    __syncthreads();
#pragma unroll
    for (int ks = 0; ks < 2; ++ks) {
      bf16x8 ah[2], al[2], bh[2], bl[2];
#pragma unroll
      for (int mi = 0; mi < 2; ++mi) {
        ah[mi] = *(const bf16x8*)&AhS[wr + mi * 16 + l16][ks * 32 + h8 * 8];
        al[mi] = *(const bf16x8*)&AlS[wr + mi * 16 + l16][ks * 32 + h8 * 8];
      }
#pragma unroll
      for (int nj = 0; nj < 2; ++nj) {
        bh[nj] = *(const bf16x8*)&BhS[wc + nj * 16 + l16][ks * 32 + h8 * 8];
        bl[nj] = *(const bf16x8*)&BlS[wc + nj * 16 + l16][ks * 32 + h8 * 8];
      }
#pragma unroll
      for (int mi = 0; mi < 2; ++mi)
#pragma unroll
        for (int nj = 0; nj < 2; ++nj) {
          acc[mi][nj] = mfma16(ah[mi], bh[nj], acc[mi][nj]);
          acc[mi][nj] = mfma16(ah[mi], bl[nj], acc[mi][nj]);
          acc[mi][nj] = mfma16(al[mi], bh[nj], acc[mi][nj]);
        }
    }
    __syncthreads();
  }
#pragma unroll
  for (int mi = 0; mi < 2; ++mi)
#pragma unroll
    for (int nj = 0; nj < 2; ++nj) {
      int grow0 = m0 + wr + mi * 16 + 4 * h8;
      int gcol = n0 + wc + nj * 16 + l16;
      float vals[4];
      ushort4 th, tl;
      unsigned short* ph = (unsigned short*)&th;
      unsigned short* pl = (unsigned short*)&tl;
#pragma unroll
      for (int r = 0; r < 4; ++r) {
        int grow = grow0 + r;
        float v = alpha * acc[mi][nj][r];
        if (grow == gcol) v += diag;
        if (Eh) v += beta * (b2f(Eh[base + (size_t)grow * 256 + gcol]) +
                             b2f(El[base + (size_t)grow * 256 + gcol]));
        vals[r] = v;
        ph[r] = f2b(v);
        pl[r] = f2b(v - b2f(ph[r]));
      }
      if (Ch) {
#pragma unroll
        for (int r = 0; r < 4; ++r) {
          Ch[base + (size_t)(grow0 + r) * 256 + gcol] = ph[r];
          Cl[base + (size_t)(grow0 + r) * 256 + gcol] = pl[r];
        }
      }
      if (CTh) {
        *(ushort4*)&CTh[base + (size_t)gcol * 256 + grow0] = th;
        *(ushort4*)&CTl[base + (size_t)gcol * 256 + grow0] = tl;
      }
      if (Cf) {
#pragma unroll
        for (int r = 0; r < 4; ++r)
          Cf[base + (size_t)(grow0 + r) * 256 + gcol] = vals[r];
      }
    }
}

// ------------- MFMA flash, swapped QK^T (keys in regs, q = l16) -------------
// QK: D[key][q] -> softmax per-q is 16-reg local + 2 shuffles (h8 axis).
// PV unchanged: acc_o[d-rows][q=l16].
// MODE 0: split-K partials (float4 Opart + ML)   MODE 1: normalize + bf16 outh
template <int MODE>
__global__ __launch_bounds__(256) void flash_mfma(
    const unsigned short* __restrict__ Q, const unsigned short* __restrict__ Kp,
    const unsigned short* __restrict__ Vp, long long sQ, long long sK,
    int kps, int nkt,
    float* __restrict__ Opart, float* __restrict__ MLpart,
    unsigned short* __restrict__ outh16) {
  __shared__ __align__(16) unsigned short Qt[128][72];
  __shared__ __align__(16) unsigned short Kt[64][72];
  __shared__ __align__(16) unsigned short Vt[64][72];
  __shared__ __align__(16) unsigned short Pb[128][72];
  const int tid = threadIdx.x;
  const int l16 = tid & 15, h8 = (tid & 63) >> 4, w = tid >> 6;
  const int bh = blockIdx.y, s = blockIdx.z, qt = blockIdx.x;
  const int q0 = qt * 128;
  const unsigned short* Qb = Q + (size_t)bh * sQ + (size_t)q0 * 64;
  const unsigned short* Kb = Kp + (size_t)bh * sK + (size_t)s * kps * 64;
  const unsigned short* Vb = Vp + (size_t)bh * sK + (size_t)s * kps * 64;
  {
    int row = tid >> 1, c0 = (tid & 1) * 32;
#pragma unroll
    for (int i = 0; i < 4; ++i)
      *(u16x8*)&Qt[row][c0 + 8 * i] = *(const u16x8*)(Qb + (size_t)row * 64 + c0 + 8 * i);
  }
  f32x4 acc_o[2][4] = {};       // [q-group mi][d-group dj]; row d=4h8+r, col q=l16
  float mreg[2] = {-1e30f, -1e30f}, lreg[2] = {0.f, 0.f};  // per-thread q state
  for (int kt = 0; kt < nkt; ++kt) {
    {
      int row = tid >> 2, c0 = (tid & 3) * 16;
      *(u16x8*)&Kt[row][c0] = *(const u16x8*)(Kb + ((size_t)(kt * 64 + row)) * 64 + c0);
      *(u16x8*)&Kt[row][c0 + 8] = *(const u16x8*)(Kb + ((size_t)(kt * 64 + row)) * 64 + c0 + 8);
      int key = tid & 63, d0 = w * 16;
      u16x8 v0 = *(const u16x8*)(Vb + ((size_t)(kt * 64 + key)) * 64 + d0);
      u16x8 v1 = *(const u16x8*)(Vb + ((size_t)(kt * 64 + key)) * 64 + d0 + 8);
#pragma unroll
      for (int i = 0; i < 8; ++i) { Vt[d0 + i][key] = v0[i]; Vt[d0 + 8 + i][key] = v1[i]; }
    }
    __syncthreads();
    // QK^T swapped: D[key = nj*16+4h8+r][q = w*32+mi*16+l16]
    f32x4 accs[2][4] = {};
#pragma unroll
    for (int ks = 0; ks < 2; ++ks) {
      bf16x8 qf[2], kf[4];
      qf[0] = *(const bf16x8*)&Qt[w * 32 + l16][ks * 32 + h8 * 8];
      qf[1] = *(const bf16x8*)&Qt[w * 32 + 16 + l16][ks * 32 + h8 * 8];
#pragma unroll
      for (int nj = 0; nj < 4; ++nj)
        kf[nj] = *(const bf16x8*)&Kt[nj * 16 + l16][ks * 32 + h8 * 8];
#pragma unroll
      for (int mi = 0; mi < 2; ++mi)
#pragma unroll
        for (int nj = 0; nj < 4; ++nj)
          accs[mi][nj] = mfma16(kf[nj], qf[mi], accs[mi][nj]);  // keys as A rows
    }
    // online softmax: per thread-q (mi), 16 local keys + h8-axis reduce
#pragma unroll
    for (int mi = 0; mi < 2; ++mi) {
      float mx = accs[mi][0][0];
#pragma unroll
      for (int nj = 0; nj < 4; ++nj)
#pragma unroll
        for (int r = 0; r < 4; ++r) mx = fmaxf(mx, accs[mi][nj][r]);
      mx = fmaxf(mx, __shfl_xor(mx, 16, 64));
      mx = fmaxf(mx, __shfl_xor(mx, 32, 64));
      float mn = fmaxf(mreg[mi], mx);
      float scf = __expf(mreg[mi] - mn);
      float ps = 0.f;
      int qrow = w * 32 + mi * 16 + l16;
#pragma unroll
      for (int nj = 0; nj < 4; ++nj) {
        ushort4 pk;
        unsigned short* pp = (unsigned short*)&pk;
#pragma unroll
        for (int r = 0; r < 4; ++r) {
          float p = __expf(accs[mi][nj][r] - mn);
          ps += p;
          pp[r] = f2b(p);
        }
        *(ushort4*)&Pb[qrow][nj * 16 + 4 * h8] = pk;  // P[q][key]
      }
      ps += __shfl_xor(ps, 16, 64);
      ps += __shfl_xor(ps, 32, 64);
      lreg[mi] = lreg[mi] * scf + ps;
      mreg[mi] = mn;
#pragma unroll
      for (int dj = 0; dj < 4; ++dj) {
        acc_o[mi][dj][0] *= scf; acc_o[mi][dj][1] *= scf;
        acc_o[mi][dj][2] *= scf; acc_o[mi][dj][3] *= scf;
      }
    }
    __syncthreads();
    // PV: a = V^T rows=d (Vt[d][key]), b = P^T cols=q (Pb[q][key])
#pragma unroll
    for (int ks = 0; ks < 2; ++ks) {
      bf16x8 pa[2], vb2[4];
      pa[0] = *(const bf16x8*)&Pb[w * 32 + l16][ks * 32 + h8 * 8];
      pa[1] = *(const bf16x8*)&Pb[w * 32 + 16 + l16][ks * 32 + h8 * 8];
#pragma unroll
      for (int dj = 0; dj < 4; ++dj)
        vb2[dj] = *(const bf16x8*)&Vt[dj * 16 + l16][ks * 32 + h8 * 8];
#pragma unroll
      for (int mi = 0; mi < 2; ++mi)
#pragma unroll
        for (int dj = 0; dj < 4; ++dj)
          acc_o[mi][dj] = mfma16(vb2[dj], pa[mi], acc_o[mi][dj]);
    }
    __syncthreads();
  }
  if (MODE == 0) {
    int p = (s * 32 + bh) * 2 + qt;
    float* Ob = Opart + (size_t)p * 8192;
#pragma unroll
    for (int mi = 0; mi < 2; ++mi) {
      int row = w * 32 + mi * 16 + l16;
#pragma unroll
      for (int dj = 0; dj < 4; ++dj) {
        int d0 = dj * 16 + 4 * h8;
        *(float4*)&Ob[(size_t)row * 64 + d0] =
            make_float4(acc_o[mi][dj][0], acc_o[mi][dj][1], acc_o[mi][dj][2], acc_o[mi][dj][3]);
      }
      if (h8 == 0) {
        MLpart[((size_t)p * 128 + row) * 2] = mreg[mi];
        MLpart[((size_t)p * 128 + row) * 2 + 1] = lreg[mi];
      }
    }
  } else {
    int bidx = bh >> 3, hh = bh & 7;
#pragma unroll
    for (int mi = 0; mi < 2; ++mi) {
      int qr = q0 + w * 32 + mi * 16 + l16;
      float linv = 1.f / lreg[mi];
#pragma unroll
      for (int dj = 0; dj < 4; ++dj) {
        int d0 = dj * 16 + 4 * h8;
        ushort4 o;
        o.x = f2b(acc_o[mi][dj][0] * linv);
        o.y = f2b(acc_o[mi][dj][1] * linv);
        o.z = f2b(acc_o[mi][dj][2] * linv);
        o.w = f2b(acc_o[mi][dj][3] * linv);
        *(ushort4*)&outh16[((size_t)bidx * NTOK + qr) * 512 + hh * 64 + d0] = o;
      }
    }
  }
}

// ------------- combine split-K flash partials -> T3 -------------
__global__ __launch_bounds__(256) void flash_combine(const float* __restrict__ Opart,
                                                     const float* __restrict__ MLpart,
                                                     float* __restrict__ T3) {
  int bh = blockIdx.y;
  int row = blockIdx.x * 4 + (threadIdx.x >> 6);
  int d = threadIdx.x & 63;
  int qt = row >> 7, rowin = row & 127;
  float mstar = -1e30f;
#pragma unroll
  for (int s = 0; s < 8; ++s) {
    int p = (s * 32 + bh) * 2 + qt;
    mstar = fmaxf(mstar, MLpart[((size_t)p * 128 + rowin) * 2]);
  }
  float L = 0.f, O = 0.f;
#pragma unroll
  for (int s = 0; s < 8; ++s) {
    int p = (s * 32 + bh) * 2 + qt;
    float ms = MLpart[((size_t)p * 128 + rowin) * 2];
    float ls = MLpart[((size_t)p * 128 + rowin) * 2 + 1];
    float e = __expf(ms - mstar);
    L += ls * e;
    O += Opart[(size_t)p * 8192 + rowin * 64 + d] * e;
  }
  T3[((size_t)bh * 256 + row) * 64 + d] = O / L;
}

// ------------- depthwise conv, input-major sliding accumulation -------------
__global__ __launch_bounds__(256) void conv_add_bf16(const unsigned short* __restrict__ v,
                                                     const float* __restrict__ cw,
                                                     unsigned short* __restrict__ outh16) {
  __shared__ float vt[96][68];
  int z = blockIdx.x;
  int bh = z >> 7, n0 = (z & 127) * 64;
  int tid = threadIdx.x;
  const unsigned short* vb = v + (size_t)bh * NTOK * 64;
  for (int f = tid; f < 768; f += 256) {
    int rowi = f >> 3, c8 = (f & 7) * 8;
    int rn = n0 - 16 + rowi;
    if (rn >= 0 && rn < NTOK) {
      u16x8 val = *(const u16x8*)(vb + (size_t)rn * 64 + c8);
#pragma unroll
      for (int i = 0; i < 8; ++i) vt[rowi][c8 + i] = b2f(val[i]);
    } else {
#pragma unroll
      for (int i = 0; i < 8; ++i) vt[rowi][c8 + i] = 0.f;
    }
  }
  float wreg[33];
#pragma unroll
  for (int k = 0; k < 33; ++k) wreg[k] = cw[(bh & 7) * 33 + k];
  __syncthreads();
  int dd = tid & 63, rg = tid >> 6;
  int bidx = bh >> 3, hh = bh & 7;
  float acc[16];
#pragma unroll
  for (int r = 0; r < 16; ++r) acc[r] = 0.f;
#pragma unroll
  for (int j = 0; j < 48; ++j) {
    float vv = vt[rg * 16 + j][dd];
    int rlo = j - 32 < 0 ? 0 : j - 32;
    int rhi = j < 15 ? j : 15;
#pragma unroll
    for (int r = 0; r < 16; ++r)
      if (r >= rlo && r <= rhi) acc[r] += wreg[j - r] * vv;
  }
#pragma unroll
  for (int r = 0; r < 16; ++r) {
    size_t o = ((size_t)bidx * NTOK + n0 + rg * 16 + r) * 512 + hh * 64 + dd;
    outh16[o] = f2b(b2f(outh16[o]) + acc[r]);
  }
}

extern "C" void kernel_launch(void* const* d_in, const int* in_sizes, int n_in,
                              void* d_out, int out_size, void* d_ws, size_t ws_size,
                              hipStream_t stream) {
  const float* x = (const float*)d_in[0];
  const float* gamma = (const float*)d_in[1];
  const float* beta = (const float*)d_in[2];
  const float* w_qkv = (const float*)d_in[3];
  const float* w_out = (const float*)d_in[4];
  const float* b_out = (const float*)d_in[5];
  const float* conv_w = (const float*)d_in[6];
  float* out = (float*)d_out;
  float* ws = (float*)d_ws;
  (void)ws_size; (void)in_sizes; (void)n_in; (void)out_size;

  float* A0 = ws;
  float* Breg = ws + 16777216;
  unsigned short* qb = (unsigned short*)(ws + 25165824);
  unsigned short* kb = (unsigned short*)(ws + 33554432);
  unsigned short* vb = (unsigned short*)(ws + 41943040);
  float* Fs = ws + 50331648;

  // A0 tenants
  float* X2 = A0;
  float* zfinal = A0;
  float* ql = A0 + 2097152;
  float* kl = A0 + 2621440;
  unsigned short* Xh  = (unsigned short*)(A0 + 2097152);
  unsigned short* Xl  = (unsigned short*)(A0 + 3145728);
  unsigned short* zAh = (unsigned short*)(A0 + 4194304);
  unsigned short* zAl = (unsigned short*)(A0 + 5242880);
  unsigned short* zAth = (unsigned short*)(A0 + 6291456);
  unsigned short* zAtl = (unsigned short*)(A0 + 7340032);
  unsigned short* zYh = (unsigned short*)(A0 + 8388608);
  unsigned short* zYl = (unsigned short*)(A0 + 9437184);
  unsigned short* zYth = (unsigned short*)(A0 + 10485760);
  unsigned short* zYtl = (unsigned short*)(A0 + 11534336);
  unsigned short* TBth = (unsigned short*)(A0 + 12582912);
  unsigned short* TBtl = (unsigned short*)(A0 + 13631488);
  unsigned short* TAth = (unsigned short*)(A0 + 14680064);
  unsigned short* TAtl = (unsigned short*)(A0 + 15728640);
  unsigned short* outh16 = (unsigned short*)A0;
  // Breg tenants
  unsigned short* xnb = (unsigned short*)Breg;
  float* Opart = Breg;
  float* MLpart = Breg + 4194304;
  float* T3 = Breg + 4325376;
  // Fs tenants
  float* xl = Fs;
  unsigned short* qlb = (unsigned short*)(Fs + 524288);
  unsigned short* klb = (unsigned short*)(Fs + 786432);
  unsigned short* W2b = (unsigned short*)(Fs + 1048576);
  unsigned short* woutT = (unsigned short*)(Fs + 1310720);
  unsigned short* wqkvT = (unsigned short*)(Fs + 1441792);
  float* part = Fs + 1835008;
  float* sc = Fs + 1900544;

  // 1. fused LayerNorm + pooling
  ln_pool<<<1024, 256, 0, stream>>>(x, gamma, beta, xnb, xl);
  // 2. weight transposes
  transpose_cvt<<<dim3(48, 16), 256, 0, stream>>>(w_qkv, wqkvT, 512, 1536);
  transpose_cvt<<<dim3(16, 16), 256, 0, stream>>>(w_out, woutT, 512, 512);
  // 3. qkv projection (XCD-swizzled)
  gemm_mfma<0><<<dim3(12, 256), 256, 0, stream>>>(xnb, wqkvT, 512, qb, kb, vb,
                                                  nullptr, nullptr, nullptr);
  // 4. ql/kl = xl @ Wq/Wk fp32 (+ bf16 fused)
  gemm_ab<<<dim3(16, 16, 1), 256, 0, stream>>>(xl, w_qkv, 512, 512, 1536, 0, 0,
                                               5, ql, kl, qlb, klb);
  // 5. sim2 -> attn2 (fp32)
  gemm_abt<<<dim3(4, 4, BH), 256, 0, stream>>>(ql, kl, X2, 64, 64, 64, 256,
                                               16384, 16384, 65536);
  softmax_rows256<<<BH * NM, 256, 0, stream>>>(X2);
  // 6. pinv scalar + hi/lo split
  init_scalars<<<1, 64, 0, stream>>>(sc);
  colsum_part<<<BH * 8, 256, 0, stream>>>(X2, part);
  colsum_final<<<BH, 256, 0, stream>>>(part, sc);
  hilo_split<<<dim3(4, 4, BH), 256, 0, stream>>>(X2, sc, Xh, Xl, zAth, zAtl, zAh, zAl);
  // 7. Newton-Schulz hi/lo MFMA (XCD-swizzled)
  unsigned short *ch = zAh, *cl = zAl, *cth = zAth, *ctl = zAtl;
  unsigned short *yh = zYh, *yl = zYl, *yth = zYth, *ytl = zYtl;
  for (int it = 0; it < 6; ++it) {
    ns_mfma<<<dim3(4, 4, BH), 256, 0, stream>>>(Xh, Xl, cth, ctl, nullptr, nullptr,
                                                1.f, 0.f, 0.f, yh, yl, yth, ytl, nullptr);
    ns_mfma<<<dim3(4, 4, BH), 256, 0, stream>>>(yh, yl, yth, ytl, yh, yl,
                                                1.f, 15.f, -7.f, nullptr, nullptr,
                                                TBth, TBtl, nullptr);
    ns_mfma<<<dim3(4, 4, BH), 256, 0, stream>>>(yh, yl, TBth, TBtl, nullptr, nullptr,
                                                -1.f, 13.f, 0.f, nullptr, nullptr,
                                                TAth, TAtl, nullptr);
    ns_mfma<<<dim3(4, 4, BH), 256, 0, stream>>>(ch, cl, TAth, TAtl, nullptr, nullptr,
                                                0.25f, 0.f, 0.f, yh, yl, yth, ytl,
                                                it == 5 ? zfinal : nullptr);
    unsigned short* t;
    t = ch; ch = yh; yh = t;  t = cl; cl = yl; yl = t;
    t = cth; cth = yth; yth = t;  t = ctl; ctl = ytl; ytl = t;
  }
  // 8. flash A (split-K=8)
  flash_mfma<0><<<dim3(2, 32, 8), 256, 0, stream>>>(qlb, kb, vb, 16384, 524288,
                                                    1024, 16, Opart, MLpart, nullptr);
  flash_combine<<<dim3(64, 32), 256, 0, stream>>>(Opart, MLpart, T3);
  // 9. W2 = pinv @ T3 -> bf16
  gemm_ab<<<dim3(1, 4, BH), 256, 0, stream>>>(zfinal, T3, 256, 256, 64, 65536, 16384,
                                              7, nullptr, nullptr, W2b, nullptr);
  // 10. flash B -> bf16 outh
  flash_mfma<1><<<dim3(64, 32, 1), 256, 0, stream>>>(qb, klb, W2b, 524288, 16384,
                                                     0, 4, nullptr, nullptr, outh16);
  // 11. conv residual
  conv_add_bf16<<<BH * (NTOK / 64), 256, 0, stream>>>(vb, conv_w, outh16);
  // 12. out = x + outh @ w_out + b_out (XCD-swizzled)
  gemm_mfma<2><<<dim3(4, 256), 256, 0, stream>>>(outh16, woutT, 512, nullptr, nullptr,
                                                 nullptr, out, b_out, x);
}